// Round 7
// baseline (580.438 us; speedup 1.0000x reference)
//
#include <hip/hip_runtime.h>
#include <hip/hip_cooperative_groups.h>
#include <hip/hip_bf16.h>

namespace cg = cooperative_groups;

typedef __hip_bfloat16 BF;
typedef __attribute__((ext_vector_type(8))) short bf16x8;
typedef __attribute__((ext_vector_type(4))) float f32x4;
typedef __attribute__((ext_vector_type(4))) unsigned short us4;

// B=2, C=128, H=W=128, K=8, STRIDE=2, DIL=2, NH=8, dh=16, HID=170, Hc=Wc=64
// Single cooperative kernel: Phase A {kv | transpose | pack} -> grid.sync ->
// Phase B (2048 cell units over 1280 blocks). Fallback: two plain kernels.

#define ASTR 200   // cell Abuf row stride (bf16)
#define KSTR 136   // kv Abuf row stride (bf16)

struct KP {
  const float *x, *qkv_w, *proj_w, *fc1_w, *fc2_w, *qkv_b;
  const float *qg, *qb, *kg, *kb, *n1g, *n1b, *proj_b, *ls1, *ls2;
  const float *n2g, *n2b, *fc1_b, *mg, *mb, *fc2_b;
  float *xt, *kcb, *vcb, *out;
  BF *pk;
};

__device__ __forceinline__ short bfr(float f){
  union{float f; unsigned u;} c; c.f = f;
  const unsigned u = c.u + 0x7FFFu + ((c.u >> 16) & 1u);
  return (short)(u >> 16);
}
__device__ __forceinline__ bf16x8 pk8(float4 a, float4 b){
  bf16x8 r;
  r[0]=bfr(a.x); r[1]=bfr(a.y); r[2]=bfr(a.z); r[3]=bfr(a.w);
  r[4]=bfr(b.x); r[5]=bfr(b.y); r[6]=bfr(b.z); r[7]=bfr(b.w);
  return r;
}

// sum-reduce 16 vals across a 128-thr half of a 256-thr block
__device__ __forceinline__ void gsum16h(float v[16], float* red, int tid){
  #pragma unroll
  for(int s = 1; s < 64; s <<= 1){
    #pragma unroll
    for(int i = 0; i < 16; i++) v[i] += __shfl_xor(v[i], s);
  }
  const int wid = tid >> 6, half = tid >> 7;
  __syncthreads();
  if((tid & 63) == 0){
    #pragma unroll
    for(int i = 0; i < 16; i++) red[wid*16 + i] = v[i];
  }
  __syncthreads();
  #pragma unroll
  for(int i = 0; i < 16; i++) v[i] = red[half*32 + i] + red[half*32 + 16 + i];
}

// per-half row-stat reduction (kv)
__device__ __forceinline__ void rowredh(float s1[4], float s2[4], float* red, int tid){
  const int lane = tid & 63, wid = tid >> 6, half = tid >> 7;
  #pragma unroll
  for(int m = 1; m < 16; m <<= 1){
    #pragma unroll
    for(int r = 0; r < 4; r++){ s1[r] += __shfl_xor(s1[r], m); s2[r] += __shfl_xor(s2[r], m); }
  }
  const int q4 = lane >> 4;
  __syncthreads();
  if((lane & 15) == 0){
    #pragma unroll
    for(int r = 0; r < 4; r++){
      red[wid*32 + q4*4 + r]      = s1[r];
      red[wid*32 + 16 + q4*4 + r] = s2[r];
    }
  }
  __syncthreads();
  #pragma unroll
  for(int r = 0; r < 4; r++){
    s1[r] = red[half*64 + q4*4 + r]      + red[half*64 + 32 + q4*4 + r];
    s2[r] = red[half*64 + 16 + q4*4 + r] + red[half*64 + 48 + q4*4 + r];
  }
}

// 4-wave row-stat reduction (cell)
__device__ __forceinline__ void rowred4(float s1[4], float s2[4], float* red,
                                        int wave, int lane){
  #pragma unroll
  for(int m = 1; m < 16; m <<= 1){
    #pragma unroll
    for(int r = 0; r < 4; r++){ s1[r] += __shfl_xor(s1[r], m); s2[r] += __shfl_xor(s2[r], m); }
  }
  const int q4 = lane >> 4;
  __syncthreads();
  if((lane & 15) == 0){
    #pragma unroll
    for(int r = 0; r < 4; r++){
      red[wave*32 + q4*4 + r]      = s1[r];
      red[wave*32 + 16 + q4*4 + r] = s2[r];
    }
  }
  __syncthreads();
  #pragma unroll
  for(int r = 0; r < 4; r++){
    s1[r] = red[q4*4 + r] + red[32 + q4*4 + r] + red[64 + q4*4 + r] + red[96 + q4*4 + r];
    s2[r] = red[16 + q4*4 + r] + red[48 + q4*4 + r] + red[80 + q4*4 + r] + red[112 + q4*4 + r];
  }
}

// ---- Phase A: blocks 0..511 kv(16px); 512..767 2 transpose tiles;
//      768..1279 1 tile + weight-pack. 1280-block layout. ----
__device__ __forceinline__ void pre_work(const KP& P, BF* uni, float* red){
  const int bid = blockIdx.x, tid = threadIdx.x;
  if(bid < 512){
    BF* const Abuf = uni;                      // 2 halves x [16][KSTR]
    const int lane = tid & 63, half = tid >> 7, wh = (tid >> 6) & 1, c = tid & 127;
    const int l15 = lane & 15, q4 = lane >> 4;
    const int cp0 = bid * 16;
    const int b = cp0 >> 12, ic = (cp0 & 4095) >> 6, jb = cp0 & 63;
    BF* const AbufH = Abuf + half*16*KSTR;

    float xv[8];
    {
      const size_t off = (size_t)(b*128 + c)*16384 + (size_t)(2*ic)*128 + 2*(jb + half*8);
      const float4* xp4 = (const float4*)(P.x + off);
      const float4 f0 = xp4[0], f1 = xp4[1], f2 = xp4[2], f3 = xp4[3];
      xv[0]=f0.x; xv[1]=f0.z; xv[2]=f1.x; xv[3]=f1.z;
      xv[4]=f2.x; xv[5]=f2.z; xv[6]=f3.x; xv[7]=f3.z;
    }
    float st[16];
    #pragma unroll
    for(int r = 0; r < 8; r++){ st[r] = xv[r]; st[8+r] = xv[r]*xv[r]; }
    gsum16h(st, red, tid);
    {
      const float g = P.n1g[c], be = P.n1b[c];
      #pragma unroll
      for(int r = 0; r < 8; r++){
        const float mu = st[r]*(1.f/128.f);
        const float var = st[8+r]*(1.f/128.f) - mu*mu;
        AbufH[r*KSTR + c] = __float2bfloat16((xv[r]-mu)*rsqrtf(var+1e-6f)*g + be);
      }
    }
    __syncthreads();
    bf16x8 af[4];
    #pragma unroll
    for(int s = 0; s < 4; s++) af[s] = *(const bf16x8*)&AbufH[l15*KSTR + s*32 + q4*8];

    // k GEMM (B-fragments straight from qkv_w)
    f32x4 acc[4];
    #pragma unroll
    for(int nt = 0; nt < 4; nt++){ acc[nt][0]=0.f; acc[nt][1]=0.f; acc[nt][2]=0.f; acc[nt][3]=0.f; }
    #pragma unroll
    for(int nt = 0; nt < 4; nt++){
      const int n = (wh*4+nt)*16 + l15;
      #pragma unroll
      for(int s = 0; s < 4; s++){
        const float* wp = P.qkv_w + (size_t)(128 + n)*128 + s*32 + q4*8;
        acc[nt] = __builtin_amdgcn_mfma_f32_16x16x32_bf16(
          af[s], pk8(*(const float4*)wp, *(const float4*)(wp+4)), acc[nt], 0,0,0);
      }
    }
    float s1[4], s2[4];
    #pragma unroll
    for(int r = 0; r < 4; r++){ s1[r]=0.f; s2[r]=0.f; }
    #pragma unroll
    for(int nt = 0; nt < 4; nt++){
      const float colb = P.qkv_b[128 + (wh*4+nt)*16 + l15];
      #pragma unroll
      for(int r = 0; r < 4; r++){
        const float vv = acc[nt][r] + colb;
        acc[nt][r] = vv; s1[r] += vv; s2[r] += vv*vv;
      }
    }
    rowredh(s1, s2, red, tid);
    #pragma unroll
    for(int nt = 0; nt < 4; nt++){
      const int col = (wh*4+nt)*16 + l15;
      const float g = P.kg[col], be = P.kb[col];
      #pragma unroll
      for(int r = 0; r < 4; r++){
        const int row = q4*4 + r;
        if(row < 8){
          const float mu = s1[r]*(1.f/128.f);
          const float var = s2[r]*(1.f/128.f) - mu*mu;
          P.kcb[(size_t)(cp0 + half*8 + row)*128 + col] =
            (acc[nt][r]-mu)*rsqrtf(var+1e-6f)*g + be;
        }
      }
    }
    // v GEMM
    #pragma unroll
    for(int nt = 0; nt < 4; nt++){ acc[nt][0]=0.f; acc[nt][1]=0.f; acc[nt][2]=0.f; acc[nt][3]=0.f; }
    #pragma unroll
    for(int nt = 0; nt < 4; nt++){
      const int n = (wh*4+nt)*16 + l15;
      #pragma unroll
      for(int s = 0; s < 4; s++){
        const float* wp = P.qkv_w + (size_t)(256 + n)*128 + s*32 + q4*8;
        acc[nt] = __builtin_amdgcn_mfma_f32_16x16x32_bf16(
          af[s], pk8(*(const float4*)wp, *(const float4*)(wp+4)), acc[nt], 0,0,0);
      }
    }
    #pragma unroll
    for(int nt = 0; nt < 4; nt++){
      const int col = (wh*4+nt)*16 + l15;
      const float bv = P.qkv_b[256 + col];
      #pragma unroll
      for(int r = 0; r < 4; r++){
        const int row = q4*4 + r;
        if(row < 8) P.vcb[(size_t)(cp0 + half*8 + row)*128 + col] = acc[nt][r] + bv;
      }
    }
    return;
  }

  // transpose x (B,C,H,W) -> xt (B,HW,C): 1024 tiles over blocks 512..1279
  float (*tile)[65] = (float(*)[65])uni;       // 16640B, aliases uni
  const int t0 = bid - 512;
  const int ntile = (bid < 768) ? 2 : 1;
  for(int it = 0; it < ntile; it++){
    const int t = t0 + it*768;                 // it=0: 0..767; it=1: 768..1023
    const int b = t >> 9, r2 = t & 511;
    const int pb = (r2 & 255) * 64, cb = (r2 >> 8) * 64;
    const int tx = tid & 63, ty = tid >> 6;
    if(it) __syncthreads();
    #pragma unroll
    for(int r = 0; r < 64; r += 4)
      tile[ty+r][tx] = P.x[(size_t)(b*128 + cb+ty+r)*16384 + pb + tx];
    __syncthreads();
    #pragma unroll
    for(int r = 0; r < 64; r += 4)
      P.xt[(size_t)((b<<14) + pb + ty + r)*128 + cb + tx] = tile[tx][ty+r];
  }
  // weight pack on blocks 768..1207
  if(bid >= 768){
    const int idx = (bid - 768) * 256 + tid;
    if(idx < 112640){
      float val;
      if(idx < 49152){
        const int reg = idx >> 14, l = idx & 16383;
        const int j = l & 7, q = (l>>3)&3, n = (l>>5)&127, s = l>>12;
        val = P.qkv_w[(reg*128 + n)*128 + (s*32 + q*8 + j)];
      } else if(idx < 65536){
        const int l = idx - 49152;
        const int j = l&7, q=(l>>3)&3, n=(l>>5)&127, s=l>>12;
        val = P.proj_w[n*128 + (s*32+q*8+j)];
      } else if(idx < 88064){
        const int l = idx - 65536;
        const int j = l&7, q=(l>>3)&3, rem = l>>5;
        const int n = rem % 176, s = rem / 176;
        const int k = s*32+q*8+j;
        val = (n < 170) ? P.fc1_w[n*128 + k] : 0.f;
      } else {
        const int l = idx - 88064;
        const int j = l&7, q=(l>>3)&3, n=(l>>5)&127, s=l>>12;
        const int k = s*32+q*8+j;
        val = (k < 170) ? P.fc2_w[n*170 + k] : 0.f;
      }
      P.pk[idx] = __float2bfloat16(val);
    }
  }
}

// ---- Phase B: one cell unit (16 px, 4x4 tile), verbatim R6 body ----
__device__ __forceinline__ void cell_unit(const KP& P, int u,
                                          BF* uni, float* xvL,
                                          ushort* qnH, ushort* cidx2){
  const int tid = threadIdx.x, wave = tid>>6, lane = tid&63;
  const int l15 = lane & 15, q4 = lane >> 4;
  BF* const Abuf = uni;
  float* const red = (float*)qnH;
  const BF* packQ  = P.pk;
  const BF* packP  = P.pk + 49152;
  const BF* packF1 = P.pk + 65536;
  const BF* packF2 = P.pk + 88064;
  __syncthreads();                             // shared reuse guard

  // XCD-aware swizzle (bijective on [0,2048))
  const int bx = ((u & 7) << 8) | (u >> 3);
  const int b = bx >> 10, rem = bx & 1023, ip = rem >> 5, jq = rem & 31;
  const size_t p0 = (size_t)b*2097152 + (size_t)(512*ip + 4*jq)*128;
  const int c = tid & 127, half = tid >> 7;

  float xv[8];
  #pragma unroll
  for(int r = 0; r < 8; r++){
    const int p = half*8 + r;
    const size_t pr = p0 + ((size_t)(p>>2)<<14) + (size_t)((p&3)<<7);
    xv[r] = P.xt[pr + c];
    xvL[p*128 + c] = xv[r];
  }
  {
    const int cell = tid >> 6, e = tid & 63;
    const int i = e >> 3, j = e & 7;
    const int ic = 2*ip + (cell>>1), jcc = 2*jq + (cell&1);
    const int ri = ic + 2*i - 8, rj = jcc + 2*j - 8;
    const bool ok = (rj >= 0) && (rj < 64) && (ri >= 0) && (ri < 64);
    cidx2[cell*64 + e] = ok ? (ushort)(b*4096 + ri*64 + rj) : (ushort)0;
  }

  // LN1
  float st[16];
  #pragma unroll
  for(int r = 0; r < 8; r++){ st[r] = xv[r]; st[8+r] = xv[r]*xv[r]; }
  gsum16h(st, red, tid);
  {
    const float g = P.n1g[c], be = P.n1b[c];
    #pragma unroll
    for(int r = 0; r < 8; r++){
      const int p = half*8 + r;
      const float mu = st[r]*(1.f/128.f);
      const float var = st[8+r]*(1.f/128.f) - mu*mu;
      Abuf[p*ASTR + c] = __float2bfloat16((xv[r]-mu)*rsqrtf(var+1e-6f)*g + be);
    }
  }
  __syncthreads();

  // q GEMM (M=16) + q-LN -> qnH
  {
    bf16x8 af[4];
    #pragma unroll
    for(int s = 0; s < 4; s++) af[s] = *(const bf16x8*)&Abuf[l15*ASTR + s*32 + q4*8];
    f32x4 acc[2];
    #pragma unroll
    for(int nt = 0; nt < 2; nt++){ acc[nt][0]=0.f; acc[nt][1]=0.f; acc[nt][2]=0.f; acc[nt][3]=0.f; }
    #pragma unroll
    for(int nt = 0; nt < 2; nt++){
      const int n = (wave*2+nt)*16 + l15;
      #pragma unroll
      for(int s = 0; s < 4; s++){
        bf16x8 bf = *(const bf16x8*)&packQ[((s*128 + n)*4 + q4)*8];
        acc[nt] = __builtin_amdgcn_mfma_f32_16x16x32_bf16(af[s], bf, acc[nt], 0,0,0);
      }
    }
    float s1[4], s2[4];
    #pragma unroll
    for(int r = 0; r < 4; r++){ s1[r]=0.f; s2[r]=0.f; }
    #pragma unroll
    for(int nt = 0; nt < 2; nt++){
      const float cb2 = P.qkv_b[(wave*2+nt)*16 + l15];
      #pragma unroll
      for(int r = 0; r < 4; r++){
        const float vv = acc[nt][r] + cb2;
        acc[nt][r] = vv; s1[r] += vv; s2[r] += vv*vv;
      }
    }
    rowred4(s1, s2, red, wave, lane);
    short tw[2][4];
    {
      float mu[4], rs[4];
      #pragma unroll
      for(int r = 0; r < 4; r++){
        mu[r] = s1[r]*(1.f/128.f);
        rs[r] = rsqrtf(s2[r]*(1.f/128.f) - mu[r]*mu[r] + 1e-6f);
      }
      #pragma unroll
      for(int nt = 0; nt < 2; nt++){
        const int col = (wave*2+nt)*16 + l15;
        const float g = P.qg[col], be = P.qb[col];
        #pragma unroll
        for(int r = 0; r < 4; r++)
          tw[nt][r] = bfr((acc[nt][r]-mu[r])*rs[r]*g + be);
      }
    }
    __syncthreads();
    #pragma unroll
    for(int nt = 0; nt < 2; nt++){
      const int col = (wave*2+nt)*16 + l15;
      const int colp = col + (col >> 4);
      #pragma unroll
      for(int r = 0; r < 4; r++){
        const int cell = 2*(q4>>1) + ((r>>1)&1);
        const int lp   = 2*(q4&1) + (r&1);
        qnH[cell*544 + colp*4 + lp] = (ushort)tw[nt][r];
      }
    }
  }
  __syncthreads();

  // attention: wave w owns cell w, 2 head-groups, no inner barriers
  const int hsub = l15 >> 2, px = l15 & 3;
  const int par = q4 >> 1, dbase = (q4 & 1) * 8;
  BF* const attw = uni + wave*2304;
  ushort* const Vt = (ushort*)attw;            // [16][72]
  ushort* const Pb = (ushort*)(attw + 1152);   // [16][72]
  const ushort* cidx = cidx2 + wave*64;
  const ushort* qp = qnH + wave*544;
  const int ic = 2*ip + (wave>>1), jcc = 2*jq + (wave&1);
  const int i0 = l15 >> 3;
  const int rj = jcc + 2*(l15 & 7) - 8;
  const bool vj = (rj >= 0) && (rj < 64);
  float madd[4];
  #pragma unroll
  for(int nt = 0; nt < 4; nt++){
    const int ri = ic + 2*(nt*2 + i0) - 8;
    madd[nt] = (vj && ri >= 0 && ri < 64) ? 0.f : -1e30f;
  }

  f32x4 oC[2];
  #pragma unroll
  for(int hg = 0; hg < 2; hg++){
    bf16x8 afq0, afq1;
    {
      const int idx0 = (hg*64 + hsub*16 + dbase + (hg*4 + hsub))*4 + px;
      short bq[8];
      #pragma unroll
      for(int j = 0; j < 8; j++) bq[j] = (short)qp[idx0 + 4*j];
      const bool a0 = (par == hsub), a1 = ((2 + par) == hsub);
      #pragma unroll
      for(int j = 0; j < 8; j++){
        afq0[j] = a0 ? bq[j] : (short)0;
        afq1[j] = a1 ? bq[j] : (short)0;
      }
    }
    f32x4 accq[4];
    #pragma unroll
    for(int nt = 0; nt < 4; nt++){ accq[nt][0]=0.f; accq[nt][1]=0.f; accq[nt][2]=0.f; accq[nt][3]=0.f; }
    #pragma unroll
    for(int nt = 0; nt < 4; nt++){
      const float* kp = P.kcb + ((size_t)cidx[nt*16 + l15] << 7) + hg*64 + q4*8;
      const float4 k00 = *(const float4*)kp;
      const float4 k01 = *(const float4*)(kp + 4);
      const float4 k10 = *(const float4*)(kp + 32);
      const float4 k11 = *(const float4*)(kp + 36);
      accq[nt] = __builtin_amdgcn_mfma_f32_16x16x32_bf16(afq0, pk8(k00,k01), accq[nt], 0,0,0);
      accq[nt] = __builtin_amdgcn_mfma_f32_16x16x32_bf16(afq1, pk8(k10,k11), accq[nt], 0,0,0);
    }
    float inv[4];
    #pragma unroll
    for(int reg = 0; reg < 4; reg++){
      const float s0 = accq[0][reg]*0.25f + madd[0];
      const float s1 = accq[1][reg]*0.25f + madd[1];
      const float s2 = accq[2][reg]*0.25f + madd[2];
      const float s3 = accq[3][reg]*0.25f + madd[3];
      float m = fmaxf(fmaxf(s0,s1), fmaxf(s2,s3));
      #pragma unroll
      for(int sft = 1; sft < 16; sft <<= 1) m = fmaxf(m, __shfl_xor(m, sft));
      const float e0 = __expf(s0-m), e1 = __expf(s1-m);
      const float e2 = __expf(s2-m), e3 = __expf(s3-m);
      ushort* pr = Pb + (q4*4 + reg)*72 + l15;
      pr[0]  = (ushort)bfr(e0);
      pr[16] = (ushort)bfr(e1);
      pr[32] = (ushort)bfr(e2);
      pr[48] = (ushort)bfr(e3);
      float es = e0+e1+e2+e3;
      #pragma unroll
      for(int sft = 1; sft < 16; sft <<= 1) es += __shfl_xor(es, sft);
      inv[reg] = 1.f/es;
    }
    const bf16x8 pa0 = *(const bf16x8*)(Pb + l15*72 + q4*8);
    const bf16x8 pa1 = *(const bf16x8*)(Pb + l15*72 + 32 + q4*8);

    f32x4 oSel; oSel[0]=0.f; oSel[1]=0.f; oSel[2]=0.f; oSel[3]=0.f;
    #pragma unroll
    for(int hs = 0; hs < 4; hs++){
      const int h = hg*4 + hs;
      float4 vv[4];
      #pragma unroll
      for(int it = 0; it < 4; it++)
        vv[it] = *(const float4*)(P.vcb + ((size_t)cidx[l15*4 + it] << 7) + h*16 + q4*4);
      #pragma unroll
      for(int dd = 0; dd < 4; dd++){
        us4 w;
        w[0] = (unsigned short)bfr(((const float*)&vv[0])[dd]);
        w[1] = (unsigned short)bfr(((const float*)&vv[1])[dd]);
        w[2] = (unsigned short)bfr(((const float*)&vv[2])[dd]);
        w[3] = (unsigned short)bfr(((const float*)&vv[3])[dd]);
        *(us4*)(Vt + (q4*4 + dd)*72 + l15*4) = w;
      }
      const bf16x8 bv0 = *(const bf16x8*)(Vt + l15*72 + q4*8);
      const bf16x8 bv1 = *(const bf16x8*)(Vt + l15*72 + 32 + q4*8);
      f32x4 accv; accv[0]=0.f; accv[1]=0.f; accv[2]=0.f; accv[3]=0.f;
      accv = __builtin_amdgcn_mfma_f32_16x16x32_bf16(pa0, bv0, accv, 0,0,0);
      accv = __builtin_amdgcn_mfma_f32_16x16x32_bf16(pa1, bv1, accv, 0,0,0);
      if(q4 == hs){ oSel[0]=accv[0]; oSel[1]=accv[1]; oSel[2]=accv[2]; oSel[3]=accv[3]; }
    }
    oC[hg][0] = oSel[0]*inv[0]; oC[hg][1] = oSel[1]*inv[1];
    oC[hg][2] = oSel[2]*inv[2]; oC[hg][3] = oSel[3]*inv[3];
  }
  __syncthreads();
  {
    ushort* ab = (ushort*)Abuf;
    #pragma unroll
    for(int hg = 0; hg < 2; hg++){
      const int col = (hg*4 + q4)*16 + l15;
      #pragma unroll
      for(int reg = 0; reg < 4; reg++){
        const int row_p = 8*(wave>>1) + 4*(reg>>1) + 2*(wave&1) + (reg&1);
        ab[row_p*ASTR + col] = (ushort)bfr(oC[hg][reg]);
      }
    }
  }
  __syncthreads();

  // proj GEMM + ls1*res -> xh, LN2 -> Abuf
  float xh[2][4];
  {
    bf16x8 af[4];
    #pragma unroll
    for(int s = 0; s < 4; s++) af[s] = *(const bf16x8*)&Abuf[l15*ASTR + s*32 + q4*8];
    f32x4 acc[2];
    #pragma unroll
    for(int nt = 0; nt < 2; nt++){ acc[nt][0]=0.f; acc[nt][1]=0.f; acc[nt][2]=0.f; acc[nt][3]=0.f; }
    #pragma unroll
    for(int nt = 0; nt < 2; nt++){
      const int n = (wave*2+nt)*16 + l15;
      #pragma unroll
      for(int s = 0; s < 4; s++){
        bf16x8 bf = *(const bf16x8*)&packP[((s*128 + n)*4 + q4)*8];
        acc[nt] = __builtin_amdgcn_mfma_f32_16x16x32_bf16(af[s], bf, acc[nt], 0,0,0);
      }
    }
    float s1[4], s2[4];
    #pragma unroll
    for(int r = 0; r < 4; r++){ s1[r]=0.f; s2[r]=0.f; }
    #pragma unroll
    for(int nt = 0; nt < 2; nt++){
      const int col = (wave*2+nt)*16 + l15;
      const float bp = P.proj_b[col], l1 = P.ls1[col];
      #pragma unroll
      for(int r = 0; r < 4; r++){
        const int p = q4*4 + r;
        const float hx = xvL[p*128 + col] + l1*(acc[nt][r] + bp);
        xh[nt][r] = hx; s1[r] += hx; s2[r] += hx*hx;
      }
    }
    rowred4(s1, s2, red, wave, lane);
    #pragma unroll
    for(int nt = 0; nt < 2; nt++){
      const int col = (wave*2+nt)*16 + l15;
      const float g2 = P.n2g[col], be = P.n2b[col];
      #pragma unroll
      for(int r = 0; r < 4; r++){
        const int p = q4*4 + r;
        const float mu = s1[r]*(1.f/128.f);
        const float var = s2[r]*(1.f/128.f) - mu*mu;
        Abuf[p*ASTR + col] =
          __float2bfloat16((xh[nt][r]-mu)*rsqrtf(var+1e-6f)*g2 + be);
      }
    }
  }
  __syncthreads();

  // fc1 GEMM (N=176) + midLN + gelu -> Abuf
  {
    bf16x8 af[4];
    #pragma unroll
    for(int s = 0; s < 4; s++) af[s] = *(const bf16x8*)&Abuf[l15*ASTR + s*32 + q4*8];
    const int NT1 = (wave < 3) ? 3 : 2;
    const int tb  = (wave < 3) ? wave*3 : 9;
    f32x4 acc1[3];
    #pragma unroll
    for(int nt = 0; nt < 3; nt++){ acc1[nt][0]=0.f; acc1[nt][1]=0.f; acc1[nt][2]=0.f; acc1[nt][3]=0.f; }
    for(int nt = 0; nt < NT1; nt++){
      const int n = (tb + nt)*16 + l15;
      #pragma unroll
      for(int s = 0; s < 4; s++){
        bf16x8 bf = *(const bf16x8*)&packF1[((s*176 + n)*4 + q4)*8];
        acc1[nt] = __builtin_amdgcn_mfma_f32_16x16x32_bf16(af[s], bf, acc1[nt], 0,0,0);
      }
    }
    float s1[4], s2[4];
    #pragma unroll
    for(int r = 0; r < 4; r++){ s1[r]=0.f; s2[r]=0.f; }
    for(int nt = 0; nt < NT1; nt++){
      const int col = (tb + nt)*16 + l15;
      const float b1 = (col < 170) ? P.fc1_b[col] : 0.f;
      #pragma unroll
      for(int r = 0; r < 4; r++){
        const float vv = acc1[nt][r] + b1;
        acc1[nt][r] = vv; s1[r] += vv; s2[r] += vv*vv;
      }
    }
    rowred4(s1, s2, red, wave, lane);
    for(int z = tid; z < 352; z += 256){
      const int row = z / 22, colz = 170 + (z - (z/22)*22);
      Abuf[row*ASTR + colz] = __float2bfloat16(0.f);
    }
    const float kA = 0.7978845608028654f, kB = 0.044715f;
    for(int nt = 0; nt < NT1; nt++){
      const int col = (tb + nt)*16 + l15;
      if(col < 170){
        const float g2 = P.mg[col], be = P.mb[col];
        #pragma unroll
        for(int r = 0; r < 4; r++){
          const int p = q4*4 + r;
          const float mu = s1[r]*(1.f/170.f);
          const float var = s2[r]*(1.f/170.f) - mu*mu;
          const float hn = (acc1[nt][r]-mu)*rsqrtf(var+1e-6f)*g2 + be;
          const float u2 = kA*(hn + kB*hn*hn*hn);
          const float gl = hn / (1.f + __expf(-2.f*u2));
          Abuf[p*ASTR + col] = __float2bfloat16(gl);
        }
      }
    }
  }
  __syncthreads();

  // fc2 GEMM (K=192) + ls2*res -> out (B,C,H,W) directly (aligned float4)
  {
    bf16x8 af[6];
    #pragma unroll
    for(int s = 0; s < 6; s++) af[s] = *(const bf16x8*)&Abuf[l15*ASTR + s*32 + q4*8];
    f32x4 acc[2];
    #pragma unroll
    for(int nt = 0; nt < 2; nt++){ acc[nt][0]=0.f; acc[nt][1]=0.f; acc[nt][2]=0.f; acc[nt][3]=0.f; }
    #pragma unroll
    for(int nt = 0; nt < 2; nt++){
      const int n = (wave*2+nt)*16 + l15;
      #pragma unroll
      for(int s = 0; s < 6; s++){
        bf16x8 bf = *(const bf16x8*)&packF2[((s*128 + n)*4 + q4)*8];
        acc[nt] = __builtin_amdgcn_mfma_f32_16x16x32_bf16(af[s], bf, acc[nt], 0,0,0);
      }
    }
    #pragma unroll
    for(int nt = 0; nt < 2; nt++){
      const int col = (wave*2+nt)*16 + l15;
      const float bf2 = P.fc2_b[col], l2 = P.ls2[col];
      float4 o4;
      o4.x = xh[nt][0] + l2*(acc[nt][0] + bf2);
      o4.y = xh[nt][1] + l2*(acc[nt][1] + bf2);
      o4.z = xh[nt][2] + l2*(acc[nt][2] + bf2);
      o4.w = xh[nt][3] + l2*(acc[nt][3] + bf2);
      *(float4*)(P.out + (size_t)(b*128 + col)*16384 + (size_t)(4*ip + q4)*128 + 4*jq) = o4;
    }
  }
}

// ---- fused cooperative kernel: 1280 blocks, Phase A -> grid.sync -> Phase B ----
__global__ void __launch_bounds__(256, 5)
k_fused(KP P){
  __shared__ __align__(16) BF uni[9216];
  __shared__ float xvL[2048];
  __shared__ __align__(16) ushort qnH[2176];
  __shared__ ushort cidx2[256];

  pre_work(P, uni, (float*)qnH);
  __threadfence();
  cg::this_grid().sync();

  const int bid = blockIdx.x;
  #pragma unroll 1
  for(int r = 0; r < 2; ++r){
    const int u = bid + r*1280;
    if(u < 2048) cell_unit(P, u, uni, xvL, qnH, cidx2);
  }
}

// ---- fallback: identical code as two plain kernels ----
__global__ void __launch_bounds__(256)
k_preFB(KP P){
  __shared__ __align__(16) BF uni[9216];
  __shared__ __align__(16) ushort qnH[2176];
  pre_work(P, uni, (float*)qnH);
}

__global__ void __launch_bounds__(256, 5)
k_cellFB(KP P){
  __shared__ __align__(16) BF uni[9216];
  __shared__ float xvL[2048];
  __shared__ __align__(16) ushort qnH[2176];
  __shared__ ushort cidx2[256];
  cell_unit(P, blockIdx.x, uni, xvL, qnH, cidx2);
}

extern "C" void kernel_launch(void* const* d_in, const int* in_sizes, int n_in,
                              void* d_out, int out_size, void* d_ws, size_t ws_size,
                              hipStream_t stream){
  float* ws = (float*)d_ws;
  KP p;
  p.x      = (const float*)d_in[0];
  p.qkv_w  = (const float*)d_in[1];
  p.qkv_b  = (const float*)d_in[2];
  p.qg     = (const float*)d_in[3];
  p.qb     = (const float*)d_in[4];
  p.kg     = (const float*)d_in[5];
  p.kb     = (const float*)d_in[6];
  p.proj_w = (const float*)d_in[7];
  p.proj_b = (const float*)d_in[8];
  p.n1g    = (const float*)d_in[9];
  p.n1b    = (const float*)d_in[10];
  p.n2g    = (const float*)d_in[11];
  p.n2b    = (const float*)d_in[12];
  p.ls1    = (const float*)d_in[13];
  p.ls2    = (const float*)d_in[14];
  p.fc1_w  = (const float*)d_in[15];
  p.fc1_b  = (const float*)d_in[16];
  p.mg     = (const float*)d_in[17];
  p.mb     = (const float*)d_in[18];
  p.fc2_w  = (const float*)d_in[19];
  p.fc2_b  = (const float*)d_in[20];
  p.xt  = ws;
  p.kcb = ws + 4194304;
  p.vcb = ws + 5242880;
  p.pk  = (BF*)(ws + 6291456);
  p.out = (float*)d_out;

  void* args[] = {(void*)&p};
  hipError_t err = hipLaunchCooperativeKernel(
      reinterpret_cast<const void*>(&k_fused),
      dim3(1280), dim3(256), args, 0, stream);
  if(err != hipSuccess){
    (void)hipGetLastError();                   // clear sticky error
    k_preFB <<<1280, 256, 0, stream>>>(p);
    k_cellFB<<<2048, 256, 0, stream>>>(p);
  }
}

// Round 8
// 233.691 us; speedup vs baseline: 2.4838x; 2.4838x over previous
//
#include <hip/hip_runtime.h>
#include <hip/hip_bf16.h>

typedef __hip_bfloat16 BF;
typedef __attribute__((ext_vector_type(8))) short bf16x8;
typedef __attribute__((ext_vector_type(4))) float f32x4;
typedef __attribute__((ext_vector_type(4))) unsigned short us4;

// B=2, C=128, H=W=128, K=8, STRIDE=2, DIL=2, NH=8, dh=16, HID=170, Hc=Wc=64
// fp32 in / fp32 out. MFMA (bf16, fp32 acc) everywhere.
// NO transpose / xt buffer: k_cell reads x and writes out directly in
// (B,C,H,W); each thread touches aligned float4s and the XCD swizzle keeps
// line-sharing blocks on one XCD (verified on the write side in R6).
// ws (floats): kcb[0,1048576) vcb[+1048576) ; packs (bf16) at 2097152.
// NOTE (R7 lesson): cooperative grid.sync on gfx950 de-caches L2 (FETCH/WRITE
// grew 10x) -- do not fuse across a coop sync on this chip.

#define ASTR 200   // k_cell Abuf row stride (bf16)
#define KSTR 136   // k_pre(kv) Abuf row stride (bf16)

__device__ __forceinline__ short bfr(float f){
  union{float f; unsigned u;} c; c.f = f;
  const unsigned u = c.u + 0x7FFFu + ((c.u >> 16) & 1u);
  return (short)(u >> 16);
}
__device__ __forceinline__ bf16x8 pk8(float4 a, float4 b){
  bf16x8 r;
  r[0]=bfr(a.x); r[1]=bfr(a.y); r[2]=bfr(a.z); r[3]=bfr(a.w);
  r[4]=bfr(b.x); r[5]=bfr(b.y); r[6]=bfr(b.z); r[7]=bfr(b.w);
  return r;
}

// sum-reduce 16 vals across a 128-thr half (2 waves) of a 256-thr block
__device__ __forceinline__ void gsum16h(float v[16], float* red, int tid){
  #pragma unroll
  for(int s = 1; s < 64; s <<= 1){
    #pragma unroll
    for(int i = 0; i < 16; i++) v[i] += __shfl_xor(v[i], s);
  }
  const int wid = tid >> 6, half = tid >> 7;
  __syncthreads();
  if((tid & 63) == 0){
    #pragma unroll
    for(int i = 0; i < 16; i++) red[wid*16 + i] = v[i];
  }
  __syncthreads();
  #pragma unroll
  for(int i = 0; i < 16; i++) v[i] = red[half*32 + i] + red[half*32 + 16 + i];
}

// per-half row-stat reduction (k_pre kv)
__device__ __forceinline__ void rowredh(float s1[4], float s2[4], float* red, int tid){
  const int lane = tid & 63, wid = tid >> 6, half = tid >> 7;
  #pragma unroll
  for(int m = 1; m < 16; m <<= 1){
    #pragma unroll
    for(int r = 0; r < 4; r++){ s1[r] += __shfl_xor(s1[r], m); s2[r] += __shfl_xor(s2[r], m); }
  }
  const int q4 = lane >> 4;
  __syncthreads();
  if((lane & 15) == 0){
    #pragma unroll
    for(int r = 0; r < 4; r++){
      red[wid*32 + q4*4 + r]      = s1[r];
      red[wid*32 + 16 + q4*4 + r] = s2[r];
    }
  }
  __syncthreads();
  #pragma unroll
  for(int r = 0; r < 4; r++){
    s1[r] = red[half*64 + q4*4 + r]      + red[half*64 + 32 + q4*4 + r];
    s2[r] = red[half*64 + 16 + q4*4 + r] + red[half*64 + 48 + q4*4 + r];
  }
}

// 4-wave row-stat reduction (k_cell): rows 0..15 = px, stats over 128 cols
__device__ __forceinline__ void rowred4(float s1[4], float s2[4], float* red,
                                        int wave, int lane){
  #pragma unroll
  for(int m = 1; m < 16; m <<= 1){
    #pragma unroll
    for(int r = 0; r < 4; r++){ s1[r] += __shfl_xor(s1[r], m); s2[r] += __shfl_xor(s2[r], m); }
  }
  const int q4 = lane >> 4;
  __syncthreads();
  if((lane & 15) == 0){
    #pragma unroll
    for(int r = 0; r < 4; r++){
      red[wave*32 + q4*4 + r]      = s1[r];
      red[wave*32 + 16 + q4*4 + r] = s2[r];
    }
  }
  __syncthreads();
  #pragma unroll
  for(int r = 0; r < 4; r++){
    s1[r] = red[q4*4 + r] + red[32 + q4*4 + r] + red[64 + q4*4 + r] + red[96 + q4*4 + r];
    s2[r] = red[16 + q4*4 + r] + red[48 + q4*4 + r] + red[80 + q4*4 + r] + red[112 + q4*4 + r];
  }
}

// ---- K_pre: {coarse k,v (blocks 0..511) | weight pack (512..951)} ----
// kv reads x and qkv_w directly; no transpose section anymore.
__global__ void __launch_bounds__(256)
k_pre(const float* __restrict__ x,
      const float* __restrict__ qkv_w, const float* __restrict__ proj_w,
      const float* __restrict__ fc1_w, const float* __restrict__ fc2_w,
      const float* __restrict__ qkv_b,
      const float* __restrict__ kg, const float* __restrict__ kb,
      const float* __restrict__ n1g, const float* __restrict__ n1b,
      BF* __restrict__ pk,
      float* __restrict__ kcb, float* __restrict__ vcb){
  __shared__ __align__(16) unsigned char sm[9216];
  const int bx = blockIdx.x, tid = threadIdx.x;

  if(bx >= 512){                       // ---- weight pack (consumed by k_cell)
    const int idx = (bx - 512) * 256 + tid;
    if(idx >= 112640) return;
    float val;
    if(idx < 49152){
      const int reg = idx >> 14, l = idx & 16383;
      const int j = l & 7, q = (l>>3)&3, n = (l>>5)&127, s = l>>12;
      val = qkv_w[(reg*128 + n)*128 + (s*32 + q*8 + j)];
    } else if(idx < 65536){
      const int l = idx - 49152;
      const int j = l&7, q=(l>>3)&3, n=(l>>5)&127, s=l>>12;
      val = proj_w[n*128 + (s*32+q*8+j)];
    } else if(idx < 88064){
      const int l = idx - 65536;
      const int j = l&7, q=(l>>3)&3, rem = l>>5;
      const int n = rem % 176, s = rem / 176;
      const int k = s*32+q*8+j;
      val = (n < 170) ? fc1_w[n*128 + k] : 0.f;
    } else {
      const int l = idx - 88064;
      const int j = l&7, q=(l>>3)&3, n=(l>>5)&127, s=l>>12;
      const int k = s*32+q*8+j;
      val = (k < 170) ? fc2_w[n*170 + k] : 0.f;
    }
    pk[idx] = __float2bfloat16(val);
    return;
  }

  // ---- kv: 16 coarse px/block, two independent 128-thr halves ----
  BF* const Abuf = (BF*)sm;                    // 2 halves x [16][KSTR]
  float* const red = (float*)(sm + 8704);      // 128 floats
  const int lane = tid & 63, half = tid >> 7, wh = (tid >> 6) & 1, c = tid & 127;
  const int l15 = lane & 15, q4 = lane >> 4;
  const int cp0 = bx * 16;
  const int b = cp0 >> 12, ic = (cp0 & 4095) >> 6, jb = cp0 & 63;
  BF* const AbufH = Abuf + half*16*KSTR;

  float xv[8];
  {
    const size_t off = (size_t)(b*128 + c)*16384 + (size_t)(2*ic)*128 + 2*(jb + half*8);
    const float4* xp4 = (const float4*)(x + off);
    const float4 f0 = xp4[0], f1 = xp4[1], f2 = xp4[2], f3 = xp4[3];
    xv[0]=f0.x; xv[1]=f0.z; xv[2]=f1.x; xv[3]=f1.z;
    xv[4]=f2.x; xv[5]=f2.z; xv[6]=f3.x; xv[7]=f3.z;
  }
  float st[16];
  #pragma unroll
  for(int r = 0; r < 8; r++){ st[r] = xv[r]; st[8+r] = xv[r]*xv[r]; }
  gsum16h(st, red, tid);
  {
    const float g = n1g[c], be = n1b[c];
    #pragma unroll
    for(int r = 0; r < 8; r++){
      const float mu = st[r]*(1.f/128.f);
      const float var = st[8+r]*(1.f/128.f) - mu*mu;
      AbufH[r*KSTR + c] = __float2bfloat16((xv[r]-mu)*rsqrtf(var+1e-6f)*g + be);
    }
  }
  __syncthreads();
  bf16x8 af[4];
  #pragma unroll
  for(int s = 0; s < 4; s++) af[s] = *(const bf16x8*)&AbufH[l15*KSTR + s*32 + q4*8];

  // ---- k GEMM (B-fragments straight from qkv_w, bf16-packed inline) ----
  f32x4 acc[4];
  #pragma unroll
  for(int nt = 0; nt < 4; nt++){ acc[nt][0]=0.f; acc[nt][1]=0.f; acc[nt][2]=0.f; acc[nt][3]=0.f; }
  #pragma unroll
  for(int nt = 0; nt < 4; nt++){
    const int n = (wh*4+nt)*16 + l15;
    #pragma unroll
    for(int s = 0; s < 4; s++){
      const float* wp = qkv_w + (size_t)(128 + n)*128 + s*32 + q4*8;
      acc[nt] = __builtin_amdgcn_mfma_f32_16x16x32_bf16(
        af[s], pk8(*(const float4*)wp, *(const float4*)(wp+4)), acc[nt], 0,0,0);
    }
  }
  float s1[4], s2[4];
  #pragma unroll
  for(int r = 0; r < 4; r++){ s1[r]=0.f; s2[r]=0.f; }
  #pragma unroll
  for(int nt = 0; nt < 4; nt++){
    const float colb = qkv_b[128 + (wh*4+nt)*16 + l15];
    #pragma unroll
    for(int r = 0; r < 4; r++){
      const float vv = acc[nt][r] + colb;
      acc[nt][r] = vv; s1[r] += vv; s2[r] += vv*vv;
    }
  }
  rowredh(s1, s2, red, tid);
  #pragma unroll
  for(int nt = 0; nt < 4; nt++){
    const int col = (wh*4+nt)*16 + l15;
    const float g = kg[col], be = kb[col];
    #pragma unroll
    for(int r = 0; r < 4; r++){
      const int row = q4*4 + r;
      if(row < 8){
        const float mu = s1[r]*(1.f/128.f);
        const float var = s2[r]*(1.f/128.f) - mu*mu;
        kcb[(size_t)(cp0 + half*8 + row)*128 + col] = (acc[nt][r]-mu)*rsqrtf(var+1e-6f)*g + be;
      }
    }
  }
  // ---- v GEMM ----
  #pragma unroll
  for(int nt = 0; nt < 4; nt++){ acc[nt][0]=0.f; acc[nt][1]=0.f; acc[nt][2]=0.f; acc[nt][3]=0.f; }
  #pragma unroll
  for(int nt = 0; nt < 4; nt++){
    const int n = (wh*4+nt)*16 + l15;
    #pragma unroll
    for(int s = 0; s < 4; s++){
      const float* wp = qkv_w + (size_t)(256 + n)*128 + s*32 + q4*8;
      acc[nt] = __builtin_amdgcn_mfma_f32_16x16x32_bf16(
        af[s], pk8(*(const float4*)wp, *(const float4*)(wp+4)), acc[nt], 0,0,0);
    }
  }
  #pragma unroll
  for(int nt = 0; nt < 4; nt++){
    const int col = (wh*4+nt)*16 + l15;
    const float bv = qkv_b[256 + col];
    #pragma unroll
    for(int r = 0; r < 4; r++){
      const int row = q4*4 + r;
      if(row < 8) vcb[(size_t)(cp0 + half*8 + row)*128 + col] = acc[nt][r] + bv;
    }
  }
}

// ---- K_cell: 256 thr / 16 px (4 cells, 4x4 spatial tile) / all-MFMA ----
// px p: h = 4ip + (p>>2), w = 4jq + (p&3); cell(p) = 2*(p>>3) + ((p>>1)&1);
// lp(p) = 2*((p>>2)&1) + (p&1). Wave w owns cell w for attention.
// In/out both directly in (B,C,H,W): thread (c,half) reads 2 aligned float4
// (rows 4ip+2*half, +1 at col 4jq); XCD swizzle keeps the 4 consecutive-jq
// blocks sharing each 64B line on one XCD.
__global__ void __launch_bounds__(256, 5)
k_cell(const float* __restrict__ x,
       const BF* __restrict__ packQ, const BF* __restrict__ packP,
       const BF* __restrict__ packF1, const BF* __restrict__ packF2,
       const float* __restrict__ qkv_b,
       const float* __restrict__ qg, const float* __restrict__ qb,
       const float* __restrict__ n1g, const float* __restrict__ n1b,
       const float* __restrict__ proj_b,
       const float* __restrict__ ls1, const float* __restrict__ ls2,
       const float* __restrict__ n2g, const float* __restrict__ n2b,
       const float* __restrict__ fc1_b,
       const float* __restrict__ mg, const float* __restrict__ mb,
       const float* __restrict__ fc2_b,
       const float* __restrict__ kcb, const float* __restrict__ vcb,
       float* __restrict__ out){
  __shared__ __align__(16) BF uni[9216];
  BF* const Abuf = uni;                        // [16][ASTR]
  __shared__ float xvL[2048];                  // [16px][128ch]
  __shared__ __align__(16) ushort qnH[2176];   // [4cell][136pad][4lp]
  __shared__ ushort cidx2[256];                // [4cell][64] safe coarse idx
  float* const red = (float*)qnH;              // 128 floats, disjoint live range
  const int tid = threadIdx.x, wave = tid>>6, lane = tid&63;
  const int l15 = lane & 15, q4 = lane >> 4;

  // XCD-aware swizzle (bijective: 2048 % 8 == 0, chunks of 256 per XCD)
  const int bx0 = blockIdx.x;
  const int bx = ((bx0 & 7) << 8) | (bx0 >> 3);
  const int b = bx >> 10, rem = bx & 1023, ip = rem >> 5, jq = rem & 31;
  const int c = tid & 127, half = tid >> 7;

  // direct (B,C,H,W) reads: 2 aligned float4 per thread
  float xv[8];
  {
    const size_t xb = (size_t)(b*128 + c)*16384 + (size_t)(4*ip + 2*half)*128 + 4*jq;
    const float4 r0 = *(const float4*)(x + xb);
    const float4 r1 = *(const float4*)(x + xb + 128);
    xv[0]=r0.x; xv[1]=r0.y; xv[2]=r0.z; xv[3]=r0.w;
    xv[4]=r1.x; xv[5]=r1.y; xv[6]=r1.z; xv[7]=r1.w;
    #pragma unroll
    for(int r = 0; r < 8; r++) xvL[(half*8 + r)*128 + c] = xv[r];
  }
  {                                            // neighbor indices, 4 cells
    const int cell = tid >> 6, e = tid & 63;
    const int i = e >> 3, j = e & 7;
    const int ic = 2*ip + (cell>>1), jcc = 2*jq + (cell&1);
    const int ri = ic + 2*i - 8, rj = jcc + 2*j - 8;
    const bool ok = (rj >= 0) && (rj < 64) && (ri >= 0) && (ri < 64);
    cidx2[cell*64 + e] = ok ? (ushort)(b*4096 + ri*64 + rj) : (ushort)0;
  }

  // ---- LN1 ----
  float st[16];
  #pragma unroll
  for(int r = 0; r < 8; r++){ st[r] = xv[r]; st[8+r] = xv[r]*xv[r]; }
  gsum16h(st, red, tid);
  {
    const float g = n1g[c], be = n1b[c];
    #pragma unroll
    for(int r = 0; r < 8; r++){
      const int p = half*8 + r;
      const float mu = st[r]*(1.f/128.f);
      const float var = st[8+r]*(1.f/128.f) - mu*mu;
      Abuf[p*ASTR + c] = __float2bfloat16((xv[r]-mu)*rsqrtf(var+1e-6f)*g + be);
    }
  }
  __syncthreads();

  // ---- q GEMM (M=16) + q-LN -> qnH ----
  {
    bf16x8 af[4];
    #pragma unroll
    for(int s = 0; s < 4; s++) af[s] = *(const bf16x8*)&Abuf[l15*ASTR + s*32 + q4*8];
    f32x4 acc[2];
    #pragma unroll
    for(int nt = 0; nt < 2; nt++){ acc[nt][0]=0.f; acc[nt][1]=0.f; acc[nt][2]=0.f; acc[nt][3]=0.f; }
    #pragma unroll
    for(int nt = 0; nt < 2; nt++){
      const int n = (wave*2+nt)*16 + l15;
      #pragma unroll
      for(int s = 0; s < 4; s++){
        bf16x8 bf = *(const bf16x8*)&packQ[((s*128 + n)*4 + q4)*8];
        acc[nt] = __builtin_amdgcn_mfma_f32_16x16x32_bf16(af[s], bf, acc[nt], 0,0,0);
      }
    }
    float s1[4], s2[4];
    #pragma unroll
    for(int r = 0; r < 4; r++){ s1[r]=0.f; s2[r]=0.f; }
    #pragma unroll
    for(int nt = 0; nt < 2; nt++){
      const float cb2 = qkv_b[(wave*2+nt)*16 + l15];
      #pragma unroll
      for(int r = 0; r < 4; r++){
        const float vv = acc[nt][r] + cb2;
        acc[nt][r] = vv; s1[r] += vv; s2[r] += vv*vv;
      }
    }
    rowred4(s1, s2, red, wave, lane);
    short tw[2][4];
    {
      float mu[4], rs[4];
      #pragma unroll
      for(int r = 0; r < 4; r++){
        mu[r] = s1[r]*(1.f/128.f);
        rs[r] = rsqrtf(s2[r]*(1.f/128.f) - mu[r]*mu[r] + 1e-6f);
      }
      #pragma unroll
      for(int nt = 0; nt < 2; nt++){
        const int col = (wave*2+nt)*16 + l15;
        const float g = qg[col], be = qb[col];
        #pragma unroll
        for(int r = 0; r < 4; r++)
          tw[nt][r] = bfr((acc[nt][r]-mu[r])*rs[r]*g + be);
      }
    }
    __syncthreads();            // red (aliased with qnH) fully consumed
    #pragma unroll
    for(int nt = 0; nt < 2; nt++){
      const int col = (wave*2+nt)*16 + l15;
      const int colp = col + (col >> 4);
      #pragma unroll
      for(int r = 0; r < 4; r++){
        const int cell = 2*(q4>>1) + ((r>>1)&1);
        const int lp   = 2*(q4&1) + (r&1);
        qnH[cell*544 + colp*4 + lp] = (ushort)tw[nt][r];
      }
    }
  }
  __syncthreads();

  // ---- attention: wave w owns cell w, 2 head-groups, no inner barriers ----
  const int hsub = l15 >> 2, px = l15 & 3;
  const int par = q4 >> 1, dbase = (q4 & 1) * 8;
  BF* const attw = uni + wave*2304;
  ushort* const Vt = (ushort*)attw;            // [16][72]
  ushort* const Pb = (ushort*)(attw + 1152);   // [16][72]
  const ushort* cidx = cidx2 + wave*64;
  const ushort* qp = qnH + wave*544;
  const int ic = 2*ip + (wave>>1), jcc = 2*jq + (wave&1);
  const int i0 = l15 >> 3;
  const int rj = jcc + 2*(l15 & 7) - 8;
  const bool vj = (rj >= 0) && (rj < 64);
  float madd[4];
  #pragma unroll
  for(int nt = 0; nt < 4; nt++){
    const int ri = ic + 2*(nt*2 + i0) - 8;
    madd[nt] = (vj && ri >= 0 && ri < 64) ? 0.f : -1e30f;
  }

  f32x4 oC[2];
  #pragma unroll
  for(int hg = 0; hg < 2; hg++){
    // block-diagonal q A-fragments
    bf16x8 afq0, afq1;
    {
      const int idx0 = (hg*64 + hsub*16 + dbase + (hg*4 + hsub))*4 + px;
      short bq[8];
      #pragma unroll
      for(int j = 0; j < 8; j++) bq[j] = (short)qp[idx0 + 4*j];
      const bool a0 = (par == hsub), a1 = ((2 + par) == hsub);
      #pragma unroll
      for(int j = 0; j < 8; j++){
        afq0[j] = a0 ? bq[j] : (short)0;
        afq1[j] = a1 ? bq[j] : (short)0;
      }
    }
    // QK: 8 MFMA
    f32x4 accq[4];
    #pragma unroll
    for(int nt = 0; nt < 4; nt++){ accq[nt][0]=0.f; accq[nt][1]=0.f; accq[nt][2]=0.f; accq[nt][3]=0.f; }
    #pragma unroll
    for(int nt = 0; nt < 4; nt++){
      const float* kp = kcb + ((size_t)cidx[nt*16 + l15] << 7) + hg*64 + q4*8;
      const float4 k00 = *(const float4*)kp;
      const float4 k01 = *(const float4*)(kp + 4);
      const float4 k10 = *(const float4*)(kp + 32);
      const float4 k11 = *(const float4*)(kp + 36);
      accq[nt] = __builtin_amdgcn_mfma_f32_16x16x32_bf16(afq0, pk8(k00,k01), accq[nt], 0,0,0);
      accq[nt] = __builtin_amdgcn_mfma_f32_16x16x32_bf16(afq1, pk8(k10,k11), accq[nt], 0,0,0);
    }
    // softmax in-register; unnormalized e (bf16) -> Pb
    float inv[4];
    #pragma unroll
    for(int reg = 0; reg < 4; reg++){
      const float s0 = accq[0][reg]*0.25f + madd[0];
      const float s1 = accq[1][reg]*0.25f + madd[1];
      const float s2 = accq[2][reg]*0.25f + madd[2];
      const float s3 = accq[3][reg]*0.25f + madd[3];
      float m = fmaxf(fmaxf(s0,s1), fmaxf(s2,s3));
      #pragma unroll
      for(int sft = 1; sft < 16; sft <<= 1) m = fmaxf(m, __shfl_xor(m, sft));
      const float e0 = __expf(s0-m), e1 = __expf(s1-m);
      const float e2 = __expf(s2-m), e3 = __expf(s3-m);
      ushort* pr = Pb + (q4*4 + reg)*72 + l15;
      pr[0]  = (ushort)bfr(e0);
      pr[16] = (ushort)bfr(e1);
      pr[32] = (ushort)bfr(e2);
      pr[48] = (ushort)bfr(e3);
      float es = e0+e1+e2+e3;
      #pragma unroll
      for(int sft = 1; sft < 16; sft <<= 1) es += __shfl_xor(es, sft);
      inv[reg] = 1.f/es;
    }
    const bf16x8 pa0 = *(const bf16x8*)(Pb + l15*72 + q4*8);
    const bf16x8 pa1 = *(const bf16x8*)(Pb + l15*72 + 32 + q4*8);

    // PV: per head stage V, 2 MFMA; keep own head's rows
    f32x4 oSel; oSel[0]=0.f; oSel[1]=0.f; oSel[2]=0.f; oSel[3]=0.f;
    #pragma unroll
    for(int hs = 0; hs < 4; hs++){
      const int h = hg*4 + hs;
      float4 vv[4];
      #pragma unroll
      for(int it = 0; it < 4; it++)
        vv[it] = *(const float4*)(vcb + ((size_t)cidx[l15*4 + it] << 7) + h*16 + q4*4);
      #pragma unroll
      for(int dd = 0; dd < 4; dd++){
        us4 w;
        w[0] = (unsigned short)bfr(((const float*)&vv[0])[dd]);
        w[1] = (unsigned short)bfr(((const float*)&vv[1])[dd]);
        w[2] = (unsigned short)bfr(((const float*)&vv[2])[dd]);
        w[3] = (unsigned short)bfr(((const float*)&vv[3])[dd]);
        *(us4*)(Vt + (q4*4 + dd)*72 + l15*4) = w;
      }
      const bf16x8 bv0 = *(const bf16x8*)(Vt + l15*72 + q4*8);
      const bf16x8 bv1 = *(const bf16x8*)(Vt + l15*72 + 32 + q4*8);
      f32x4 accv; accv[0]=0.f; accv[1]=0.f; accv[2]=0.f; accv[3]=0.f;
      accv = __builtin_amdgcn_mfma_f32_16x16x32_bf16(pa0, bv0, accv, 0,0,0);
      accv = __builtin_amdgcn_mfma_f32_16x16x32_bf16(pa1, bv1, accv, 0,0,0);
      if(q4 == hs){ oSel[0]=accv[0]; oSel[1]=accv[1]; oSel[2]=accv[2]; oSel[3]=accv[3]; }
    }
    oC[hg][0] = oSel[0]*inv[0]; oC[hg][1] = oSel[1]*inv[1];
    oC[hg][2] = oSel[2]*inv[2]; oC[hg][3] = oSel[3]*inv[3];
  }
  __syncthreads();
  // ao -> Abuf[px p][head*16 + d]
  {
    ushort* ab = (ushort*)Abuf;
    #pragma unroll
    for(int hg = 0; hg < 2; hg++){
      const int col = (hg*4 + q4)*16 + l15;
      #pragma unroll
      for(int reg = 0; reg < 4; reg++){
        const int row_p = 8*(wave>>1) + 4*(reg>>1) + 2*(wave&1) + (reg&1);
        ab[row_p*ASTR + col] = (ushort)bfr(oC[hg][reg]);
      }
    }
  }
  __syncthreads();

  // ---- proj GEMM + ls1*res -> xh, LN2 -> Abuf ----
  float xh[2][4];
  {
    bf16x8 af[4];
    #pragma unroll
    for(int s = 0; s < 4; s++) af[s] = *(const bf16x8*)&Abuf[l15*ASTR + s*32 + q4*8];
    f32x4 acc[2];
    #pragma unroll
    for(int nt = 0; nt < 2; nt++){ acc[nt][0]=0.f; acc[nt][1]=0.f; acc[nt][2]=0.f; acc[nt][3]=0.f; }
    #pragma unroll
    for(int nt = 0; nt < 2; nt++){
      const int n = (wave*2+nt)*16 + l15;
      #pragma unroll
      for(int s = 0; s < 4; s++){
        bf16x8 bf = *(const bf16x8*)&packP[((s*128 + n)*4 + q4)*8];
        acc[nt] = __builtin_amdgcn_mfma_f32_16x16x32_bf16(af[s], bf, acc[nt], 0,0,0);
      }
    }
    float s1[4], s2[4];
    #pragma unroll
    for(int r = 0; r < 4; r++){ s1[r]=0.f; s2[r]=0.f; }
    #pragma unroll
    for(int nt = 0; nt < 2; nt++){
      const int col = (wave*2+nt)*16 + l15;
      const float bp = proj_b[col], l1 = ls1[col];
      #pragma unroll
      for(int r = 0; r < 4; r++){
        const int p = q4*4 + r;
        const float hx = xvL[p*128 + col] + l1*(acc[nt][r] + bp);
        xh[nt][r] = hx; s1[r] += hx; s2[r] += hx*hx;
      }
    }
    rowred4(s1, s2, red, wave, lane);
    #pragma unroll
    for(int nt = 0; nt < 2; nt++){
      const int col = (wave*2+nt)*16 + l15;
      const float g2 = n2g[col], be = n2b[col];
      #pragma unroll
      for(int r = 0; r < 4; r++){
        const int p = q4*4 + r;
        const float mu = s1[r]*(1.f/128.f);
        const float var = s2[r]*(1.f/128.f) - mu*mu;
        Abuf[p*ASTR + col] =
          __float2bfloat16((xh[nt][r]-mu)*rsqrtf(var+1e-6f)*g2 + be);
      }
    }
  }
  __syncthreads();

  // ---- fc1 GEMM (N=176, tiles 3/3/3/2) + midLN + gelu -> Abuf ----
  {
    bf16x8 af[4];
    #pragma unroll
    for(int s = 0; s < 4; s++) af[s] = *(const bf16x8*)&Abuf[l15*ASTR + s*32 + q4*8];
    const int NT1 = (wave < 3) ? 3 : 2;
    const int tb  = (wave < 3) ? wave*3 : 9;
    f32x4 acc1[3];
    #pragma unroll
    for(int nt = 0; nt < 3; nt++){ acc1[nt][0]=0.f; acc1[nt][1]=0.f; acc1[nt][2]=0.f; acc1[nt][3]=0.f; }
    for(int nt = 0; nt < NT1; nt++){
      const int n = (tb + nt)*16 + l15;
      #pragma unroll
      for(int s = 0; s < 4; s++){
        bf16x8 bf = *(const bf16x8*)&packF1[((s*176 + n)*4 + q4)*8];
        acc1[nt] = __builtin_amdgcn_mfma_f32_16x16x32_bf16(af[s], bf, acc1[nt], 0,0,0);
      }
    }
    float s1[4], s2[4];
    #pragma unroll
    for(int r = 0; r < 4; r++){ s1[r]=0.f; s2[r]=0.f; }
    for(int nt = 0; nt < NT1; nt++){
      const int col = (tb + nt)*16 + l15;
      const float b1 = (col < 170) ? fc1_b[col] : 0.f;
      #pragma unroll
      for(int r = 0; r < 4; r++){
        const float vv = acc1[nt][r] + b1;
        acc1[nt][r] = vv; s1[r] += vv; s2[r] += vv*vv;
      }
    }
    rowred4(s1, s2, red, wave, lane);
    for(int z = tid; z < 352; z += 256){          // zero fc2 K-pad cols 170..191
      const int row = z / 22, colz = 170 + (z - (z/22)*22);
      Abuf[row*ASTR + colz] = __float2bfloat16(0.f);
    }
    const float kA = 0.7978845608028654f, kB = 0.044715f;
    for(int nt = 0; nt < NT1; nt++){
      const int col = (tb + nt)*16 + l15;
      if(col < 170){
        const float g2 = mg[col], be = mb[col];
        #pragma unroll
        for(int r = 0; r < 4; r++){
          const int p = q4*4 + r;
          const float mu = s1[r]*(1.f/170.f);
          const float var = s2[r]*(1.f/170.f) - mu*mu;
          const float hn = (acc1[nt][r]-mu)*rsqrtf(var+1e-6f)*g2 + be;
          const float u = kA*(hn + kB*hn*hn*hn);
          const float gl = hn / (1.f + __expf(-2.f*u));
          Abuf[p*ASTR + col] = __float2bfloat16(gl);
        }
      }
    }
  }
  __syncthreads();

  // ---- fc2 GEMM (K=192) + ls2*res -> out (B,C,H,W) directly ----
  // thread's 4 r-values = (col, h=4ip+q4, w=4jq..4jq+3): one aligned float4.
  {
    bf16x8 af[6];
    #pragma unroll
    for(int s = 0; s < 6; s++) af[s] = *(const bf16x8*)&Abuf[l15*ASTR + s*32 + q4*8];
    f32x4 acc[2];
    #pragma unroll
    for(int nt = 0; nt < 2; nt++){ acc[nt][0]=0.f; acc[nt][1]=0.f; acc[nt][2]=0.f; acc[nt][3]=0.f; }
    #pragma unroll
    for(int nt = 0; nt < 2; nt++){
      const int n = (wave*2+nt)*16 + l15;
      #pragma unroll
      for(int s = 0; s < 6; s++){
        bf16x8 bf = *(const bf16x8*)&packF2[((s*128 + n)*4 + q4)*8];
        acc[nt] = __builtin_amdgcn_mfma_f32_16x16x32_bf16(af[s], bf, acc[nt], 0,0,0);
      }
    }
    #pragma unroll
    for(int nt = 0; nt < 2; nt++){
      const int col = (wave*2+nt)*16 + l15;
      const float bf2 = fc2_b[col], l2 = ls2[col];
      float4 o4;
      o4.x = xh[nt][0] + l2*(acc[nt][0] + bf2);
      o4.y = xh[nt][1] + l2*(acc[nt][1] + bf2);
      o4.z = xh[nt][2] + l2*(acc[nt][2] + bf2);
      o4.w = xh[nt][3] + l2*(acc[nt][3] + bf2);
      *(float4*)(out + (size_t)(b*128 + col)*16384 + (size_t)(4*ip + q4)*128 + 4*jq) = o4;
    }
  }
}

extern "C" void kernel_launch(void* const* d_in, const int* in_sizes, int n_in,
                              void* d_out, int out_size, void* d_ws, size_t ws_size,
                              hipStream_t stream){
  const float* x      = (const float*)d_in[0];
  const float* qkv_w  = (const float*)d_in[1];
  const float* qkv_b  = (const float*)d_in[2];
  const float* qg     = (const float*)d_in[3];
  const float* qb     = (const float*)d_in[4];
  const float* kg     = (const float*)d_in[5];
  const float* kb     = (const float*)d_in[6];
  const float* proj_w = (const float*)d_in[7];
  const float* proj_b = (const float*)d_in[8];
  const float* n1g    = (const float*)d_in[9];
  const float* n1b    = (const float*)d_in[10];
  const float* n2g    = (const float*)d_in[11];
  const float* n2b    = (const float*)d_in[12];
  const float* ls1    = (const float*)d_in[13];
  const float* ls2    = (const float*)d_in[14];
  const float* fc1_w  = (const float*)d_in[15];
  const float* fc1_b  = (const float*)d_in[16];
  const float* mg     = (const float*)d_in[17];
  const float* mb     = (const float*)d_in[18];
  const float* fc2_w  = (const float*)d_in[19];
  const float* fc2_b  = (const float*)d_in[20];

  float* ws  = (float*)d_ws;
  float* kcb = ws;
  float* vcb = ws + 1048576;
  BF* pk     = (BF*)(ws + 2097152);
  BF* packQ  = pk;
  BF* packP  = pk + 49152;
  BF* packF1 = pk + 65536;
  BF* packF2 = pk + 88064;

  k_pre <<<952, 256, 0, stream>>>(x, qkv_w, proj_w, fc1_w, fc2_w, qkv_b,
                                  kg, kb, n1g, n1b, pk, kcb, vcb);
  k_cell<<<2048, 256, 0, stream>>>(x, packQ, packP, packF1, packF2,
                                   qkv_b, qg, qb, n1g, n1b, proj_b, ls1, ls2,
                                   n2g, n2b, fc1_b, mg, mb, fc2_b,
                                   kcb, vcb, (float*)d_out);
}

// Round 9
// 230.893 us; speedup vs baseline: 2.5139x; 1.0121x over previous
//
#include <hip/hip_runtime.h>
#include <hip/hip_bf16.h>

typedef __hip_bfloat16 BF;
typedef __attribute__((ext_vector_type(8))) short bf16x8;
typedef __attribute__((ext_vector_type(4))) float f32x4;
typedef __attribute__((ext_vector_type(4))) unsigned short us4;

// B=2, C=128, H=W=128, K=8, STRIDE=2, DIL=2, NH=8, dh=16, HID=170, Hc=Wc=64
// fp32 in / fp32 out. MFMA (bf16, fp32 acc) everywhere.
// R8 structure frozen (233.7us); this round: all hot-path f32->bf16
// conversions via v_cvt_pk_bf16_f32 (RNE, bit-identical to old bfr path).
// ws (floats): kcb[0,1048576) vcb[+1048576) ; packs (bf16) at 2097152.
// NOTE (R7 lesson): cooperative grid.sync on gfx950 de-caches L2 -- never
// fuse across a coop sync on this chip.

#define ASTR 200   // k_cell Abuf row stride (bf16)
#define KSTR 136   // k_pre(kv) Abuf row stride (bf16)

// 2x f32 -> packed bf16 (RNE) in one instruction
__device__ __forceinline__ unsigned cvt2(float lo, float hi){
  unsigned r;
  asm("v_cvt_pk_bf16_f32 %0, %1, %2" : "=v"(r) : "v"(lo), "v"(hi));
  return r;
}
__device__ __forceinline__ bf16x8 pk8(float4 a, float4 b){
  union{ unsigned u[4]; bf16x8 v; } c;
  c.u[0] = cvt2(a.x, a.y); c.u[1] = cvt2(a.z, a.w);
  c.u[2] = cvt2(b.x, b.y); c.u[3] = cvt2(b.z, b.w);
  return c.v;
}

// sum-reduce 16 vals across a 128-thr half (2 waves) of a 256-thr block
__device__ __forceinline__ void gsum16h(float v[16], float* red, int tid){
  #pragma unroll
  for(int s = 1; s < 64; s <<= 1){
    #pragma unroll
    for(int i = 0; i < 16; i++) v[i] += __shfl_xor(v[i], s);
  }
  const int wid = tid >> 6, half = tid >> 7;
  __syncthreads();
  if((tid & 63) == 0){
    #pragma unroll
    for(int i = 0; i < 16; i++) red[wid*16 + i] = v[i];
  }
  __syncthreads();
  #pragma unroll
  for(int i = 0; i < 16; i++) v[i] = red[half*32 + i] + red[half*32 + 16 + i];
}

// per-half row-stat reduction (k_pre kv)
__device__ __forceinline__ void rowredh(float s1[4], float s2[4], float* red, int tid){
  const int lane = tid & 63, wid = tid >> 6, half = tid >> 7;
  #pragma unroll
  for(int m = 1; m < 16; m <<= 1){
    #pragma unroll
    for(int r = 0; r < 4; r++){ s1[r] += __shfl_xor(s1[r], m); s2[r] += __shfl_xor(s2[r], m); }
  }
  const int q4 = lane >> 4;
  __syncthreads();
  if((lane & 15) == 0){
    #pragma unroll
    for(int r = 0; r < 4; r++){
      red[wid*32 + q4*4 + r]      = s1[r];
      red[wid*32 + 16 + q4*4 + r] = s2[r];
    }
  }
  __syncthreads();
  #pragma unroll
  for(int r = 0; r < 4; r++){
    s1[r] = red[half*64 + q4*4 + r]      + red[half*64 + 32 + q4*4 + r];
    s2[r] = red[half*64 + 16 + q4*4 + r] + red[half*64 + 48 + q4*4 + r];
  }
}

// 4-wave row-stat reduction (k_cell): rows 0..15 = px, stats over 128 cols
__device__ __forceinline__ void rowred4(float s1[4], float s2[4], float* red,
                                        int wave, int lane){
  #pragma unroll
  for(int m = 1; m < 16; m <<= 1){
    #pragma unroll
    for(int r = 0; r < 4; r++){ s1[r] += __shfl_xor(s1[r], m); s2[r] += __shfl_xor(s2[r], m); }
  }
  const int q4 = lane >> 4;
  __syncthreads();
  if((lane & 15) == 0){
    #pragma unroll
    for(int r = 0; r < 4; r++){
      red[wave*32 + q4*4 + r]      = s1[r];
      red[wave*32 + 16 + q4*4 + r] = s2[r];
    }
  }
  __syncthreads();
  #pragma unroll
  for(int r = 0; r < 4; r++){
    s1[r] = red[q4*4 + r] + red[32 + q4*4 + r] + red[64 + q4*4 + r] + red[96 + q4*4 + r];
    s2[r] = red[16 + q4*4 + r] + red[48 + q4*4 + r] + red[80 + q4*4 + r] + red[112 + q4*4 + r];
  }
}

// ---- K_pre: {coarse k,v (blocks 0..511) | weight pack (512..951)} ----
__global__ void __launch_bounds__(256)
k_pre(const float* __restrict__ x,
      const float* __restrict__ qkv_w, const float* __restrict__ proj_w,
      const float* __restrict__ fc1_w, const float* __restrict__ fc2_w,
      const float* __restrict__ qkv_b,
      const float* __restrict__ kg, const float* __restrict__ kb,
      const float* __restrict__ n1g, const float* __restrict__ n1b,
      BF* __restrict__ pk,
      float* __restrict__ kcb, float* __restrict__ vcb){
  __shared__ __align__(16) unsigned char sm[9216];
  const int bx = blockIdx.x, tid = threadIdx.x;

  if(bx >= 512){                       // ---- weight pack (consumed by k_cell)
    const int idx = (bx - 512) * 256 + tid;
    if(idx >= 112640) return;
    float val;
    if(idx < 49152){
      const int reg = idx >> 14, l = idx & 16383;
      const int j = l & 7, q = (l>>3)&3, n = (l>>5)&127, s = l>>12;
      val = qkv_w[(reg*128 + n)*128 + (s*32 + q*8 + j)];
    } else if(idx < 65536){
      const int l = idx - 49152;
      const int j = l&7, q=(l>>3)&3, n=(l>>5)&127, s=l>>12;
      val = proj_w[n*128 + (s*32+q*8+j)];
    } else if(idx < 88064){
      const int l = idx - 65536;
      const int j = l&7, q=(l>>3)&3, rem = l>>5;
      const int n = rem % 176, s = rem / 176;
      const int k = s*32+q*8+j;
      val = (n < 170) ? fc1_w[n*128 + k] : 0.f;
    } else {
      const int l = idx - 88064;
      const int j = l&7, q=(l>>3)&3, n=(l>>5)&127, s=l>>12;
      const int k = s*32+q*8+j;
      val = (k < 170) ? fc2_w[n*170 + k] : 0.f;
    }
    pk[idx] = __float2bfloat16(val);
    return;
  }

  // ---- kv: 16 coarse px/block, two independent 128-thr halves ----
  BF* const Abuf = (BF*)sm;                    // 2 halves x [16][KSTR]
  float* const red = (float*)(sm + 8704);      // 128 floats
  const int lane = tid & 63, half = tid >> 7, wh = (tid >> 6) & 1, c = tid & 127;
  const int l15 = lane & 15, q4 = lane >> 4;
  const int cp0 = bx * 16;
  const int b = cp0 >> 12, ic = (cp0 & 4095) >> 6, jb = cp0 & 63;
  BF* const AbufH = Abuf + half*16*KSTR;

  float xv[8];
  {
    const size_t off = (size_t)(b*128 + c)*16384 + (size_t)(2*ic)*128 + 2*(jb + half*8);
    const float4* xp4 = (const float4*)(x + off);
    const float4 f0 = xp4[0], f1 = xp4[1], f2 = xp4[2], f3 = xp4[3];
    xv[0]=f0.x; xv[1]=f0.z; xv[2]=f1.x; xv[3]=f1.z;
    xv[4]=f2.x; xv[5]=f2.z; xv[6]=f3.x; xv[7]=f3.z;
  }
  float st[16];
  #pragma unroll
  for(int r = 0; r < 8; r++){ st[r] = xv[r]; st[8+r] = xv[r]*xv[r]; }
  gsum16h(st, red, tid);
  {
    const float g = n1g[c], be = n1b[c];
    #pragma unroll
    for(int r = 0; r < 8; r++){
      const float mu = st[r]*(1.f/128.f);
      const float var = st[8+r]*(1.f/128.f) - mu*mu;
      AbufH[r*KSTR + c] = __float2bfloat16((xv[r]-mu)*rsqrtf(var+1e-6f)*g + be);
    }
  }
  __syncthreads();
  bf16x8 af[4];
  #pragma unroll
  for(int s = 0; s < 4; s++) af[s] = *(const bf16x8*)&AbufH[l15*KSTR + s*32 + q4*8];

  // ---- k GEMM (B-fragments straight from qkv_w, cvt_pk inline) ----
  f32x4 acc[4];
  #pragma unroll
  for(int nt = 0; nt < 4; nt++){ acc[nt][0]=0.f; acc[nt][1]=0.f; acc[nt][2]=0.f; acc[nt][3]=0.f; }
  #pragma unroll
  for(int nt = 0; nt < 4; nt++){
    const int n = (wh*4+nt)*16 + l15;
    #pragma unroll
    for(int s = 0; s < 4; s++){
      const float* wp = qkv_w + (size_t)(128 + n)*128 + s*32 + q4*8;
      acc[nt] = __builtin_amdgcn_mfma_f32_16x16x32_bf16(
        af[s], pk8(*(const float4*)wp, *(const float4*)(wp+4)), acc[nt], 0,0,0);
    }
  }
  float s1[4], s2[4];
  #pragma unroll
  for(int r = 0; r < 4; r++){ s1[r]=0.f; s2[r]=0.f; }
  #pragma unroll
  for(int nt = 0; nt < 4; nt++){
    const float colb = qkv_b[128 + (wh*4+nt)*16 + l15];
    #pragma unroll
    for(int r = 0; r < 4; r++){
      const float vv = acc[nt][r] + colb;
      acc[nt][r] = vv; s1[r] += vv; s2[r] += vv*vv;
    }
  }
  rowredh(s1, s2, red, tid);
  #pragma unroll
  for(int nt = 0; nt < 4; nt++){
    const int col = (wh*4+nt)*16 + l15;
    const float g = kg[col], be = kb[col];
    #pragma unroll
    for(int r = 0; r < 4; r++){
      const int row = q4*4 + r;
      if(row < 8){
        const float mu = s1[r]*(1.f/128.f);
        const float var = s2[r]*(1.f/128.f) - mu*mu;
        kcb[(size_t)(cp0 + half*8 + row)*128 + col] = (acc[nt][r]-mu)*rsqrtf(var+1e-6f)*g + be;
      }
    }
  }
  // ---- v GEMM ----
  #pragma unroll
  for(int nt = 0; nt < 4; nt++){ acc[nt][0]=0.f; acc[nt][1]=0.f; acc[nt][2]=0.f; acc[nt][3]=0.f; }
  #pragma unroll
  for(int nt = 0; nt < 4; nt++){
    const int n = (wh*4+nt)*16 + l15;
    #pragma unroll
    for(int s = 0; s < 4; s++){
      const float* wp = qkv_w + (size_t)(256 + n)*128 + s*32 + q4*8;
      acc[nt] = __builtin_amdgcn_mfma_f32_16x16x32_bf16(
        af[s], pk8(*(const float4*)wp, *(const float4*)(wp+4)), acc[nt], 0,0,0);
    }
  }
  #pragma unroll
  for(int nt = 0; nt < 4; nt++){
    const int col = (wh*4+nt)*16 + l15;
    const float bv = qkv_b[256 + col];
    #pragma unroll
    for(int r = 0; r < 4; r++){
      const int row = q4*4 + r;
      if(row < 8) vcb[(size_t)(cp0 + half*8 + row)*128 + col] = acc[nt][r] + bv;
    }
  }
}

// ---- K_cell: 256 thr / 16 px (4 cells, 4x4 spatial tile) / all-MFMA ----
// px p: h = 4ip + (p>>2), w = 4jq + (p&3); cell(p) = 2*(p>>3) + ((p>>1)&1);
// lp(p) = 2*((p>>2)&1) + (p&1). Wave w owns cell w for attention.
__global__ void __launch_bounds__(256, 5)
k_cell(const float* __restrict__ x,
       const BF* __restrict__ packQ, const BF* __restrict__ packP,
       const BF* __restrict__ packF1, const BF* __restrict__ packF2,
       const float* __restrict__ qkv_b,
       const float* __restrict__ qg, const float* __restrict__ qb,
       const float* __restrict__ n1g, const float* __restrict__ n1b,
       const float* __restrict__ proj_b,
       const float* __restrict__ ls1, const float* __restrict__ ls2,
       const float* __restrict__ n2g, const float* __restrict__ n2b,
       const float* __restrict__ fc1_b,
       const float* __restrict__ mg, const float* __restrict__ mb,
       const float* __restrict__ fc2_b,
       const float* __restrict__ kcb, const float* __restrict__ vcb,
       float* __restrict__ out){
  __shared__ __align__(16) BF uni[9216];
  BF* const Abuf = uni;                        // [16][ASTR]
  __shared__ float xvL[2048];                  // [16px][128ch]
  __shared__ __align__(16) ushort qnH[2176];   // [4cell][136pad][4lp]
  __shared__ ushort cidx2[256];                // [4cell][64] safe coarse idx
  float* const red = (float*)qnH;              // 128 floats, disjoint live range
  const int tid = threadIdx.x, wave = tid>>6, lane = tid&63;
  const int l15 = lane & 15, q4 = lane >> 4;

  // XCD-aware swizzle (bijective: 2048 % 8 == 0, chunks of 256 per XCD)
  const int bx0 = blockIdx.x;
  const int bx = ((bx0 & 7) << 8) | (bx0 >> 3);
  const int b = bx >> 10, rem = bx & 1023, ip = rem >> 5, jq = rem & 31;
  const int c = tid & 127, half = tid >> 7;

  // direct (B,C,H,W) reads: 2 aligned float4 per thread
  float xv[8];
  {
    const size_t xb = (size_t)(b*128 + c)*16384 + (size_t)(4*ip + 2*half)*128 + 4*jq;
    const float4 r0 = *(const float4*)(x + xb);
    const float4 r1 = *(const float4*)(x + xb + 128);
    xv[0]=r0.x; xv[1]=r0.y; xv[2]=r0.z; xv[3]=r0.w;
    xv[4]=r1.x; xv[5]=r1.y; xv[6]=r1.z; xv[7]=r1.w;
    #pragma unroll
    for(int r = 0; r < 8; r++) xvL[(half*8 + r)*128 + c] = xv[r];
  }
  {                                            // neighbor indices, 4 cells
    const int cell = tid >> 6, e = tid & 63;
    const int i = e >> 3, j = e & 7;
    const int ic = 2*ip + (cell>>1), jcc = 2*jq + (cell&1);
    const int ri = ic + 2*i - 8, rj = jcc + 2*j - 8;
    const bool ok = (rj >= 0) && (rj < 64) && (ri >= 0) && (ri < 64);
    cidx2[cell*64 + e] = ok ? (ushort)(b*4096 + ri*64 + rj) : (ushort)0;
  }

  // ---- LN1 ----
  float st[16];
  #pragma unroll
  for(int r = 0; r < 8; r++){ st[r] = xv[r]; st[8+r] = xv[r]*xv[r]; }
  gsum16h(st, red, tid);
  {
    const float g = n1g[c], be = n1b[c];
    #pragma unroll
    for(int r = 0; r < 8; r++){
      const int p = half*8 + r;
      const float mu = st[r]*(1.f/128.f);
      const float var = st[8+r]*(1.f/128.f) - mu*mu;
      Abuf[p*ASTR + c] = __float2bfloat16((xv[r]-mu)*rsqrtf(var+1e-6f)*g + be);
    }
  }
  __syncthreads();

  // ---- q GEMM (M=16) + q-LN -> qnH ----
  {
    bf16x8 af[4];
    #pragma unroll
    for(int s = 0; s < 4; s++) af[s] = *(const bf16x8*)&Abuf[l15*ASTR + s*32 + q4*8];
    f32x4 acc[2];
    #pragma unroll
    for(int nt = 0; nt < 2; nt++){ acc[nt][0]=0.f; acc[nt][1]=0.f; acc[nt][2]=0.f; acc[nt][3]=0.f; }
    #pragma unroll
    for(int nt = 0; nt < 2; nt++){
      const int n = (wave*2+nt)*16 + l15;
      #pragma unroll
      for(int s = 0; s < 4; s++){
        bf16x8 bf = *(const bf16x8*)&packQ[((s*128 + n)*4 + q4)*8];
        acc[nt] = __builtin_amdgcn_mfma_f32_16x16x32_bf16(af[s], bf, acc[nt], 0,0,0);
      }
    }
    float s1[4], s2[4];
    #pragma unroll
    for(int r = 0; r < 4; r++){ s1[r]=0.f; s2[r]=0.f; }
    #pragma unroll
    for(int nt = 0; nt < 2; nt++){
      const float cb2 = qkv_b[(wave*2+nt)*16 + l15];
      #pragma unroll
      for(int r = 0; r < 4; r++){
        const float vv = acc[nt][r] + cb2;
        acc[nt][r] = vv; s1[r] += vv; s2[r] += vv*vv;
      }
    }
    rowred4(s1, s2, red, wave, lane);
    ushort tw[2][4];
    {
      float mu[4], rs[4];
      #pragma unroll
      for(int r = 0; r < 4; r++){
        mu[r] = s1[r]*(1.f/128.f);
        rs[r] = rsqrtf(s2[r]*(1.f/128.f) - mu[r]*mu[r] + 1e-6f);
      }
      #pragma unroll
      for(int nt = 0; nt < 2; nt++){
        const int col = (wave*2+nt)*16 + l15;
        const float g = qg[col], be = qb[col];
        float v0 = (acc[nt][0]-mu[0])*rs[0]*g + be;
        float v1 = (acc[nt][1]-mu[1])*rs[1]*g + be;
        float v2 = (acc[nt][2]-mu[2])*rs[2]*g + be;
        float v3 = (acc[nt][3]-mu[3])*rs[3]*g + be;
        const unsigned d0 = cvt2(v0, v1), d1 = cvt2(v2, v3);
        tw[nt][0] = (ushort)d0; tw[nt][1] = (ushort)(d0 >> 16);
        tw[nt][2] = (ushort)d1; tw[nt][3] = (ushort)(d1 >> 16);
      }
    }
    __syncthreads();            // red (aliased with qnH) fully consumed
    #pragma unroll
    for(int nt = 0; nt < 2; nt++){
      const int col = (wave*2+nt)*16 + l15;
      const int colp = col + (col >> 4);
      #pragma unroll
      for(int r = 0; r < 4; r++){
        const int cell = 2*(q4>>1) + ((r>>1)&1);
        const int lp   = 2*(q4&1) + (r&1);
        qnH[cell*544 + colp*4 + lp] = tw[nt][r];
      }
    }
  }
  __syncthreads();

  // ---- attention: wave w owns cell w, 2 head-groups, no inner barriers ----
  const int hsub = l15 >> 2, px = l15 & 3;
  const int par = q4 >> 1, dbase = (q4 & 1) * 8;
  BF* const attw = uni + wave*2304;
  ushort* const Vt = (ushort*)attw;            // [16][72]
  ushort* const Pb = (ushort*)(attw + 1152);   // [16][72]
  const ushort* cidx = cidx2 + wave*64;
  const ushort* qp = qnH + wave*544;
  const int ic = 2*ip + (wave>>1), jcc = 2*jq + (wave&1);
  const int i0 = l15 >> 3;
  const int rj = jcc + 2*(l15 & 7) - 8;
  const bool vj = (rj >= 0) && (rj < 64);
  float madd[4];
  #pragma unroll
  for(int nt = 0; nt < 4; nt++){
    const int ri = ic + 2*(nt*2 + i0) - 8;
    madd[nt] = (vj && ri >= 0 && ri < 64) ? 0.f : -1e30f;
  }

  f32x4 oC[2];
  #pragma unroll
  for(int hg = 0; hg < 2; hg++){
    // block-diagonal q A-fragments
    bf16x8 afq0, afq1;
    {
      const int idx0 = (hg*64 + hsub*16 + dbase + (hg*4 + hsub))*4 + px;
      short bq[8];
      #pragma unroll
      for(int j = 0; j < 8; j++) bq[j] = (short)qp[idx0 + 4*j];
      const bool a0 = (par == hsub), a1 = ((2 + par) == hsub);
      #pragma unroll
      for(int j = 0; j < 8; j++){
        afq0[j] = a0 ? bq[j] : (short)0;
        afq1[j] = a1 ? bq[j] : (short)0;
      }
    }
    // QK: 8 MFMA (operands packed via cvt_pk)
    f32x4 accq[4];
    #pragma unroll
    for(int nt = 0; nt < 4; nt++){ accq[nt][0]=0.f; accq[nt][1]=0.f; accq[nt][2]=0.f; accq[nt][3]=0.f; }
    #pragma unroll
    for(int nt = 0; nt < 4; nt++){
      const float* kp = kcb + ((size_t)cidx[nt*16 + l15] << 7) + hg*64 + q4*8;
      const float4 k00 = *(const float4*)kp;
      const float4 k01 = *(const float4*)(kp + 4);
      const float4 k10 = *(const float4*)(kp + 32);
      const float4 k11 = *(const float4*)(kp + 36);
      accq[nt] = __builtin_amdgcn_mfma_f32_16x16x32_bf16(afq0, pk8(k00,k01), accq[nt], 0,0,0);
      accq[nt] = __builtin_amdgcn_mfma_f32_16x16x32_bf16(afq1, pk8(k10,k11), accq[nt], 0,0,0);
    }
    // softmax in-register; unnormalized e (bf16 via cvt_pk) -> Pb
    float inv[4];
    #pragma unroll
    for(int reg = 0; reg < 4; reg++){
      const float s0 = accq[0][reg]*0.25f + madd[0];
      const float s1 = accq[1][reg]*0.25f + madd[1];
      const float s2 = accq[2][reg]*0.25f + madd[2];
      const float s3 = accq[3][reg]*0.25f + madd[3];
      float m = fmaxf(fmaxf(s0,s1), fmaxf(s2,s3));
      #pragma unroll
      for(int sft = 1; sft < 16; sft <<= 1) m = fmaxf(m, __shfl_xor(m, sft));
      const float e0 = __expf(s0-m), e1 = __expf(s1-m);
      const float e2 = __expf(s2-m), e3 = __expf(s3-m);
      ushort* pr = Pb + (q4*4 + reg)*72 + l15;
      const unsigned d0 = cvt2(e0, e1), d1 = cvt2(e2, e3);
      pr[0]  = (ushort)d0;
      pr[16] = (ushort)(d0 >> 16);
      pr[32] = (ushort)d1;
      pr[48] = (ushort)(d1 >> 16);
      float es = e0+e1+e2+e3;
      #pragma unroll
      for(int sft = 1; sft < 16; sft <<= 1) es += __shfl_xor(es, sft);
      inv[reg] = 1.f/es;
    }
    const bf16x8 pa0 = *(const bf16x8*)(Pb + l15*72 + q4*8);
    const bf16x8 pa1 = *(const bf16x8*)(Pb + l15*72 + 32 + q4*8);

    // PV: per head stage V (cvt_pk pairs), 2 MFMA; keep own head's rows
    f32x4 oSel; oSel[0]=0.f; oSel[1]=0.f; oSel[2]=0.f; oSel[3]=0.f;
    #pragma unroll
    for(int hs = 0; hs < 4; hs++){
      const int h = hg*4 + hs;
      float4 vv[4];
      #pragma unroll
      for(int it = 0; it < 4; it++)
        vv[it] = *(const float4*)(vcb + ((size_t)cidx[l15*4 + it] << 7) + h*16 + q4*4);
      #pragma unroll
      for(int dd = 0; dd < 4; dd++){
        union{ unsigned u[2]; us4 v; } w;
        w.u[0] = cvt2(((const float*)&vv[0])[dd], ((const float*)&vv[1])[dd]);
        w.u[1] = cvt2(((const float*)&vv[2])[dd], ((const float*)&vv[3])[dd]);
        *(us4*)(Vt + (q4*4 + dd)*72 + l15*4) = w.v;
      }
      const bf16x8 bv0 = *(const bf16x8*)(Vt + l15*72 + q4*8);
      const bf16x8 bv1 = *(const bf16x8*)(Vt + l15*72 + 32 + q4*8);
      f32x4 accv; accv[0]=0.f; accv[1]=0.f; accv[2]=0.f; accv[3]=0.f;
      accv = __builtin_amdgcn_mfma_f32_16x16x32_bf16(pa0, bv0, accv, 0,0,0);
      accv = __builtin_amdgcn_mfma_f32_16x16x32_bf16(pa1, bv1, accv, 0,0,0);
      if(q4 == hs){ oSel[0]=accv[0]; oSel[1]=accv[1]; oSel[2]=accv[2]; oSel[3]=accv[3]; }
    }
    oC[hg][0] = oSel[0]*inv[0]; oC[hg][1] = oSel[1]*inv[1];
    oC[hg][2] = oSel[2]*inv[2]; oC[hg][3] = oSel[3]*inv[3];
  }
  __syncthreads();
  // ao -> Abuf[px p][head*16 + d] (cvt_pk pairs)
  {
    ushort* ab = (ushort*)Abuf;
    #pragma unroll
    for(int hg = 0; hg < 2; hg++){
      const int col = (hg*4 + q4)*16 + l15;
      const unsigned d0 = cvt2(oC[hg][0], oC[hg][1]);
      const unsigned d1 = cvt2(oC[hg][2], oC[hg][3]);
      const ushort ov[4] = {(ushort)d0, (ushort)(d0>>16), (ushort)d1, (ushort)(d1>>16)};
      #pragma unroll
      for(int reg = 0; reg < 4; reg++){
        const int row_p = 8*(wave>>1) + 4*(reg>>1) + 2*(wave&1) + (reg&1);
        ab[row_p*ASTR + col] = ov[reg];
      }
    }
  }
  __syncthreads();

  // ---- proj GEMM + ls1*res -> xh, LN2 -> Abuf ----
  float xh[2][4];
  {
    bf16x8 af[4];
    #pragma unroll
    for(int s = 0; s < 4; s++) af[s] = *(const bf16x8*)&Abuf[l15*ASTR + s*32 + q4*8];
    f32x4 acc[2];
    #pragma unroll
    for(int nt = 0; nt < 2; nt++){ acc[nt][0]=0.f; acc[nt][1]=0.f; acc[nt][2]=0.f; acc[nt][3]=0.f; }
    #pragma unroll
    for(int nt = 0; nt < 2; nt++){
      const int n = (wave*2+nt)*16 + l15;
      #pragma unroll
      for(int s = 0; s < 4; s++){
        bf16x8 bf = *(const bf16x8*)&packP[((s*128 + n)*4 + q4)*8];
        acc[nt] = __builtin_amdgcn_mfma_f32_16x16x32_bf16(af[s], bf, acc[nt], 0,0,0);
      }
    }
    float s1[4], s2[4];
    #pragma unroll
    for(int r = 0; r < 4; r++){ s1[r]=0.f; s2[r]=0.f; }
    #pragma unroll
    for(int nt = 0; nt < 2; nt++){
      const int col = (wave*2+nt)*16 + l15;
      const float bp = proj_b[col], l1 = ls1[col];
      #pragma unroll
      for(int r = 0; r < 4; r++){
        const int p = q4*4 + r;
        const float hx = xvL[p*128 + col] + l1*(acc[nt][r] + bp);
        xh[nt][r] = hx; s1[r] += hx; s2[r] += hx*hx;
      }
    }
    rowred4(s1, s2, red, wave, lane);
    #pragma unroll
    for(int nt = 0; nt < 2; nt++){
      const int col = (wave*2+nt)*16 + l15;
      const float g2 = n2g[col], be = n2b[col];
      #pragma unroll
      for(int r = 0; r < 4; r++){
        const int p = q4*4 + r;
        const float mu = s1[r]*(1.f/128.f);
        const float var = s2[r]*(1.f/128.f) - mu*mu;
        Abuf[p*ASTR + col] =
          __float2bfloat16((xh[nt][r]-mu)*rsqrtf(var+1e-6f)*g2 + be);
      }
    }
  }
  __syncthreads();

  // ---- fc1 GEMM (N=176, tiles 3/3/3/2) + midLN + gelu -> Abuf ----
  {
    bf16x8 af[4];
    #pragma unroll
    for(int s = 0; s < 4; s++) af[s] = *(const bf16x8*)&Abuf[l15*ASTR + s*32 + q4*8];
    const int NT1 = (wave < 3) ? 3 : 2;
    const int tb  = (wave < 3) ? wave*3 : 9;
    f32x4 acc1[3];
    #pragma unroll
    for(int nt = 0; nt < 3; nt++){ acc1[nt][0]=0.f; acc1[nt][1]=0.f; acc1[nt][2]=0.f; acc1[nt][3]=0.f; }
    for(int nt = 0; nt < NT1; nt++){
      const int n = (tb + nt)*16 + l15;
      #pragma unroll
      for(int s = 0; s < 4; s++){
        bf16x8 bf = *(const bf16x8*)&packF1[((s*176 + n)*4 + q4)*8];
        acc1[nt] = __builtin_amdgcn_mfma_f32_16x16x32_bf16(af[s], bf, acc1[nt], 0,0,0);
      }
    }
    float s1[4], s2[4];
    #pragma unroll
    for(int r = 0; r < 4; r++){ s1[r]=0.f; s2[r]=0.f; }
    for(int nt = 0; nt < NT1; nt++){
      const int col = (tb + nt)*16 + l15;
      const float b1 = (col < 170) ? fc1_b[col] : 0.f;
      #pragma unroll
      for(int r = 0; r < 4; r++){
        const float vv = acc1[nt][r] + b1;
        acc1[nt][r] = vv; s1[r] += vv; s2[r] += vv*vv;
      }
    }
    rowred4(s1, s2, red, wave, lane);
    for(int z = tid; z < 352; z += 256){          // zero fc2 K-pad cols 170..191
      const int row = z / 22, colz = 170 + (z - (z/22)*22);
      Abuf[row*ASTR + colz] = __float2bfloat16(0.f);
    }
    const float kA = 0.7978845608028654f, kB = 0.044715f;
    for(int nt = 0; nt < NT1; nt++){
      const int col = (tb + nt)*16 + l15;
      if(col < 170){
        const float g2 = mg[col], be = mb[col];
        #pragma unroll
        for(int r = 0; r < 4; r++){
          const int p = q4*4 + r;
          const float mu = s1[r]*(1.f/170.f);
          const float var = s2[r]*(1.f/170.f) - mu*mu;
          const float hn = (acc1[nt][r]-mu)*rsqrtf(var+1e-6f)*g2 + be;
          const float u = kA*(hn + kB*hn*hn*hn);
          const float gl = hn / (1.f + __expf(-2.f*u));
          Abuf[p*ASTR + col] = __float2bfloat16(gl);
        }
      }
    }
  }
  __syncthreads();

  // ---- fc2 GEMM (K=192) + ls2*res -> out (B,C,H,W) directly ----
  {
    bf16x8 af[6];
    #pragma unroll
    for(int s = 0; s < 6; s++) af[s] = *(const bf16x8*)&Abuf[l15*ASTR + s*32 + q4*8];
    f32x4 acc[2];
    #pragma unroll
    for(int nt = 0; nt < 2; nt++){ acc[nt][0]=0.f; acc[nt][1]=0.f; acc[nt][2]=0.f; acc[nt][3]=0.f; }
    #pragma unroll
    for(int nt = 0; nt < 2; nt++){
      const int n = (wave*2+nt)*16 + l15;
      #pragma unroll
      for(int s = 0; s < 6; s++){
        bf16x8 bf = *(const bf16x8*)&packF2[((s*128 + n)*4 + q4)*8];
        acc[nt] = __builtin_amdgcn_mfma_f32_16x16x32_bf16(af[s], bf, acc[nt], 0,0,0);
      }
    }
    #pragma unroll
    for(int nt = 0; nt < 2; nt++){
      const int col = (wave*2+nt)*16 + l15;
      const float bf2 = fc2_b[col], l2 = ls2[col];
      float4 o4;
      o4.x = xh[nt][0] + l2*(acc[nt][0] + bf2);
      o4.y = xh[nt][1] + l2*(acc[nt][1] + bf2);
      o4.z = xh[nt][2] + l2*(acc[nt][2] + bf2);
      o4.w = xh[nt][3] + l2*(acc[nt][3] + bf2);
      *(float4*)(out + (size_t)(b*128 + col)*16384 + (size_t)(4*ip + q4)*128 + 4*jq) = o4;
    }
  }
}

extern "C" void kernel_launch(void* const* d_in, const int* in_sizes, int n_in,
                              void* d_out, int out_size, void* d_ws, size_t ws_size,
                              hipStream_t stream){
  const float* x      = (const float*)d_in[0];
  const float* qkv_w  = (const float*)d_in[1];
  const float* qkv_b  = (const float*)d_in[2];
  const float* qg     = (const float*)d_in[3];
  const float* qb     = (const float*)d_in[4];
  const float* kg     = (const float*)d_in[5];
  const float* kb     = (const float*)d_in[6];
  const float* proj_w = (const float*)d_in[7];
  const float* proj_b = (const float*)d_in[8];
  const float* n1g    = (const float*)d_in[9];
  const float* n1b    = (const float*)d_in[10];
  const float* n2g    = (const float*)d_in[11];
  const float* n2b    = (const float*)d_in[12];
  const float* ls1    = (const float*)d_in[13];
  const float* ls2    = (const float*)d_in[14];
  const float* fc1_w  = (const float*)d_in[15];
  const float* fc1_b  = (const float*)d_in[16];
  const float* mg     = (const float*)d_in[17];
  const float* mb     = (const float*)d_in[18];
  const float* fc2_w  = (const float*)d_in[19];
  const float* fc2_b  = (const float*)d_in[20];

  float* ws  = (float*)d_ws;
  float* kcb = ws;
  float* vcb = ws + 1048576;
  BF* pk     = (BF*)(ws + 2097152);
  BF* packQ  = pk;
  BF* packP  = pk + 49152;
  BF* packF1 = pk + 65536;
  BF* packF2 = pk + 88064;

  k_pre <<<952, 256, 0, stream>>>(x, qkv_w, proj_w, fc1_w, fc2_w, qkv_b,
                                  kg, kb, n1g, n1b, pk, kcb, vcb);
  k_cell<<<2048, 256, 0, stream>>>(x, packQ, packP, packF1, packF2,
                                   qkv_b, qg, qb, n1g, n1b, proj_b, ls1, ls2,
                                   n2g, n2b, fc1_b, mg, mb, fc2_b,
                                   kcb, vcb, (float*)d_out);
}

// Round 10
// 212.240 us; speedup vs baseline: 2.7348x; 1.0879x over previous
//
#include <hip/hip_runtime.h>
#include <hip/hip_bf16.h>

typedef __hip_bfloat16 BF;
typedef __attribute__((ext_vector_type(8))) short bf16x8;
typedef __attribute__((ext_vector_type(4))) float f32x4;

// B=2, C=128, H=W=128, K=8, STRIDE=2, DIL=2, NH=8, dh=16, HID=170, Hc=Wc=64
// fp32 in / fp32 out. MFMA (bf16, fp32 acc) everywhere.
// R10: V stored PRE-TRANSPOSED as vcbT[b][par][ri][rjh(40)][d(128)] so PV
// loads B-fragments directly from global (no LDS Vt staging) -> LDS 31.7KB ->
// 22.5KB -> 7 blocks/CU. Pad cols {0..4,37..39} zeroed (P=0 + finite = safe).
// ws (floats): kcb[0,1048576) vcbT[1048576,3670016) packs(bf16) at 3670016.
// NOTE (R7): cooperative grid.sync on gfx950 de-caches L2 -- never fuse
// across a coop sync on this chip.

#define ASTR 200   // k_cell Abuf row stride (bf16)
#define KSTR 136   // k_pre(kv) Abuf row stride (bf16)

// 2x f32 -> packed bf16 (RNE) in one instruction
__device__ __forceinline__ unsigned cvt2(float lo, float hi){
  unsigned r;
  asm("v_cvt_pk_bf16_f32 %0, %1, %2" : "=v"(r) : "v"(lo), "v"(hi));
  return r;
}
__device__ __forceinline__ bf16x8 pk8(float4 a, float4 b){
  union{ unsigned u[4]; bf16x8 v; } c;
  c.u[0] = cvt2(a.x, a.y); c.u[1] = cvt2(a.z, a.w);
  c.u[2] = cvt2(b.x, b.y); c.u[3] = cvt2(b.z, b.w);
  return c.v;
}

// sum-reduce 16 vals across a 128-thr half (2 waves) of a 256-thr block
__device__ __forceinline__ void gsum16h(float v[16], float* red, int tid){
  #pragma unroll
  for(int s = 1; s < 64; s <<= 1){
    #pragma unroll
    for(int i = 0; i < 16; i++) v[i] += __shfl_xor(v[i], s);
  }
  const int wid = tid >> 6, half = tid >> 7;
  __syncthreads();
  if((tid & 63) == 0){
    #pragma unroll
    for(int i = 0; i < 16; i++) red[wid*16 + i] = v[i];
  }
  __syncthreads();
  #pragma unroll
  for(int i = 0; i < 16; i++) v[i] = red[half*32 + i] + red[half*32 + 16 + i];
}

// per-half row-stat reduction (k_pre kv)
__device__ __forceinline__ void rowredh(float s1[4], float s2[4], float* red, int tid){
  const int lane = tid & 63, wid = tid >> 6, half = tid >> 7;
  #pragma unroll
  for(int m = 1; m < 16; m <<= 1){
    #pragma unroll
    for(int r = 0; r < 4; r++){ s1[r] += __shfl_xor(s1[r], m); s2[r] += __shfl_xor(s2[r], m); }
  }
  const int q4 = lane >> 4;
  __syncthreads();
  if((lane & 15) == 0){
    #pragma unroll
    for(int r = 0; r < 4; r++){
      red[wid*32 + q4*4 + r]      = s1[r];
      red[wid*32 + 16 + q4*4 + r] = s2[r];
    }
  }
  __syncthreads();
  #pragma unroll
  for(int r = 0; r < 4; r++){
    s1[r] = red[half*64 + q4*4 + r]      + red[half*64 + 32 + q4*4 + r];
    s2[r] = red[half*64 + 16 + q4*4 + r] + red[half*64 + 48 + q4*4 + r];
  }
}

// 4-wave row-stat reduction (k_cell): rows 0..15 = px, stats over 128 cols
__device__ __forceinline__ void rowred4(float s1[4], float s2[4], float* red,
                                        int wave, int lane){
  #pragma unroll
  for(int m = 1; m < 16; m <<= 1){
    #pragma unroll
    for(int r = 0; r < 4; r++){ s1[r] += __shfl_xor(s1[r], m); s2[r] += __shfl_xor(s2[r], m); }
  }
  const int q4 = lane >> 4;
  __syncthreads();
  if((lane & 15) == 0){
    #pragma unroll
    for(int r = 0; r < 4; r++){
      red[wave*32 + q4*4 + r]      = s1[r];
      red[wave*32 + 16 + q4*4 + r] = s2[r];
    }
  }
  __syncthreads();
  #pragma unroll
  for(int r = 0; r < 4; r++){
    s1[r] = red[q4*4 + r] + red[32 + q4*4 + r] + red[64 + q4*4 + r] + red[96 + q4*4 + r];
    s2[r] = red[16 + q4*4 + r] + red[48 + q4*4 + r] + red[80 + q4*4 + r] + red[112 + q4*4 + r];
  }
}

// ---- K_pre: {coarse k,v (blocks 0..511) | weight pack + pad-zero (512..951)} ----
__global__ void __launch_bounds__(256)
k_pre(const float* __restrict__ x,
      const float* __restrict__ qkv_w, const float* __restrict__ proj_w,
      const float* __restrict__ fc1_w, const float* __restrict__ fc2_w,
      const float* __restrict__ qkv_b,
      const float* __restrict__ kg, const float* __restrict__ kb,
      const float* __restrict__ n1g, const float* __restrict__ n1b,
      BF* __restrict__ pk,
      float* __restrict__ kcb, float* __restrict__ vcbT){
  __shared__ __align__(16) unsigned char sm[9216];
  const int bx = blockIdx.x, tid = threadIdx.x;

  if(bx >= 512){                       // ---- weight pack + vcbT pad zeroing
    const int idx = (bx - 512) * 256 + tid;
    if(idx < 112640){
      float val;
      if(idx < 49152){
        const int reg = idx >> 14, l = idx & 16383;
        const int j = l & 7, q = (l>>3)&3, n = (l>>5)&127, s = l>>12;
        val = qkv_w[(reg*128 + n)*128 + (s*32 + q*8 + j)];
      } else if(idx < 65536){
        const int l = idx - 49152;
        const int j = l&7, q=(l>>3)&3, n=(l>>5)&127, s=l>>12;
        val = proj_w[n*128 + (s*32+q*8+j)];
      } else if(idx < 88064){
        const int l = idx - 65536;
        const int j = l&7, q=(l>>3)&3, rem = l>>5;
        const int n = rem % 176, s = rem / 176;
        const int k = s*32+q*8+j;
        val = (n < 170) ? fc1_w[n*128 + k] : 0.f;
      } else {
        const int l = idx - 88064;
        const int j = l&7, q=(l>>3)&3, n=(l>>5)&127, s=l>>12;
        const int k = s*32+q*8+j;
        val = (k < 170) ? fc2_w[n*170 + k] : 0.f;
      }
      pk[idx] = __float2bfloat16(val);
    }
    // zero vcbT pad columns (rjh5 in {0..4,37..39}) -- disjoint from data
    // writers in kv blocks, so safe in the same dispatch.
    for(int z = (bx - 512)*256 + tid; z < 262144; z += 440*256){
      const int bpr = z >> 10;               // (b*2+par)*64 + ri, 256 combos
      const int pc  = (z >> 7) & 7;
      const int d   = z & 127;
      const int rjh5 = (pc < 5) ? pc : (32 + pc);
      vcbT[((size_t)bpr*40 + rjh5)*128 + d] = 0.f;
    }
    return;
  }

  // ---- kv: 16 coarse px/block, two independent 128-thr halves ----
  BF* const Abuf = (BF*)sm;                    // 2 halves x [16][KSTR]
  float* const red = (float*)(sm + 8704);      // 128 floats
  const int lane = tid & 63, half = tid >> 7, wh = (tid >> 6) & 1, c = tid & 127;
  const int l15 = lane & 15, q4 = lane >> 4;
  const int cp0 = bx * 16;
  const int b = cp0 >> 12, ic = (cp0 & 4095) >> 6, jb = cp0 & 63;
  BF* const AbufH = Abuf + half*16*KSTR;

  float xv[8];
  {
    const size_t off = (size_t)(b*128 + c)*16384 + (size_t)(2*ic)*128 + 2*(jb + half*8);
    const float4* xp4 = (const float4*)(x + off);
    const float4 f0 = xp4[0], f1 = xp4[1], f2 = xp4[2], f3 = xp4[3];
    xv[0]=f0.x; xv[1]=f0.z; xv[2]=f1.x; xv[3]=f1.z;
    xv[4]=f2.x; xv[5]=f2.z; xv[6]=f3.x; xv[7]=f3.z;
  }
  float st[16];
  #pragma unroll
  for(int r = 0; r < 8; r++){ st[r] = xv[r]; st[8+r] = xv[r]*xv[r]; }
  gsum16h(st, red, tid);
  {
    const float g = n1g[c], be = n1b[c];
    #pragma unroll
    for(int r = 0; r < 8; r++){
      const float mu = st[r]*(1.f/128.f);
      const float var = st[8+r]*(1.f/128.f) - mu*mu;
      AbufH[r*KSTR + c] = __float2bfloat16((xv[r]-mu)*rsqrtf(var+1e-6f)*g + be);
    }
  }
  __syncthreads();
  bf16x8 af[4];
  #pragma unroll
  for(int s = 0; s < 4; s++) af[s] = *(const bf16x8*)&AbufH[l15*KSTR + s*32 + q4*8];

  // ---- k GEMM (B-fragments straight from qkv_w, cvt_pk inline) ----
  f32x4 acc[4];
  #pragma unroll
  for(int nt = 0; nt < 4; nt++){ acc[nt][0]=0.f; acc[nt][1]=0.f; acc[nt][2]=0.f; acc[nt][3]=0.f; }
  #pragma unroll
  for(int nt = 0; nt < 4; nt++){
    const int n = (wh*4+nt)*16 + l15;
    #pragma unroll
    for(int s = 0; s < 4; s++){
      const float* wp = qkv_w + (size_t)(128 + n)*128 + s*32 + q4*8;
      acc[nt] = __builtin_amdgcn_mfma_f32_16x16x32_bf16(
        af[s], pk8(*(const float4*)wp, *(const float4*)(wp+4)), acc[nt], 0,0,0);
    }
  }
  float s1[4], s2[4];
  #pragma unroll
  for(int r = 0; r < 4; r++){ s1[r]=0.f; s2[r]=0.f; }
  #pragma unroll
  for(int nt = 0; nt < 4; nt++){
    const float colb = qkv_b[128 + (wh*4+nt)*16 + l15];
    #pragma unroll
    for(int r = 0; r < 4; r++){
      const float vv = acc[nt][r] + colb;
      acc[nt][r] = vv; s1[r] += vv; s2[r] += vv*vv;
    }
  }
  rowredh(s1, s2, red, tid);
  #pragma unroll
  for(int nt = 0; nt < 4; nt++){
    const int col = (wh*4+nt)*16 + l15;
    const float g = kg[col], be = kb[col];
    #pragma unroll
    for(int r = 0; r < 4; r++){
      const int row = q4*4 + r;
      if(row < 8){
        const float mu = s1[r]*(1.f/128.f);
        const float var = s2[r]*(1.f/128.f) - mu*mu;
        kcb[(size_t)(cp0 + half*8 + row)*128 + col] = (acc[nt][r]-mu)*rsqrtf(var+1e-6f)*g + be;
      }
    }
  }
  // ---- v GEMM -> vcbT[b][par][ri][rjh+5][d] (transposed, parity-split) ----
  #pragma unroll
  for(int nt = 0; nt < 4; nt++){ acc[nt][0]=0.f; acc[nt][1]=0.f; acc[nt][2]=0.f; acc[nt][3]=0.f; }
  #pragma unroll
  for(int nt = 0; nt < 4; nt++){
    const int n = (wh*4+nt)*16 + l15;
    #pragma unroll
    for(int s = 0; s < 4; s++){
      const float* wp = qkv_w + (size_t)(256 + n)*128 + s*32 + q4*8;
      acc[nt] = __builtin_amdgcn_mfma_f32_16x16x32_bf16(
        af[s], pk8(*(const float4*)wp, *(const float4*)(wp+4)), acc[nt], 0,0,0);
    }
  }
  #pragma unroll
  for(int nt = 0; nt < 4; nt++){
    const int col = (wh*4+nt)*16 + l15;
    const float bv = qkv_b[256 + col];
    #pragma unroll
    for(int r = 0; r < 4; r++){
      const int row = q4*4 + r;
      if(row < 8){
        const int cp = cp0 + half*8 + row;
        const int b2 = cp >> 12, rr = cp & 4095;
        const int ri = rr >> 6, rj = rr & 63;
        vcbT[((((size_t)(b2*2 + (rj&1))*64 + ri)*40) + (rj>>1) + 5)*128 + col]
          = acc[nt][r] + bv;
      }
    }
  }
}

// ---- K_cell: 256 thr / 16 px (4 cells) / all-MFMA, direct-V PV ----
// px p: h = 4ip + (p>>2), w = 4jq + (p&3); cell(p) = 2*(p>>3) + ((p>>1)&1);
// lp(p) = 2*((p>>2)&1) + (p&1). Wave w owns cell w for attention.
// LDS 22.5KB -> 7 blocks/CU: uni 9216 (Abuf[16][200] U 4x Pb[16][72]) +
// xvL 8192 + qnH 4352 (red aliased) + cidx 512.
__global__ void __launch_bounds__(256, 6)
k_cell(const float* __restrict__ x,
       const BF* __restrict__ packQ, const BF* __restrict__ packP,
       const BF* __restrict__ packF1, const BF* __restrict__ packF2,
       const float* __restrict__ qkv_b,
       const float* __restrict__ qg, const float* __restrict__ qb,
       const float* __restrict__ n1g, const float* __restrict__ n1b,
       const float* __restrict__ proj_b,
       const float* __restrict__ ls1, const float* __restrict__ ls2,
       const float* __restrict__ n2g, const float* __restrict__ n2b,
       const float* __restrict__ fc1_b,
       const float* __restrict__ mg, const float* __restrict__ mb,
       const float* __restrict__ fc2_b,
       const float* __restrict__ kcb, const float* __restrict__ vcbT,
       float* __restrict__ out){
  __shared__ __align__(16) BF uni[4608];       // Abuf[16][ASTR] U 4x Pb
  BF* const Abuf = uni;
  __shared__ float xvL[2048];                  // [16px][128ch]
  __shared__ __align__(16) ushort qnH[2176];   // [4cell][136pad][4lp]
  __shared__ ushort cidx2[256];                // [4cell][64] safe coarse idx
  float* const red = (float*)qnH;              // 128 floats, disjoint live range
  const int tid = threadIdx.x, wave = tid>>6, lane = tid&63;
  const int l15 = lane & 15, q4 = lane >> 4;

  // XCD-aware swizzle (bijective: 2048 % 8 == 0, chunks of 256 per XCD)
  const int bx0 = blockIdx.x;
  const int bx = ((bx0 & 7) << 8) | (bx0 >> 3);
  const int b = bx >> 10, rem = bx & 1023, ip = rem >> 5, jq = rem & 31;
  const int c = tid & 127, half = tid >> 7;

  // direct (B,C,H,W) reads: 2 aligned float4 per thread
  float xv[8];
  {
    const size_t xb = (size_t)(b*128 + c)*16384 + (size_t)(4*ip + 2*half)*128 + 4*jq;
    const float4 r0 = *(const float4*)(x + xb);
    const float4 r1 = *(const float4*)(x + xb + 128);
    xv[0]=r0.x; xv[1]=r0.y; xv[2]=r0.z; xv[3]=r0.w;
    xv[4]=r1.x; xv[5]=r1.y; xv[6]=r1.z; xv[7]=r1.w;
    #pragma unroll
    for(int r = 0; r < 8; r++) xvL[(half*8 + r)*128 + c] = xv[r];
  }
  {                                            // neighbor indices, 4 cells
    const int cell = tid >> 6, e = tid & 63;
    const int i = e >> 3, j = e & 7;
    const int ic = 2*ip + (cell>>1), jcc = 2*jq + (cell&1);
    const int ri = ic + 2*i - 8, rj = jcc + 2*j - 8;
    const bool ok = (rj >= 0) && (rj < 64) && (ri >= 0) && (ri < 64);
    cidx2[cell*64 + e] = ok ? (ushort)(b*4096 + ri*64 + rj) : (ushort)0;
  }

  // ---- LN1 ----
  float st[16];
  #pragma unroll
  for(int r = 0; r < 8; r++){ st[r] = xv[r]; st[8+r] = xv[r]*xv[r]; }
  gsum16h(st, red, tid);
  {
    const float g = n1g[c], be = n1b[c];
    #pragma unroll
    for(int r = 0; r < 8; r++){
      const int p = half*8 + r;
      const float mu = st[r]*(1.f/128.f);
      const float var = st[8+r]*(1.f/128.f) - mu*mu;
      Abuf[p*ASTR + c] = __float2bfloat16((xv[r]-mu)*rsqrtf(var+1e-6f)*g + be);
    }
  }
  __syncthreads();

  // ---- q GEMM (M=16) + q-LN -> qnH ----
  {
    bf16x8 af[4];
    #pragma unroll
    for(int s = 0; s < 4; s++) af[s] = *(const bf16x8*)&Abuf[l15*ASTR + s*32 + q4*8];
    f32x4 acc[2];
    #pragma unroll
    for(int nt = 0; nt < 2; nt++){ acc[nt][0]=0.f; acc[nt][1]=0.f; acc[nt][2]=0.f; acc[nt][3]=0.f; }
    #pragma unroll
    for(int nt = 0; nt < 2; nt++){
      const int n = (wave*2+nt)*16 + l15;
      #pragma unroll
      for(int s = 0; s < 4; s++){
        bf16x8 bf = *(const bf16x8*)&packQ[((s*128 + n)*4 + q4)*8];
        acc[nt] = __builtin_amdgcn_mfma_f32_16x16x32_bf16(af[s], bf, acc[nt], 0,0,0);
      }
    }
    float s1[4], s2[4];
    #pragma unroll
    for(int r = 0; r < 4; r++){ s1[r]=0.f; s2[r]=0.f; }
    #pragma unroll
    for(int nt = 0; nt < 2; nt++){
      const float cb2 = qkv_b[(wave*2+nt)*16 + l15];
      #pragma unroll
      for(int r = 0; r < 4; r++){
        const float vv = acc[nt][r] + cb2;
        acc[nt][r] = vv; s1[r] += vv; s2[r] += vv*vv;
      }
    }
    rowred4(s1, s2, red, wave, lane);
    ushort tw[2][4];
    {
      float mu[4], rs[4];
      #pragma unroll
      for(int r = 0; r < 4; r++){
        mu[r] = s1[r]*(1.f/128.f);
        rs[r] = rsqrtf(s2[r]*(1.f/128.f) - mu[r]*mu[r] + 1e-6f);
      }
      #pragma unroll
      for(int nt = 0; nt < 2; nt++){
        const int col = (wave*2+nt)*16 + l15;
        const float g = qg[col], be = qb[col];
        float v0 = (acc[nt][0]-mu[0])*rs[0]*g + be;
        float v1 = (acc[nt][1]-mu[1])*rs[1]*g + be;
        float v2 = (acc[nt][2]-mu[2])*rs[2]*g + be;
        float v3 = (acc[nt][3]-mu[3])*rs[3]*g + be;
        const unsigned d0 = cvt2(v0, v1), d1 = cvt2(v2, v3);
        tw[nt][0] = (ushort)d0; tw[nt][1] = (ushort)(d0 >> 16);
        tw[nt][2] = (ushort)d1; tw[nt][3] = (ushort)(d1 >> 16);
      }
    }
    __syncthreads();            // red (aliased with qnH) fully consumed
    #pragma unroll
    for(int nt = 0; nt < 2; nt++){
      const int col = (wave*2+nt)*16 + l15;
      const int colp = col + (col >> 4);
      #pragma unroll
      for(int r = 0; r < 4; r++){
        const int cell = 2*(q4>>1) + ((r>>1)&1);
        const int lp   = 2*(q4&1) + (r&1);
        qnH[cell*544 + colp*4 + lp] = tw[nt][r];
      }
    }
  }
  __syncthreads();

  // ---- attention: wave w owns cell w, 2 head-groups, no inner barriers ----
  const int hsub = l15 >> 2, px = l15 & 3;
  const int par4 = q4 >> 1, dbase = (q4 & 1) * 8;
  BF* const attw = uni + wave*1152;
  ushort* const Pb = (ushort*)attw;            // [16][72]
  const ushort* cidx = cidx2 + wave*64;
  const ushort* qp = qnH + wave*544;
  const int ic = 2*ip + (wave>>1), jcc = 2*jq + (wave&1);
  const int i0 = l15 >> 3;
  const int rj = jcc + 2*(l15 & 7) - 8;
  const bool vj = (rj >= 0) && (rj < 64);
  float madd[4];
  #pragma unroll
  for(int nt = 0; nt < 4; nt++){
    const int ri = ic + 2*(nt*2 + i0) - 8;
    madd[nt] = (vj && ri >= 0 && ri < 64) ? 0.f : -1e30f;
  }
  // direct-V base pointers: fragment pa0 uses ri=ic+2q4-8, pa1 ri=ic+2q4;
  // col index (jcc>>1)+1+j lands in pads (zeroed) exactly when rj invalid.
  const int parv = jcc & 1;
  const int riA = min(63, max(0, ic + 2*q4 - 8));
  const int riB = min(63, max(0, ic + 2*q4));
  const float* vbA = vcbT + ((((size_t)(b*2 + parv)*64 + riA)*40) + (jcc>>1) + 1)*128 + l15;
  const float* vbB = vcbT + ((((size_t)(b*2 + parv)*64 + riB)*40) + (jcc>>1) + 1)*128 + l15;

  f32x4 oC[2];
  #pragma unroll
  for(int hg = 0; hg < 2; hg++){
    // block-diagonal q A-fragments
    bf16x8 afq0, afq1;
    {
      const int idx0 = (hg*64 + hsub*16 + dbase + (hg*4 + hsub))*4 + px;
      short bq[8];
      #pragma unroll
      for(int j = 0; j < 8; j++) bq[j] = (short)qp[idx0 + 4*j];
      const bool a0 = (par4 == hsub), a1 = ((2 + par4) == hsub);
      #pragma unroll
      for(int j = 0; j < 8; j++){
        afq0[j] = a0 ? bq[j] : (short)0;
        afq1[j] = a1 ? bq[j] : (short)0;
      }
    }
    // QK: 8 MFMA (operands packed via cvt_pk)
    f32x4 accq[4];
    #pragma unroll
    for(int nt = 0; nt < 4; nt++){ accq[nt][0]=0.f; accq[nt][1]=0.f; accq[nt][2]=0.f; accq[nt][3]=0.f; }
    #pragma unroll
    for(int nt = 0; nt < 4; nt++){
      const float* kp = kcb + ((size_t)cidx[nt*16 + l15] << 7) + hg*64 + q4*8;
      const float4 k00 = *(const float4*)kp;
      const float4 k01 = *(const float4*)(kp + 4);
      const float4 k10 = *(const float4*)(kp + 32);
      const float4 k11 = *(const float4*)(kp + 36);
      accq[nt] = __builtin_amdgcn_mfma_f32_16x16x32_bf16(afq0, pk8(k00,k01), accq[nt], 0,0,0);
      accq[nt] = __builtin_amdgcn_mfma_f32_16x16x32_bf16(afq1, pk8(k10,k11), accq[nt], 0,0,0);
    }
    // softmax in-register; unnormalized e (bf16 via cvt_pk) -> Pb
    float inv[4];
    #pragma unroll
    for(int reg = 0; reg < 4; reg++){
      const float s0 = accq[0][reg]*0.25f + madd[0];
      const float s1 = accq[1][reg]*0.25f + madd[1];
      const float s2 = accq[2][reg]*0.25f + madd[2];
      const float s3 = accq[3][reg]*0.25f + madd[3];
      float m = fmaxf(fmaxf(s0,s1), fmaxf(s2,s3));
      #pragma unroll
      for(int sft = 1; sft < 16; sft <<= 1) m = fmaxf(m, __shfl_xor(m, sft));
      const float e0 = __expf(s0-m), e1 = __expf(s1-m);
      const float e2 = __expf(s2-m), e3 = __expf(s3-m);
      ushort* pr = Pb + (q4*4 + reg)*72 + l15;
      const unsigned d0 = cvt2(e0, e1), d1 = cvt2(e2, e3);
      pr[0]  = (ushort)d0;
      pr[16] = (ushort)(d0 >> 16);
      pr[32] = (ushort)d1;
      pr[48] = (ushort)(d1 >> 16);
      float es = e0+e1+e2+e3;
      #pragma unroll
      for(int sft = 1; sft < 16; sft <<= 1) es += __shfl_xor(es, sft);
      inv[reg] = 1.f/es;
    }
    const bf16x8 pa0 = *(const bf16x8*)(Pb + l15*72 + q4*8);
    const bf16x8 pa1 = *(const bf16x8*)(Pb + l15*72 + 32 + q4*8);

    // PV: direct per-lane B-fragment loads from vcbT (no LDS staging)
    f32x4 oSel; oSel[0]=0.f; oSel[1]=0.f; oSel[2]=0.f; oSel[3]=0.f;
    #pragma unroll
    for(int hs = 0; hs < 4; hs++){
      const int hoff = (hg*4 + hs)*16;
      float a0[8], a1[8];
      #pragma unroll
      for(int j = 0; j < 8; j++){
        a0[j] = vbA[j*128 + hoff];
        a1[j] = vbB[j*128 + hoff];
      }
      union{ unsigned u[4]; bf16x8 v; } c0, c1;
      c0.u[0]=cvt2(a0[0],a0[1]); c0.u[1]=cvt2(a0[2],a0[3]);
      c0.u[2]=cvt2(a0[4],a0[5]); c0.u[3]=cvt2(a0[6],a0[7]);
      c1.u[0]=cvt2(a1[0],a1[1]); c1.u[1]=cvt2(a1[2],a1[3]);
      c1.u[2]=cvt2(a1[4],a1[5]); c1.u[3]=cvt2(a1[6],a1[7]);
      f32x4 accv; accv[0]=0.f; accv[1]=0.f; accv[2]=0.f; accv[3]=0.f;
      accv = __builtin_amdgcn_mfma_f32_16x16x32_bf16(pa0, c0.v, accv, 0,0,0);
      accv = __builtin_amdgcn_mfma_f32_16x16x32_bf16(pa1, c1.v, accv, 0,0,0);
      if(q4 == hs){ oSel[0]=accv[0]; oSel[1]=accv[1]; oSel[2]=accv[2]; oSel[3]=accv[3]; }
    }
    oC[hg][0] = oSel[0]*inv[0]; oC[hg][1] = oSel[1]*inv[1];
    oC[hg][2] = oSel[2]*inv[2]; oC[hg][3] = oSel[3]*inv[3];
  }
  __syncthreads();
  // ao -> Abuf[px p][head*16 + d] (cvt_pk pairs)
  {
    ushort* ab = (ushort*)Abuf;
    #pragma unroll
    for(int hg = 0; hg < 2; hg++){
      const int col = (hg*4 + q4)*16 + l15;
      const unsigned d0 = cvt2(oC[hg][0], oC[hg][1]);
      const unsigned d1 = cvt2(oC[hg][2], oC[hg][3]);
      const ushort ov[4] = {(ushort)d0, (ushort)(d0>>16), (ushort)d1, (ushort)(d1>>16)};
      #pragma unroll
      for(int reg = 0; reg < 4; reg++){
        const int row_p = 8*(wave>>1) + 4*(reg>>1) + 2*(wave&1) + (reg&1);
        ab[row_p*ASTR + col] = ov[reg];
      }
    }
  }
  __syncthreads();

  // ---- proj GEMM + ls1*res -> xh, LN2 -> Abuf ----
  float xh[2][4];
  {
    bf16x8 af[4];
    #pragma unroll
    for(int s = 0; s < 4; s++) af[s] = *(const bf16x8*)&Abuf[l15*ASTR + s*32 + q4*8];
    f32x4 acc[2];
    #pragma unroll
    for(int nt = 0; nt < 2; nt++){ acc[nt][0]=0.f; acc[nt][1]=0.f; acc[nt][2]=0.f; acc[nt][3]=0.f; }
    #pragma unroll
    for(int nt = 0; nt < 2; nt++){
      const int n = (wave*2+nt)*16 + l15;
      #pragma unroll
      for(int s = 0; s < 4; s++){
        bf16x8 bf = *(const bf16x8*)&packP[((s*128 + n)*4 + q4)*8];
        acc[nt] = __builtin_amdgcn_mfma_f32_16x16x32_bf16(af[s], bf, acc[nt], 0,0,0);
      }
    }
    float s1[4], s2[4];
    #pragma unroll
    for(int r = 0; r < 4; r++){ s1[r]=0.f; s2[r]=0.f; }
    #pragma unroll
    for(int nt = 0; nt < 2; nt++){
      const int col = (wave*2+nt)*16 + l15;
      const float bp = proj_b[col], l1 = ls1[col];
      #pragma unroll
      for(int r = 0; r < 4; r++){
        const int p = q4*4 + r;
        const float hx = xvL[p*128 + col] + l1*(acc[nt][r] + bp);
        xh[nt][r] = hx; s1[r] += hx; s2[r] += hx*hx;
      }
    }
    rowred4(s1, s2, red, wave, lane);
    #pragma unroll
    for(int nt = 0; nt < 2; nt++){
      const int col = (wave*2+nt)*16 + l15;
      const float g2 = n2g[col], be = n2b[col];
      #pragma unroll
      for(int r = 0; r < 4; r++){
        const int p = q4*4 + r;
        const float mu = s1[r]*(1.f/128.f);
        const float var = s2[r]*(1.f/128.f) - mu*mu;
        Abuf[p*ASTR + col] =
          __float2bfloat16((xh[nt][r]-mu)*rsqrtf(var+1e-6f)*g2 + be);
      }
    }
  }
  __syncthreads();

  // ---- fc1 GEMM (N=176, tiles 3/3/3/2) + midLN + gelu -> Abuf ----
  {
    bf16x8 af[4];
    #pragma unroll
    for(int s = 0; s < 4; s++) af[s] = *(const bf16x8*)&Abuf[l15*ASTR + s*32 + q4*8];
    const int NT1 = (wave < 3) ? 3 : 2;
    const int tb  = (wave < 3) ? wave*3 : 9;
    f32x4 acc1[3];
    #pragma unroll
    for(int nt = 0; nt < 3; nt++){ acc1[nt][0]=0.f; acc1[nt][1]=0.f; acc1[nt][2]=0.f; acc1[nt][3]=0.f; }
    for(int nt = 0; nt < NT1; nt++){
      const int n = (tb + nt)*16 + l15;
      #pragma unroll
      for(int s = 0; s < 4; s++){
        bf16x8 bf = *(const bf16x8*)&packF1[((s*176 + n)*4 + q4)*8];
        acc1[nt] = __builtin_amdgcn_mfma_f32_16x16x32_bf16(af[s], bf, acc1[nt], 0,0,0);
      }
    }
    float s1[4], s2[4];
    #pragma unroll
    for(int r = 0; r < 4; r++){ s1[r]=0.f; s2[r]=0.f; }
    for(int nt = 0; nt < NT1; nt++){
      const int col = (tb + nt)*16 + l15;
      const float b1 = (col < 170) ? fc1_b[col] : 0.f;
      #pragma unroll
      for(int r = 0; r < 4; r++){
        const float vv = acc1[nt][r] + b1;
        acc1[nt][r] = vv; s1[r] += vv; s2[r] += vv*vv;
      }
    }
    rowred4(s1, s2, red, wave, lane);
    for(int z = tid; z < 352; z += 256){          // zero fc2 K-pad cols 170..191
      const int row = z / 22, colz = 170 + (z - (z/22)*22);
      Abuf[row*ASTR + colz] = __float2bfloat16(0.f);
    }
    const float kA = 0.7978845608028654f, kB = 0.044715f;
    for(int nt = 0; nt < NT1; nt++){
      const int col = (tb + nt)*16 + l15;
      if(col < 170){
        const float g2 = mg[col], be = mb[col];
        #pragma unroll
        for(int r = 0; r < 4; r++){
          const int p = q4*4 + r;
          const float mu = s1[r]*(1.f/170.f);
          const float var = s2[r]*(1.f/170.f) - mu*mu;
          const float hn = (acc1[nt][r]-mu)*rsqrtf(var+1e-6f)*g2 + be;
          const float u = kA*(hn + kB*hn*hn*hn);
          const float gl = hn / (1.f + __expf(-2.f*u));
          Abuf[p*ASTR + col] = __float2bfloat16(gl);
        }
      }
    }
  }
  __syncthreads();

  // ---- fc2 GEMM (K=192) + ls2*res -> out (B,C,H,W) directly ----
  {
    bf16x8 af[6];
    #pragma unroll
    for(int s = 0; s < 6; s++) af[s] = *(const bf16x8*)&Abuf[l15*ASTR + s*32 + q4*8];
    f32x4 acc[2];
    #pragma unroll
    for(int nt = 0; nt < 2; nt++){ acc[nt][0]=0.f; acc[nt][1]=0.f; acc[nt][2]=0.f; acc[nt][3]=0.f; }
    #pragma unroll
    for(int nt = 0; nt < 2; nt++){
      const int n = (wave*2+nt)*16 + l15;
      #pragma unroll
      for(int s = 0; s < 6; s++){
        bf16x8 bf = *(const bf16x8*)&packF2[((s*128 + n)*4 + q4)*8];
        acc[nt] = __builtin_amdgcn_mfma_f32_16x16x32_bf16(af[s], bf, acc[nt], 0,0,0);
      }
    }
    #pragma unroll
    for(int nt = 0; nt < 2; nt++){
      const int col = (wave*2+nt)*16 + l15;
      const float bf2 = fc2_b[col], l2 = ls2[col];
      float4 o4;
      o4.x = xh[nt][0] + l2*(acc[nt][0] + bf2);
      o4.y = xh[nt][1] + l2*(acc[nt][1] + bf2);
      o4.z = xh[nt][2] + l2*(acc[nt][2] + bf2);
      o4.w = xh[nt][3] + l2*(acc[nt][3] + bf2);
      *(float4*)(out + (size_t)(b*128 + col)*16384 + (size_t)(4*ip + q4)*128 + 4*jq) = o4;
    }
  }
}

extern "C" void kernel_launch(void* const* d_in, const int* in_sizes, int n_in,
                              void* d_out, int out_size, void* d_ws, size_t ws_size,
                              hipStream_t stream){
  const float* x      = (const float*)d_in[0];
  const float* qkv_w  = (const float*)d_in[1];
  const float* qkv_b  = (const float*)d_in[2];
  const float* qg     = (const float*)d_in[3];
  const float* qb     = (const float*)d_in[4];
  const float* kg     = (const float*)d_in[5];
  const float* kb     = (const float*)d_in[6];
  const float* proj_w = (const float*)d_in[7];
  const float* proj_b = (const float*)d_in[8];
  const float* n1g    = (const float*)d_in[9];
  const float* n1b    = (const float*)d_in[10];
  const float* n2g    = (const float*)d_in[11];
  const float* n2b    = (const float*)d_in[12];
  const float* ls1    = (const float*)d_in[13];
  const float* ls2    = (const float*)d_in[14];
  const float* fc1_w  = (const float*)d_in[15];
  const float* fc1_b  = (const float*)d_in[16];
  const float* mg     = (const float*)d_in[17];
  const float* mb     = (const float*)d_in[18];
  const float* fc2_w  = (const float*)d_in[19];
  const float* fc2_b  = (const float*)d_in[20];

  float* ws   = (float*)d_ws;
  float* kcb  = ws;
  float* vcbT = ws + 1048576;                 // [2][2][64][40][128] = 2.62M floats
  BF* pk      = (BF*)(ws + 3670016);
  BF* packQ   = pk;
  BF* packP   = pk + 49152;
  BF* packF1  = pk + 65536;
  BF* packF2  = pk + 88064;

  k_pre <<<952, 256, 0, stream>>>(x, qkv_w, proj_w, fc1_w, fc2_w, qkv_b,
                                  kg, kb, n1g, n1b, pk, kcb, vcbT);
  k_cell<<<2048, 256, 0, stream>>>(x, packQ, packP, packF1, packF2,
                                   qkv_b, qg, qb, n1g, n1b, proj_b, ls1, ls2,
                                   n2g, n2b, fc1_b, mg, mb, fc2_b,
                                   kcb, vcbT, (float*)d_out);
}

// Round 13
// 197.767 us; speedup vs baseline: 2.9350x; 1.0732x over previous
//
#include <hip/hip_runtime.h>
#include <hip/hip_bf16.h>

typedef __hip_bfloat16 BF;
typedef __attribute__((ext_vector_type(8))) short bf16x8;
typedef __attribute__((ext_vector_type(4))) float f32x4;

// B=2, C=128, H=W=128, K=8, STRIDE=2, DIL=2, NH=8, dh=16, HID=170, Hc=Wc=64
// fp32 in / fp32 out. MFMA (bf16, fp32 acc) everywhere.
// R13 (= R12 resubmit; R12 never ran - GPU acquisition timeout):
// K and V stored bf16 in MFMA-operand order:
//   kcb_bf[nb(8192)][d(128)]            -> QK frag = 2 aligned 16B loads, 0 cvt
//   vcbT2[b][par][ri][d(128)][rjh(48)]  -> PV frag = 1 16B load, 0 cvt
//     (rjh pads [0..7],[40..47] zeroed; data at [8..39]; bases 8-ushort aligned)
// Bit-identical operands vs R10 (store-time RNE == load-time RNE).
// ws: kcb_bf[0,524288 fl) vcbT2[524288,2097152 fl) packs(bf16) at 2097152 fl.
// NOTE (R7): cooperative grid.sync on gfx950 de-caches L2 -- never fuse
// across a coop sync on this chip.

#define ASTR 200   // k_cell Abuf row stride (bf16)
#define KSTR 136   // k_pre(kv) Abuf row stride (bf16)

// 2x f32 -> packed bf16 (RNE) in one instruction
__device__ __forceinline__ unsigned cvt2(float lo, float hi){
  unsigned r;
  asm("v_cvt_pk_bf16_f32 %0, %1, %2" : "=v"(r) : "v"(lo), "v"(hi));
  return r;
}
// single f32 -> bf16 bits (RNE), via cvt_pk low half
__device__ __forceinline__ ushort bf1(float f){
  return (ushort)cvt2(f, f);
}
__device__ __forceinline__ bf16x8 pk8(float4 a, float4 b){
  union{ unsigned u[4]; bf16x8 v; } c;
  c.u[0] = cvt2(a.x, a.y); c.u[1] = cvt2(a.z, a.w);
  c.u[2] = cvt2(b.x, b.y); c.u[3] = cvt2(b.z, b.w);
  return c.v;
}

// sum-reduce 16 vals across a 128-thr half (2 waves) of a 256-thr block
__device__ __forceinline__ void gsum16h(float v[16], float* red, int tid){
  #pragma unroll
  for(int s = 1; s < 64; s <<= 1){
    #pragma unroll
    for(int i = 0; i < 16; i++) v[i] += __shfl_xor(v[i], s);
  }
  const int wid = tid >> 6, half = tid >> 7;
  __syncthreads();
  if((tid & 63) == 0){
    #pragma unroll
    for(int i = 0; i < 16; i++) red[wid*16 + i] = v[i];
  }
  __syncthreads();
  #pragma unroll
  for(int i = 0; i < 16; i++) v[i] = red[half*32 + i] + red[half*32 + 16 + i];
}

// per-half row-stat reduction (k_pre kv)
__device__ __forceinline__ void rowredh(float s1[4], float s2[4], float* red, int tid){
  const int lane = tid & 63, wid = tid >> 6, half = tid >> 7;
  #pragma unroll
  for(int m = 1; m < 16; m <<= 1){
    #pragma unroll
    for(int r = 0; r < 4; r++){ s1[r] += __shfl_xor(s1[r], m); s2[r] += __shfl_xor(s2[r], m); }
  }
  const int q4 = lane >> 4;
  __syncthreads();
  if((lane & 15) == 0){
    #pragma unroll
    for(int r = 0; r < 4; r++){
      red[wid*32 + q4*4 + r]      = s1[r];
      red[wid*32 + 16 + q4*4 + r] = s2[r];
    }
  }
  __syncthreads();
  #pragma unroll
  for(int r = 0; r < 4; r++){
    s1[r] = red[half*64 + q4*4 + r]      + red[half*64 + 32 + q4*4 + r];
    s2[r] = red[half*64 + 16 + q4*4 + r] + red[half*64 + 48 + q4*4 + r];
  }
}

// 4-wave row-stat reduction (k_cell): rows 0..15 = px, stats over 128 cols
__device__ __forceinline__ void rowred4(float s1[4], float s2[4], float* red,
                                        int wave, int lane){
  #pragma unroll
  for(int m = 1; m < 16; m <<= 1){
    #pragma unroll
    for(int r = 0; r < 4; r++){ s1[r] += __shfl_xor(s1[r], m); s2[r] += __shfl_xor(s2[r], m); }
  }
  const int q4 = lane >> 4;
  __syncthreads();
  if((lane & 15) == 0){
    #pragma unroll
    for(int r = 0; r < 4; r++){
      red[wave*32 + q4*4 + r]      = s1[r];
      red[wave*32 + 16 + q4*4 + r] = s2[r];
    }
  }
  __syncthreads();
  #pragma unroll
  for(int r = 0; r < 4; r++){
    s1[r] = red[q4*4 + r] + red[32 + q4*4 + r] + red[64 + q4*4 + r] + red[96 + q4*4 + r];
    s2[r] = red[16 + q4*4 + r] + red[48 + q4*4 + r] + red[80 + q4*4 + r] + red[112 + q4*4 + r];
  }
}

// ---- K_pre: {coarse k,v (blocks 0..511) | weight pack + pad-zero (512..951)} ----
__global__ void __launch_bounds__(256)
k_pre(const float* __restrict__ x,
      const float* __restrict__ qkv_w, const float* __restrict__ proj_w,
      const float* __restrict__ fc1_w, const float* __restrict__ fc2_w,
      const float* __restrict__ qkv_b,
      const float* __restrict__ kg, const float* __restrict__ kb,
      const float* __restrict__ n1g, const float* __restrict__ n1b,
      BF* __restrict__ pk,
      BF* __restrict__ kcb, BF* __restrict__ vcbT){
  __shared__ __align__(16) unsigned char sm[9216];
  const int bx0 = blockIdx.x, tid = threadIdx.x;

  if(bx0 >= 512){                      // ---- weight pack + vcbT pad zeroing
    const int idx = (bx0 - 512) * 256 + tid;
    if(idx < 112640){
      float val;
      if(idx < 49152){
        const int reg = idx >> 14, l = idx & 16383;
        const int j = l & 7, q = (l>>3)&3, n = (l>>5)&127, s = l>>12;
        val = qkv_w[(reg*128 + n)*128 + (s*32 + q*8 + j)];
      } else if(idx < 65536){
        const int l = idx - 49152;
        const int j = l&7, q=(l>>3)&3, n=(l>>5)&127, s=l>>12;
        val = proj_w[n*128 + (s*32+q*8+j)];
      } else if(idx < 88064){
        const int l = idx - 65536;
        const int j = l&7, q=(l>>3)&3, rem = l>>5;
        const int n = rem % 176, s = rem / 176;
        const int k = s*32+q*8+j;
        val = (n < 170) ? fc1_w[n*128 + k] : 0.f;
      } else {
        const int l = idx - 88064;
        const int j = l&7, q=(l>>3)&3, n=(l>>5)&127, s=l>>12;
        const int k = s*32+q*8+j;
        val = (k < 170) ? fc2_w[n*170 + k] : 0.f;
      }
      pk[idx] = __float2bfloat16(val);
    }
    // zero vcbT2 pad chunks: 32768 rows x 2 chunks (rjh [0..7] and [40..47]),
    // each 8 ushorts = one aligned uint4 store. Disjoint from kv writers.
    if(idx < 65536){
      const int row = idx >> 1, side = idx & 1;
      uint4 z; z.x = 0u; z.y = 0u; z.z = 0u; z.w = 0u;
      *(uint4*)(vcbT + (size_t)row*48 + side*40) = z;
    }
    return;
  }

  // ---- kv: 16 coarse px/block (one ri row, rj=jb..jb+15), 2 indep halves ----
  // XCD swizzle (512 % 8 == 0, chunks of 64): groups of 4 consecutive bx
  // (which share vcbT2 cache lines) land on one XCD, temporally adjacent.
  const int bx = ((bx0 & 7) << 6) | (bx0 >> 3);
  BF* const Abuf = (BF*)sm;                    // 2 halves x [16][KSTR]
  ushort* const vbuf = (ushort*)sm;            // [16][128] (aliases Abuf, post-GEMM)
  float* const red = (float*)(sm + 8704);      // 128 floats
  const int lane = tid & 63, half = tid >> 7, wh = (tid >> 6) & 1, c = tid & 127;
  const int l15 = lane & 15, q4 = lane >> 4;
  const int cp0 = bx * 16;
  const int b = cp0 >> 12, ic = (cp0 & 4095) >> 6, jb = cp0 & 63;
  BF* const AbufH = Abuf + half*16*KSTR;

  float xv[8];
  {
    const size_t off = (size_t)(b*128 + c)*16384 + (size_t)(2*ic)*128 + 2*(jb + half*8);
    const float4* xp4 = (const float4*)(x + off);
    const float4 f0 = xp4[0], f1 = xp4[1], f2 = xp4[2], f3 = xp4[3];
    xv[0]=f0.x; xv[1]=f0.z; xv[2]=f1.x; xv[3]=f1.z;
    xv[4]=f2.x; xv[5]=f2.z; xv[6]=f3.x; xv[7]=f3.z;
  }
  float st[16];
  #pragma unroll
  for(int r = 0; r < 8; r++){ st[r] = xv[r]; st[8+r] = xv[r]*xv[r]; }
  gsum16h(st, red, tid);
  {
    const float g = n1g[c], be = n1b[c];
    #pragma unroll
    for(int r = 0; r < 8; r++){
      const float mu = st[r]*(1.f/128.f);
      const float var = st[8+r]*(1.f/128.f) - mu*mu;
      AbufH[r*KSTR + c] = __float2bfloat16((xv[r]-mu)*rsqrtf(var+1e-6f)*g + be);
    }
  }
  __syncthreads();
  bf16x8 af[4];
  #pragma unroll
  for(int s = 0; s < 4; s++) af[s] = *(const bf16x8*)&AbufH[l15*KSTR + s*32 + q4*8];

  // ---- k GEMM -> kcb (bf16, fragment-row order) ----
  f32x4 acc[4];
  #pragma unroll
  for(int nt = 0; nt < 4; nt++){ acc[nt][0]=0.f; acc[nt][1]=0.f; acc[nt][2]=0.f; acc[nt][3]=0.f; }
  #pragma unroll
  for(int nt = 0; nt < 4; nt++){
    const int n = (wh*4+nt)*16 + l15;
    #pragma unroll
    for(int s = 0; s < 4; s++){
      const float* wp = qkv_w + (size_t)(128 + n)*128 + s*32 + q4*8;
      acc[nt] = __builtin_amdgcn_mfma_f32_16x16x32_bf16(
        af[s], pk8(*(const float4*)wp, *(const float4*)(wp+4)), acc[nt], 0,0,0);
    }
  }
  float s1[4], s2[4];
  #pragma unroll
  for(int r = 0; r < 4; r++){ s1[r]=0.f; s2[r]=0.f; }
  #pragma unroll
  for(int nt = 0; nt < 4; nt++){
    const float colb = qkv_b[128 + (wh*4+nt)*16 + l15];
    #pragma unroll
    for(int r = 0; r < 4; r++){
      const float vv = acc[nt][r] + colb;
      acc[nt][r] = vv; s1[r] += vv; s2[r] += vv*vv;
    }
  }
  rowredh(s1, s2, red, tid);
  #pragma unroll
  for(int nt = 0; nt < 4; nt++){
    const int col = (wh*4+nt)*16 + l15;
    const float g = kg[col], be = kb[col];
    #pragma unroll
    for(int r = 0; r < 4; r++){
      const int row = q4*4 + r;
      if(row < 8){
        const float mu = s1[r]*(1.f/128.f);
        const float var = s2[r]*(1.f/128.f) - mu*mu;
        ((ushort*)kcb)[(size_t)(cp0 + half*8 + row)*128 + col] =
          bf1((acc[nt][r]-mu)*rsqrtf(var+1e-6f)*g + be);
      }
    }
  }
  // ---- v GEMM -> vbuf (LDS) -> transposed bf16 store to vcbT2 ----
  #pragma unroll
  for(int nt = 0; nt < 4; nt++){ acc[nt][0]=0.f; acc[nt][1]=0.f; acc[nt][2]=0.f; acc[nt][3]=0.f; }
  #pragma unroll
  for(int nt = 0; nt < 4; nt++){
    const int n = (wh*4+nt)*16 + l15;
    #pragma unroll
    for(int s = 0; s < 4; s++){
      const float* wp = qkv_w + (size_t)(256 + n)*128 + s*32 + q4*8;
      acc[nt] = __builtin_amdgcn_mfma_f32_16x16x32_bf16(
        af[s], pk8(*(const float4*)wp, *(const float4*)(wp+4)), acc[nt], 0,0,0);
    }
  }
  __syncthreads();                       // Abuf reads done; reuse as vbuf
  #pragma unroll
  for(int nt = 0; nt < 4; nt++){
    const int col = (wh*4+nt)*16 + l15;
    const float bv = qkv_b[256 + col];
    #pragma unroll
    for(int r = 0; r < 4; r++){
      const int row = q4*4 + r;
      if(row < 8)
        vbuf[(half*8 + row)*128 + col] = bf1(acc[nt][r] + bv);
    }
  }
  __syncthreads();
  {
    // thread (par, d): gather 8 rjh values (rows 2j+par) at fixed d -> 16B store
    const int par = tid >> 7, d = tid & 127;
    union{ ushort s[8]; uint4 q; } w;
    #pragma unroll
    for(int j = 0; j < 8; j++) w.s[j] = vbuf[(2*j + par)*128 + d];
    *(uint4*)(vcbT + ((((size_t)(b*2 + par)*64 + ic)*128) + d)*48 + (jb>>1) + 8) = w.q;
  }
}

// ---- K_cell: 256 thr / 16 px (4 cells) / all-MFMA, bf16 direct operands ----
// px p: h = 4ip + (p>>2), w = 4jq + (p&3); cell(p) = 2*(p>>3) + ((p>>1)&1);
// lp(p) = 2*((p>>2)&1) + (p&1). Wave w owns cell w for attention.
__global__ void __launch_bounds__(256, 6)
k_cell(const float* __restrict__ x,
       const BF* __restrict__ packQ, const BF* __restrict__ packP,
       const BF* __restrict__ packF1, const BF* __restrict__ packF2,
       const float* __restrict__ qkv_b,
       const float* __restrict__ qg, const float* __restrict__ qb,
       const float* __restrict__ n1g, const float* __restrict__ n1b,
       const float* __restrict__ proj_b,
       const float* __restrict__ ls1, const float* __restrict__ ls2,
       const float* __restrict__ n2g, const float* __restrict__ n2b,
       const float* __restrict__ fc1_b,
       const float* __restrict__ mg, const float* __restrict__ mb,
       const float* __restrict__ fc2_b,
       const BF* __restrict__ kcb, const BF* __restrict__ vcbT,
       float* __restrict__ out){
  __shared__ __align__(16) BF uni[4608];       // Abuf[16][ASTR] U 4x Pb
  BF* const Abuf = uni;
  __shared__ float xvL[2048];                  // [16px][128ch]
  __shared__ __align__(16) ushort qnH[2176];   // [4cell][136pad][4lp]
  __shared__ ushort cidx2[256];                // [4cell][64] safe coarse idx
  float* const red = (float*)qnH;              // 128 floats, disjoint live range
  const int tid = threadIdx.x, wave = tid>>6, lane = tid&63;
  const int l15 = lane & 15, q4 = lane >> 4;

  // XCD-aware swizzle (bijective: 2048 % 8 == 0, chunks of 256 per XCD)
  const int bx0 = blockIdx.x;
  const int bx = ((bx0 & 7) << 8) | (bx0 >> 3);
  const int b = bx >> 10, rem = bx & 1023, ip = rem >> 5, jq = rem & 31;
  const int c = tid & 127, half = tid >> 7;

  // direct (B,C,H,W) reads: 2 aligned float4 per thread
  float xv[8];
  {
    const size_t xb = (size_t)(b*128 + c)*16384 + (size_t)(4*ip + 2*half)*128 + 4*jq;
    const float4 r0 = *(const float4*)(x + xb);
    const float4 r1 = *(const float4*)(x + xb + 128);
    xv[0]=r0.x; xv[1]=r0.y; xv[2]=r0.z; xv[3]=r0.w;
    xv[4]=r1.x; xv[5]=r1.y; xv[6]=r1.z; xv[7]=r1.w;
    #pragma unroll
    for(int r = 0; r < 8; r++) xvL[(half*8 + r)*128 + c] = xv[r];
  }
  {                                            // neighbor indices, 4 cells
    const int cell = tid >> 6, e = tid & 63;
    const int i = e >> 3, j = e & 7;
    const int ic = 2*ip + (cell>>1), jcc = 2*jq + (cell&1);
    const int ri = ic + 2*i - 8, rj = jcc + 2*j - 8;
    const bool ok = (rj >= 0) && (rj < 64) && (ri >= 0) && (ri < 64);
    cidx2[cell*64 + e] = ok ? (ushort)(b*4096 + ri*64 + rj) : (ushort)0;
  }

  // ---- LN1 ----
  float st[16];
  #pragma unroll
  for(int r = 0; r < 8; r++){ st[r] = xv[r]; st[8+r] = xv[r]*xv[r]; }
  gsum16h(st, red, tid);
  {
    const float g = n1g[c], be = n1b[c];
    #pragma unroll
    for(int r = 0; r < 8; r++){
      const int p = half*8 + r;
      const float mu = st[r]*(1.f/128.f);
      const float var = st[8+r]*(1.f/128.f) - mu*mu;
      Abuf[p*ASTR + c] = __float2bfloat16((xv[r]-mu)*rsqrtf(var+1e-6f)*g + be);
    }
  }
  __syncthreads();

  // ---- q GEMM (M=16) + q-LN -> qnH ----
  {
    bf16x8 af[4];
    #pragma unroll
    for(int s = 0; s < 4; s++) af[s] = *(const bf16x8*)&Abuf[l15*ASTR + s*32 + q4*8];
    f32x4 acc[2];
    #pragma unroll
    for(int nt = 0; nt < 2; nt++){ acc[nt][0]=0.f; acc[nt][1]=0.f; acc[nt][2]=0.f; acc[nt][3]=0.f; }
    #pragma unroll
    for(int nt = 0; nt < 2; nt++){
      const int n = (wave*2+nt)*16 + l15;
      #pragma unroll
      for(int s = 0; s < 4; s++){
        bf16x8 bf = *(const bf16x8*)&packQ[((s*128 + n)*4 + q4)*8];
        acc[nt] = __builtin_amdgcn_mfma_f32_16x16x32_bf16(af[s], bf, acc[nt], 0,0,0);
      }
    }
    float s1[4], s2[4];
    #pragma unroll
    for(int r = 0; r < 4; r++){ s1[r]=0.f; s2[r]=0.f; }
    #pragma unroll
    for(int nt = 0; nt < 2; nt++){
      const float cb2 = qkv_b[(wave*2+nt)*16 + l15];
      #pragma unroll
      for(int r = 0; r < 4; r++){
        const float vv = acc[nt][r] + cb2;
        acc[nt][r] = vv; s1[r] += vv; s2[r] += vv*vv;
      }
    }
    rowred4(s1, s2, red, wave, lane);
    ushort tw[2][4];
    {
      float mu[4], rs[4];
      #pragma unroll
      for(int r = 0; r < 4; r++){
        mu[r] = s1[r]*(1.f/128.f);
        rs[r] = rsqrtf(s2[r]*(1.f/128.f) - mu[r]*mu[r] + 1e-6f);
      }
      #pragma unroll
      for(int nt = 0; nt < 2; nt++){
        const int col = (wave*2+nt)*16 + l15;
        const float g = qg[col], be = qb[col];
        float v0 = (acc[nt][0]-mu[0])*rs[0]*g + be;
        float v1 = (acc[nt][1]-mu[1])*rs[1]*g + be;
        float v2 = (acc[nt][2]-mu[2])*rs[2]*g + be;
        float v3 = (acc[nt][3]-mu[3])*rs[3]*g + be;
        const unsigned d0 = cvt2(v0, v1), d1 = cvt2(v2, v3);
        tw[nt][0] = (ushort)d0; tw[nt][1] = (ushort)(d0 >> 16);
        tw[nt][2] = (ushort)d1; tw[nt][3] = (ushort)(d1 >> 16);
      }
    }
    __syncthreads();            // red (aliased with qnH) fully consumed
    #pragma unroll
    for(int nt = 0; nt < 2; nt++){
      const int col = (wave*2+nt)*16 + l15;
      const int colp = col + (col >> 4);
      #pragma unroll
      for(int r = 0; r < 4; r++){
        const int cell = 2*(q4>>1) + ((r>>1)&1);
        const int lp   = 2*(q4&1) + (r&1);
        qnH[cell*544 + colp*4 + lp] = tw[nt][r];
      }
    }
  }
  __syncthreads();

  // ---- attention: wave w owns cell w, 2 head-groups, no inner barriers ----
  const int hsub = l15 >> 2, px = l15 & 3;
  const int par4 = q4 >> 1, dbase = (q4 & 1) * 8;
  BF* const attw = uni + wave*1152;
  ushort* const Pb = (ushort*)attw;            // [16][72]
  const ushort* cidx = cidx2 + wave*64;
  const ushort* qp = qnH + wave*544;
  const int ic = 2*ip + (wave>>1), jcc = 2*jq + (wave&1);
  const int i0 = l15 >> 3;
  const int rj = jcc + 2*(l15 & 7) - 8;
  const bool vj = (rj >= 0) && (rj < 64);
  float madd[4];
  #pragma unroll
  for(int nt = 0; nt < 4; nt++){
    const int ri = ic + 2*(nt*2 + i0) - 8;
    madd[nt] = (vj && ri >= 0 && ri < 64) ? 0.f : -1e30f;
  }
  // direct-V bf16 base pointers (frag = 8 consecutive rjh at fixed d=hoff+l15)
  const int parv = jcc & 1;
  const int riA = min(63, max(0, ic + 2*q4 - 8));
  const int riB = min(63, max(0, ic + 2*q4));
  const BF* vbA = vcbT + ((((size_t)(b*2 + parv)*64 + riA)*128) + l15)*48 + (jcc>>1) + 4;
  const BF* vbB = vcbT + ((((size_t)(b*2 + parv)*64 + riB)*128) + l15)*48 + (jcc>>1) + 4;

  f32x4 oC[2];
  #pragma unroll
  for(int hg = 0; hg < 2; hg++){
    // block-diagonal q A-fragments
    bf16x8 afq0, afq1;
    {
      const int idx0 = (hg*64 + hsub*16 + dbase + (hg*4 + hsub))*4 + px;
      short bq[8];
      #pragma unroll
      for(int j = 0; j < 8; j++) bq[j] = (short)qp[idx0 + 4*j];
      const bool a0 = (par4 == hsub), a1 = ((2 + par4) == hsub);
      #pragma unroll
      for(int j = 0; j < 8; j++){
        afq0[j] = a0 ? bq[j] : (short)0;
        afq1[j] = a1 ? bq[j] : (short)0;
      }
    }
    // QK: 8 MFMA, operands straight from kcb (bf16, aligned)
    f32x4 accq[4];
    #pragma unroll
    for(int nt = 0; nt < 4; nt++){ accq[nt][0]=0.f; accq[nt][1]=0.f; accq[nt][2]=0.f; accq[nt][3]=0.f; }
    #pragma unroll
    for(int nt = 0; nt < 4; nt++){
      const ushort* kp = (const ushort*)kcb + ((size_t)cidx[nt*16 + l15] << 7) + hg*64 + q4*8;
      bf16x8 b0, b1;
      __builtin_memcpy(&b0, kp, 16);
      __builtin_memcpy(&b1, kp + 32, 16);
      accq[nt] = __builtin_amdgcn_mfma_f32_16x16x32_bf16(afq0, b0, accq[nt], 0,0,0);
      accq[nt] = __builtin_amdgcn_mfma_f32_16x16x32_bf16(afq1, b1, accq[nt], 0,0,0);
    }
    // softmax in-register; unnormalized e (bf16 via cvt_pk) -> Pb
    float inv[4];
    #pragma unroll
    for(int reg = 0; reg < 4; reg++){
      const float s0 = accq[0][reg]*0.25f + madd[0];
      const float s1 = accq[1][reg]*0.25f + madd[1];
      const float s2 = accq[2][reg]*0.25f + madd[2];
      const float s3 = accq[3][reg]*0.25f + madd[3];
      float m = fmaxf(fmaxf(s0,s1), fmaxf(s2,s3));
      #pragma unroll
      for(int sft = 1; sft < 16; sft <<= 1) m = fmaxf(m, __shfl_xor(m, sft));
      const float e0 = __expf(s0-m), e1 = __expf(s1-m);
      const float e2 = __expf(s2-m), e3 = __expf(s3-m);
      ushort* pr = Pb + (q4*4 + reg)*72 + l15;
      const unsigned d0 = cvt2(e0, e1), d1 = cvt2(e2, e3);
      pr[0]  = (ushort)d0;
      pr[16] = (ushort)(d0 >> 16);
      pr[32] = (ushort)d1;
      pr[48] = (ushort)(d1 >> 16);
      float es = e0+e1+e2+e3;
      #pragma unroll
      for(int sft = 1; sft < 16; sft <<= 1) es += __shfl_xor(es, sft);
      inv[reg] = 1.f/es;
    }
    const bf16x8 pa0 = *(const bf16x8*)(Pb + l15*72 + q4*8);
    const bf16x8 pa1 = *(const bf16x8*)(Pb + l15*72 + 32 + q4*8);

    // PV: one (possibly unaligned) 16B bf16 load per fragment, zero cvt
    f32x4 oSel; oSel[0]=0.f; oSel[1]=0.f; oSel[2]=0.f; oSel[3]=0.f;
    #pragma unroll
    for(int hs = 0; hs < 4; hs++){
      const int hoff = (hg*4 + hs)*16;
      bf16x8 c0, c1;
      __builtin_memcpy(&c0, vbA + (size_t)hoff*48, 16);
      __builtin_memcpy(&c1, vbB + (size_t)hoff*48, 16);
      f32x4 accv; accv[0]=0.f; accv[1]=0.f; accv[2]=0.f; accv[3]=0.f;
      accv = __builtin_amdgcn_mfma_f32_16x16x32_bf16(pa0, c0, accv, 0,0,0);
      accv = __builtin_amdgcn_mfma_f32_16x16x32_bf16(pa1, c1, accv, 0,0,0);
      if(q4 == hs){ oSel[0]=accv[0]; oSel[1]=accv[1]; oSel[2]=accv[2]; oSel[3]=accv[3]; }
    }
    oC[hg][0] = oSel[0]*inv[0]; oC[hg][1] = oSel[1]*inv[1];
    oC[hg][2] = oSel[2]*inv[2]; oC[hg][3] = oSel[3]*inv[3];
  }
  __syncthreads();
  // ao -> Abuf[px p][head*16 + d] (cvt_pk pairs)
  {
    ushort* ab = (ushort*)Abuf;
    #pragma unroll
    for(int hg = 0; hg < 2; hg++){
      const int col = (hg*4 + q4)*16 + l15;
      const unsigned d0 = cvt2(oC[hg][0], oC[hg][1]);
      const unsigned d1 = cvt2(oC[hg][2], oC[hg][3]);
      const ushort ov[4] = {(ushort)d0, (ushort)(d0>>16), (ushort)d1, (ushort)(d1>>16)};
      #pragma unroll
      for(int reg = 0; reg < 4; reg++){
        const int row_p = 8*(wave>>1) + 4*(reg>>1) + 2*(wave&1) + (reg&1);
        ab[row_p*ASTR + col] = ov[reg];
      }
    }
  }
  __syncthreads();

  // ---- proj GEMM + ls1*res -> xh, LN2 -> Abuf ----
  float xh[2][4];
  {
    bf16x8 af[4];
    #pragma unroll
    for(int s = 0; s < 4; s++) af[s] = *(const bf16x8*)&Abuf[l15*ASTR + s*32 + q4*8];
    f32x4 acc[2];
    #pragma unroll
    for(int nt = 0; nt < 2; nt++){ acc[nt][0]=0.f; acc[nt][1]=0.f; acc[nt][2]=0.f; acc[nt][3]=0.f; }
    #pragma unroll
    for(int nt = 0; nt < 2; nt++){
      const int n = (wave*2+nt)*16 + l15;
      #pragma unroll
      for(int s = 0; s < 4; s++){
        bf16x8 bf = *(const bf16x8*)&packP[((s*128 + n)*4 + q4)*8];
        acc[nt] = __builtin_amdgcn_mfma_f32_16x16x32_bf16(af[s], bf, acc[nt], 0,0,0);
      }
    }
    float s1[4], s2[4];
    #pragma unroll
    for(int r = 0; r < 4; r++){ s1[r]=0.f; s2[r]=0.f; }
    #pragma unroll
    for(int nt = 0; nt < 2; nt++){
      const int col = (wave*2+nt)*16 + l15;
      const float bp = proj_b[col], l1 = ls1[col];
      #pragma unroll
      for(int r = 0; r < 4; r++){
        const int p = q4*4 + r;
        const float hx = xvL[p*128 + col] + l1*(acc[nt][r] + bp);
        xh[nt][r] = hx; s1[r] += hx; s2[r] += hx*hx;
      }
    }
    rowred4(s1, s2, red, wave, lane);
    #pragma unroll
    for(int nt = 0; nt < 2; nt++){
      const int col = (wave*2+nt)*16 + l15;
      const float g2 = n2g[col], be = n2b[col];
      #pragma unroll
      for(int r = 0; r < 4; r++){
        const int p = q4*4 + r;
        const float mu = s1[r]*(1.f/128.f);
        const float var = s2[r]*(1.f/128.f) - mu*mu;
        Abuf[p*ASTR + col] =
          __float2bfloat16((xh[nt][r]-mu)*rsqrtf(var+1e-6f)*g2 + be);
      }
    }
  }
  __syncthreads();

  // ---- fc1 GEMM (N=176, tiles 3/3/3/2) + midLN + gelu -> Abuf ----
  {
    bf16x8 af[4];
    #pragma unroll
    for(int s = 0; s < 4; s++) af[s] = *(const bf16x8*)&Abuf[l15*ASTR + s*32 + q4*8];
    const int NT1 = (wave < 3) ? 3 : 2;
    const int tb  = (wave < 3) ? wave*3 : 9;
    f32x4 acc1[3];
    #pragma unroll
    for(int nt = 0; nt < 3; nt++){ acc1[nt][0]=0.f; acc1[nt][1]=0.f; acc1[nt][2]=0.f; acc1[nt][3]=0.f; }
    for(int nt = 0; nt < NT1; nt++){
      const int n = (tb + nt)*16 + l15;
      #pragma unroll
      for(int s = 0; s < 4; s++){
        bf16x8 bf = *(const bf16x8*)&packF1[((s*176 + n)*4 + q4)*8];
        acc1[nt] = __builtin_amdgcn_mfma_f32_16x16x32_bf16(af[s], bf, acc1[nt], 0,0,0);
      }
    }
    float s1[4], s2[4];
    #pragma unroll
    for(int r = 0; r < 4; r++){ s1[r]=0.f; s2[r]=0.f; }
    for(int nt = 0; nt < NT1; nt++){
      const int col = (tb + nt)*16 + l15;
      const float b1 = (col < 170) ? fc1_b[col] : 0.f;
      #pragma unroll
      for(int r = 0; r < 4; r++){
        const float vv = acc1[nt][r] + b1;
        acc1[nt][r] = vv; s1[r] += vv; s2[r] += vv*vv;
      }
    }
    rowred4(s1, s2, red, wave, lane);
    for(int z = tid; z < 352; z += 256){          // zero fc2 K-pad cols 170..191
      const int row = z / 22, colz = 170 + (z - (z/22)*22);
      Abuf[row*ASTR + colz] = __float2bfloat16(0.f);
    }
    const float kA = 0.7978845608028654f, kB = 0.044715f;
    for(int nt = 0; nt < NT1; nt++){
      const int col = (tb + nt)*16 + l15;
      if(col < 170){
        const float g2 = mg[col], be = mb[col];
        #pragma unroll
        for(int r = 0; r < 4; r++){
          const int p = q4*4 + r;
          const float mu = s1[r]*(1.f/170.f);
          const float var = s2[r]*(1.f/170.f) - mu*mu;
          const float hn = (acc1[nt][r]-mu)*rsqrtf(var+1e-6f)*g2 + be;
          const float u = kA*(hn + kB*hn*hn*hn);
          const float gl = hn / (1.f + __expf(-2.f*u));
          Abuf[p*ASTR + col] = __float2bfloat16(gl);
        }
      }
    }
  }
  __syncthreads();

  // ---- fc2 GEMM (K=192) + ls2*res -> out (B,C,H,W) directly ----
  {
    bf16x8 af[6];
    #pragma unroll
    for(int s = 0; s < 6; s++) af[s] = *(const bf16x8*)&Abuf[l15*ASTR + s*32 + q4*8];
    f32x4 acc[2];
    #pragma unroll
    for(int nt = 0; nt < 2; nt++){ acc[nt][0]=0.f; acc[nt][1]=0.f; acc[nt][2]=0.f; acc[nt][3]=0.f; }
    #pragma unroll
    for(int nt = 0; nt < 2; nt++){
      const int n = (wave*2+nt)*16 + l15;
      #pragma unroll
      for(int s = 0; s < 6; s++){
        bf16x8 bf = *(const bf16x8*)&packF2[((s*128 + n)*4 + q4)*8];
        acc[nt] = __builtin_amdgcn_mfma_f32_16x16x32_bf16(af[s], bf, acc[nt], 0,0,0);
      }
    }
    #pragma unroll
    for(int nt = 0; nt < 2; nt++){
      const int col = (wave*2+nt)*16 + l15;
      const float bf2 = fc2_b[col], l2 = ls2[col];
      float4 o4;
      o4.x = xh[nt][0] + l2*(acc[nt][0] + bf2);
      o4.y = xh[nt][1] + l2*(acc[nt][1] + bf2);
      o4.z = xh[nt][2] + l2*(acc[nt][2] + bf2);
      o4.w = xh[nt][3] + l2*(acc[nt][3] + bf2);
      *(float4*)(out + (size_t)(b*128 + col)*16384 + (size_t)(4*ip + q4)*128 + 4*jq) = o4;
    }
  }
}

extern "C" void kernel_launch(void* const* d_in, const int* in_sizes, int n_in,
                              void* d_out, int out_size, void* d_ws, size_t ws_size,
                              hipStream_t stream){
  const float* x      = (const float*)d_in[0];
  const float* qkv_w  = (const float*)d_in[1];
  const float* qkv_b  = (const float*)d_in[2];
  const float* qg     = (const float*)d_in[3];
  const float* qb     = (const float*)d_in[4];
  const float* kg     = (const float*)d_in[5];
  const float* kb     = (const float*)d_in[6];
  const float* proj_w = (const float*)d_in[7];
  const float* proj_b = (const float*)d_in[8];
  const float* n1g    = (const float*)d_in[9];
  const float* n1b    = (const float*)d_in[10];
  const float* n2g    = (const float*)d_in[11];
  const float* n2b    = (const float*)d_in[12];
  const float* ls1    = (const float*)d_in[13];
  const float* ls2    = (const float*)d_in[14];
  const float* fc1_w  = (const float*)d_in[15];
  const float* fc1_b  = (const float*)d_in[16];
  const float* mg     = (const float*)d_in[17];
  const float* mb     = (const float*)d_in[18];
  const float* fc2_w  = (const float*)d_in[19];
  const float* fc2_b  = (const float*)d_in[20];

  float* ws   = (float*)d_ws;
  BF* kcb     = (BF*)ws;                       // 8192*128 bf16 = 2MB
  BF* vcbT    = (BF*)(ws + 524288);            // 2*2*64*128*48 bf16 = 6MB
  BF* pk      = (BF*)(ws + 2097152);
  BF* packQ   = pk;
  BF* packP   = pk + 49152;
  BF* packF1  = pk + 65536;
  BF* packF2  = pk + 88064;

  k_pre <<<952, 256, 0, stream>>>(x, qkv_w, proj_w, fc1_w, fc2_w, qkv_b,
                                  kg, kb, n1g, n1b, pk, kcb, vcbT);
  k_cell<<<2048, 256, 0, stream>>>(x, packQ, packP, packF1, packF2,
                                   qkv_b, qg, qb, n1g, n1b, proj_b, ls1, ls2,
                                   n2g, n2b, fc1_b, mg, mb, fc2_b,
                                   kcb, vcbT, (float*)d_out);
}

// Round 14
// 195.765 us; speedup vs baseline: 2.9650x; 1.0102x over previous
//
#include <hip/hip_runtime.h>
#include <hip/hip_bf16.h>

typedef __hip_bfloat16 BF;
typedef __attribute__((ext_vector_type(8))) short bf16x8;
typedef __attribute__((ext_vector_type(4))) float f32x4;

// B=2, C=128, H=W=128, K=8, STRIDE=2, DIL=2, NH=8, dh=16, HID=170, Hc=Wc=64
// fp32 in / fp32 out. MFMA (bf16, fp32 acc) everywhere.
// R14 (= R13 + softmax shift-0 + setprio around attention MFMAs):
// K and V stored bf16 in MFMA-operand order:
//   kcb_bf[nb(8192)][d(128)]            -> QK frag = 2 aligned 16B loads, 0 cvt
//   vcbT2[b][par][ri][d(128)][rjh(48)]  -> PV frag = 1 16B load, 0 cvt
//     (rjh pads [0..7],[40..47] zeroed; data at [8..39]; bases 8-ushort aligned)
// Softmax uses shift=0 (shift-invariant; |scores| << 88 with LN'd q,k;
// masked entries exp(s-1e30)=0 exactly).
// NOTE (R7): cooperative grid.sync on gfx950 de-caches L2 -- never fuse
// across a coop sync on this chip.

#define ASTR 200   // k_cell Abuf row stride (bf16)
#define KSTR 136   // k_pre(kv) Abuf row stride (bf16)

// 2x f32 -> packed bf16 (RNE) in one instruction
__device__ __forceinline__ unsigned cvt2(float lo, float hi){
  unsigned r;
  asm("v_cvt_pk_bf16_f32 %0, %1, %2" : "=v"(r) : "v"(lo), "v"(hi));
  return r;
}
// single f32 -> bf16 bits (RNE), via cvt_pk low half
__device__ __forceinline__ ushort bf1(float f){
  return (ushort)cvt2(f, f);
}
__device__ __forceinline__ bf16x8 pk8(float4 a, float4 b){
  union{ unsigned u[4]; bf16x8 v; } c;
  c.u[0] = cvt2(a.x, a.y); c.u[1] = cvt2(a.z, a.w);
  c.u[2] = cvt2(b.x, b.y); c.u[3] = cvt2(b.z, b.w);
  return c.v;
}

// sum-reduce 16 vals across a 128-thr half (2 waves) of a 256-thr block
__device__ __forceinline__ void gsum16h(float v[16], float* red, int tid){
  #pragma unroll
  for(int s = 1; s < 64; s <<= 1){
    #pragma unroll
    for(int i = 0; i < 16; i++) v[i] += __shfl_xor(v[i], s);
  }
  const int wid = tid >> 6, half = tid >> 7;
  __syncthreads();
  if((tid & 63) == 0){
    #pragma unroll
    for(int i = 0; i < 16; i++) red[wid*16 + i] = v[i];
  }
  __syncthreads();
  #pragma unroll
  for(int i = 0; i < 16; i++) v[i] = red[half*32 + i] + red[half*32 + 16 + i];
}

// per-half row-stat reduction (k_pre kv)
__device__ __forceinline__ void rowredh(float s1[4], float s2[4], float* red, int tid){
  const int lane = tid & 63, wid = tid >> 6, half = tid >> 7;
  #pragma unroll
  for(int m = 1; m < 16; m <<= 1){
    #pragma unroll
    for(int r = 0; r < 4; r++){ s1[r] += __shfl_xor(s1[r], m); s2[r] += __shfl_xor(s2[r], m); }
  }
  const int q4 = lane >> 4;
  __syncthreads();
  if((lane & 15) == 0){
    #pragma unroll
    for(int r = 0; r < 4; r++){
      red[wid*32 + q4*4 + r]      = s1[r];
      red[wid*32 + 16 + q4*4 + r] = s2[r];
    }
  }
  __syncthreads();
  #pragma unroll
  for(int r = 0; r < 4; r++){
    s1[r] = red[half*64 + q4*4 + r]      + red[half*64 + 32 + q4*4 + r];
    s2[r] = red[half*64 + 16 + q4*4 + r] + red[half*64 + 48 + q4*4 + r];
  }
}

// 4-wave row-stat reduction (k_cell): rows 0..15 = px, stats over 128 cols
__device__ __forceinline__ void rowred4(float s1[4], float s2[4], float* red,
                                        int wave, int lane){
  #pragma unroll
  for(int m = 1; m < 16; m <<= 1){
    #pragma unroll
    for(int r = 0; r < 4; r++){ s1[r] += __shfl_xor(s1[r], m); s2[r] += __shfl_xor(s2[r], m); }
  }
  const int q4 = lane >> 4;
  __syncthreads();
  if((lane & 15) == 0){
    #pragma unroll
    for(int r = 0; r < 4; r++){
      red[wave*32 + q4*4 + r]      = s1[r];
      red[wave*32 + 16 + q4*4 + r] = s2[r];
    }
  }
  __syncthreads();
  #pragma unroll
  for(int r = 0; r < 4; r++){
    s1[r] = red[q4*4 + r] + red[32 + q4*4 + r] + red[64 + q4*4 + r] + red[96 + q4*4 + r];
    s2[r] = red[16 + q4*4 + r] + red[48 + q4*4 + r] + red[80 + q4*4 + r] + red[112 + q4*4 + r];
  }
}

// ---- K_pre: {coarse k,v (blocks 0..511) | weight pack + pad-zero (512..951)} ----
__global__ void __launch_bounds__(256)
k_pre(const float* __restrict__ x,
      const float* __restrict__ qkv_w, const float* __restrict__ proj_w,
      const float* __restrict__ fc1_w, const float* __restrict__ fc2_w,
      const float* __restrict__ qkv_b,
      const float* __restrict__ kg, const float* __restrict__ kb,
      const float* __restrict__ n1g, const float* __restrict__ n1b,
      BF* __restrict__ pk,
      BF* __restrict__ kcb, BF* __restrict__ vcbT){
  __shared__ __align__(16) unsigned char sm[9216];
  const int bx0 = blockIdx.x, tid = threadIdx.x;

  if(bx0 >= 512){                      // ---- weight pack + vcbT pad zeroing
    const int idx = (bx0 - 512) * 256 + tid;
    if(idx < 112640){
      float val;
      if(idx < 49152){
        const int reg = idx >> 14, l = idx & 16383;
        const int j = l & 7, q = (l>>3)&3, n = (l>>5)&127, s = l>>12;
        val = qkv_w[(reg*128 + n)*128 + (s*32 + q*8 + j)];
      } else if(idx < 65536){
        const int l = idx - 49152;
        const int j = l&7, q=(l>>3)&3, n=(l>>5)&127, s=l>>12;
        val = proj_w[n*128 + (s*32+q*8+j)];
      } else if(idx < 88064){
        const int l = idx - 65536;
        const int j = l&7, q=(l>>3)&3, rem = l>>5;
        const int n = rem % 176, s = rem / 176;
        const int k = s*32+q*8+j;
        val = (n < 170) ? fc1_w[n*128 + k] : 0.f;
      } else {
        const int l = idx - 88064;
        const int j = l&7, q=(l>>3)&3, n=(l>>5)&127, s=l>>12;
        const int k = s*32+q*8+j;
        val = (k < 170) ? fc2_w[n*170 + k] : 0.f;
      }
      pk[idx] = __float2bfloat16(val);
    }
    // zero vcbT2 pad chunks: 32768 rows x 2 chunks (rjh [0..7] and [40..47]),
    // each 8 ushorts = one aligned uint4 store. Disjoint from kv writers.
    if(idx < 65536){
      const int row = idx >> 1, side = idx & 1;
      uint4 z; z.x = 0u; z.y = 0u; z.z = 0u; z.w = 0u;
      *(uint4*)(vcbT + (size_t)row*48 + side*40) = z;
    }
    return;
  }

  // ---- kv: 16 coarse px/block (one ri row, rj=jb..jb+15), 2 indep halves ----
  const int bx = ((bx0 & 7) << 6) | (bx0 >> 3);
  BF* const Abuf = (BF*)sm;                    // 2 halves x [16][KSTR]
  ushort* const vbuf = (ushort*)sm;            // [16][128] (aliases Abuf, post-GEMM)
  float* const red = (float*)(sm + 8704);      // 128 floats
  const int lane = tid & 63, half = tid >> 7, wh = (tid >> 6) & 1, c = tid & 127;
  const int l15 = lane & 15, q4 = lane >> 4;
  const int cp0 = bx * 16;
  const int b = cp0 >> 12, ic = (cp0 & 4095) >> 6, jb = cp0 & 63;
  BF* const AbufH = Abuf + half*16*KSTR;

  float xv[8];
  {
    const size_t off = (size_t)(b*128 + c)*16384 + (size_t)(2*ic)*128 + 2*(jb + half*8);
    const float4* xp4 = (const float4*)(x + off);
    const float4 f0 = xp4[0], f1 = xp4[1], f2 = xp4[2], f3 = xp4[3];
    xv[0]=f0.x; xv[1]=f0.z; xv[2]=f1.x; xv[3]=f1.z;
    xv[4]=f2.x; xv[5]=f2.z; xv[6]=f3.x; xv[7]=f3.z;
  }
  float st[16];
  #pragma unroll
  for(int r = 0; r < 8; r++){ st[r] = xv[r]; st[8+r] = xv[r]*xv[r]; }
  gsum16h(st, red, tid);
  {
    const float g = n1g[c], be = n1b[c];
    #pragma unroll
    for(int r = 0; r < 8; r++){
      const float mu = st[r]*(1.f/128.f);
      const float var = st[8+r]*(1.f/128.f) - mu*mu;
      AbufH[r*KSTR + c] = __float2bfloat16((xv[r]-mu)*rsqrtf(var+1e-6f)*g + be);
    }
  }
  __syncthreads();
  bf16x8 af[4];
  #pragma unroll
  for(int s = 0; s < 4; s++) af[s] = *(const bf16x8*)&AbufH[l15*KSTR + s*32 + q4*8];

  // ---- k GEMM -> kcb (bf16, fragment-row order) ----
  f32x4 acc[4];
  #pragma unroll
  for(int nt = 0; nt < 4; nt++){ acc[nt][0]=0.f; acc[nt][1]=0.f; acc[nt][2]=0.f; acc[nt][3]=0.f; }
  #pragma unroll
  for(int nt = 0; nt < 4; nt++){
    const int n = (wh*4+nt)*16 + l15;
    #pragma unroll
    for(int s = 0; s < 4; s++){
      const float* wp = qkv_w + (size_t)(128 + n)*128 + s*32 + q4*8;
      acc[nt] = __builtin_amdgcn_mfma_f32_16x16x32_bf16(
        af[s], pk8(*(const float4*)wp, *(const float4*)(wp+4)), acc[nt], 0,0,0);
    }
  }
  float s1[4], s2[4];
  #pragma unroll
  for(int r = 0; r < 4; r++){ s1[r]=0.f; s2[r]=0.f; }
  #pragma unroll
  for(int nt = 0; nt < 4; nt++){
    const float colb = qkv_b[128 + (wh*4+nt)*16 + l15];
    #pragma unroll
    for(int r = 0; r < 4; r++){
      const float vv = acc[nt][r] + colb;
      acc[nt][r] = vv; s1[r] += vv; s2[r] += vv*vv;
    }
  }
  rowredh(s1, s2, red, tid);
  #pragma unroll
  for(int nt = 0; nt < 4; nt++){
    const int col = (wh*4+nt)*16 + l15;
    const float g = kg[col], be = kb[col];
    #pragma unroll
    for(int r = 0; r < 4; r++){
      const int row = q4*4 + r;
      if(row < 8){
        const float mu = s1[r]*(1.f/128.f);
        const float var = s2[r]*(1.f/128.f) - mu*mu;
        ((ushort*)kcb)[(size_t)(cp0 + half*8 + row)*128 + col] =
          bf1((acc[nt][r]-mu)*rsqrtf(var+1e-6f)*g + be);
      }
    }
  }
  // ---- v GEMM -> vbuf (LDS) -> transposed bf16 store to vcbT2 ----
  #pragma unroll
  for(int nt = 0; nt < 4; nt++){ acc[nt][0]=0.f; acc[nt][1]=0.f; acc[nt][2]=0.f; acc[nt][3]=0.f; }
  #pragma unroll
  for(int nt = 0; nt < 4; nt++){
    const int n = (wh*4+nt)*16 + l15;
    #pragma unroll
    for(int s = 0; s < 4; s++){
      const float* wp = qkv_w + (size_t)(256 + n)*128 + s*32 + q4*8;
      acc[nt] = __builtin_amdgcn_mfma_f32_16x16x32_bf16(
        af[s], pk8(*(const float4*)wp, *(const float4*)(wp+4)), acc[nt], 0,0,0);
    }
  }
  __syncthreads();                       // Abuf reads done; reuse as vbuf
  #pragma unroll
  for(int nt = 0; nt < 4; nt++){
    const int col = (wh*4+nt)*16 + l15;
    const float bv = qkv_b[256 + col];
    #pragma unroll
    for(int r = 0; r < 4; r++){
      const int row = q4*4 + r;
      if(row < 8)
        vbuf[(half*8 + row)*128 + col] = bf1(acc[nt][r] + bv);
    }
  }
  __syncthreads();
  {
    // thread (par, d): gather 8 rjh values (rows 2j+par) at fixed d -> 16B store
    const int par = tid >> 7, d = tid & 127;
    union{ ushort s[8]; uint4 q; } w;
    #pragma unroll
    for(int j = 0; j < 8; j++) w.s[j] = vbuf[(2*j + par)*128 + d];
    *(uint4*)(vcbT + ((((size_t)(b*2 + par)*64 + ic)*128) + d)*48 + (jb>>1) + 8) = w.q;
  }
}

// ---- K_cell: 256 thr / 16 px (4 cells) / all-MFMA, bf16 direct operands ----
// px p: h = 4ip + (p>>2), w = 4jq + (p&3); cell(p) = 2*(p>>3) + ((p>>1)&1);
// lp(p) = 2*((p>>2)&1) + (p&1). Wave w owns cell w for attention.
__global__ void __launch_bounds__(256, 6)
k_cell(const float* __restrict__ x,
       const BF* __restrict__ packQ, const BF* __restrict__ packP,
       const BF* __restrict__ packF1, const BF* __restrict__ packF2,
       const float* __restrict__ qkv_b,
       const float* __restrict__ qg, const float* __restrict__ qb,
       const float* __restrict__ n1g, const float* __restrict__ n1b,
       const float* __restrict__ proj_b,
       const float* __restrict__ ls1, const float* __restrict__ ls2,
       const float* __restrict__ n2g, const float* __restrict__ n2b,
       const float* __restrict__ fc1_b,
       const float* __restrict__ mg, const float* __restrict__ mb,
       const float* __restrict__ fc2_b,
       const BF* __restrict__ kcb, const BF* __restrict__ vcbT,
       float* __restrict__ out){
  __shared__ __align__(16) BF uni[4608];       // Abuf[16][ASTR] U 4x Pb
  BF* const Abuf = uni;
  __shared__ float xvL[2048];                  // [16px][128ch]
  __shared__ __align__(16) ushort qnH[2176];   // [4cell][136pad][4lp]
  __shared__ ushort cidx2[256];                // [4cell][64] safe coarse idx
  float* const red = (float*)qnH;              // 128 floats, disjoint live range
  const int tid = threadIdx.x, wave = tid>>6, lane = tid&63;
  const int l15 = lane & 15, q4 = lane >> 4;

  // XCD-aware swizzle (bijective: 2048 % 8 == 0, chunks of 256 per XCD)
  const int bx0 = blockIdx.x;
  const int bx = ((bx0 & 7) << 8) | (bx0 >> 3);
  const int b = bx >> 10, rem = bx & 1023, ip = rem >> 5, jq = rem & 31;
  const int c = tid & 127, half = tid >> 7;

  // direct (B,C,H,W) reads: 2 aligned float4 per thread
  float xv[8];
  {
    const size_t xb = (size_t)(b*128 + c)*16384 + (size_t)(4*ip + 2*half)*128 + 4*jq;
    const float4 r0 = *(const float4*)(x + xb);
    const float4 r1 = *(const float4*)(x + xb + 128);
    xv[0]=r0.x; xv[1]=r0.y; xv[2]=r0.z; xv[3]=r0.w;
    xv[4]=r1.x; xv[5]=r1.y; xv[6]=r1.z; xv[7]=r1.w;
    #pragma unroll
    for(int r = 0; r < 8; r++) xvL[(half*8 + r)*128 + c] = xv[r];
  }
  {                                            // neighbor indices, 4 cells
    const int cell = tid >> 6, e = tid & 63;
    const int i = e >> 3, j = e & 7;
    const int ic = 2*ip + (cell>>1), jcc = 2*jq + (cell&1);
    const int ri = ic + 2*i - 8, rj = jcc + 2*j - 8;
    const bool ok = (rj >= 0) && (rj < 64) && (ri >= 0) && (ri < 64);
    cidx2[cell*64 + e] = ok ? (ushort)(b*4096 + ri*64 + rj) : (ushort)0;
  }

  // ---- LN1 ----
  float st[16];
  #pragma unroll
  for(int r = 0; r < 8; r++){ st[r] = xv[r]; st[8+r] = xv[r]*xv[r]; }
  gsum16h(st, red, tid);
  {
    const float g = n1g[c], be = n1b[c];
    #pragma unroll
    for(int r = 0; r < 8; r++){
      const int p = half*8 + r;
      const float mu = st[r]*(1.f/128.f);
      const float var = st[8+r]*(1.f/128.f) - mu*mu;
      Abuf[p*ASTR + c] = __float2bfloat16((xv[r]-mu)*rsqrtf(var+1e-6f)*g + be);
    }
  }
  __syncthreads();

  // ---- q GEMM (M=16) + q-LN -> qnH ----
  {
    bf16x8 af[4];
    #pragma unroll
    for(int s = 0; s < 4; s++) af[s] = *(const bf16x8*)&Abuf[l15*ASTR + s*32 + q4*8];
    f32x4 acc[2];
    #pragma unroll
    for(int nt = 0; nt < 2; nt++){ acc[nt][0]=0.f; acc[nt][1]=0.f; acc[nt][2]=0.f; acc[nt][3]=0.f; }
    #pragma unroll
    for(int nt = 0; nt < 2; nt++){
      const int n = (wave*2+nt)*16 + l15;
      #pragma unroll
      for(int s = 0; s < 4; s++){
        bf16x8 bf = *(const bf16x8*)&packQ[((s*128 + n)*4 + q4)*8];
        acc[nt] = __builtin_amdgcn_mfma_f32_16x16x32_bf16(af[s], bf, acc[nt], 0,0,0);
      }
    }
    float s1[4], s2[4];
    #pragma unroll
    for(int r = 0; r < 4; r++){ s1[r]=0.f; s2[r]=0.f; }
    #pragma unroll
    for(int nt = 0; nt < 2; nt++){
      const float cb2 = qkv_b[(wave*2+nt)*16 + l15];
      #pragma unroll
      for(int r = 0; r < 4; r++){
        const float vv = acc[nt][r] + cb2;
        acc[nt][r] = vv; s1[r] += vv; s2[r] += vv*vv;
      }
    }
    rowred4(s1, s2, red, wave, lane);
    ushort tw[2][4];
    {
      float mu[4], rs[4];
      #pragma unroll
      for(int r = 0; r < 4; r++){
        mu[r] = s1[r]*(1.f/128.f);
        rs[r] = rsqrtf(s2[r]*(1.f/128.f) - mu[r]*mu[r] + 1e-6f);
      }
      #pragma unroll
      for(int nt = 0; nt < 2; nt++){
        const int col = (wave*2+nt)*16 + l15;
        const float g = qg[col], be = qb[col];
        float v0 = (acc[nt][0]-mu[0])*rs[0]*g + be;
        float v1 = (acc[nt][1]-mu[1])*rs[1]*g + be;
        float v2 = (acc[nt][2]-mu[2])*rs[2]*g + be;
        float v3 = (acc[nt][3]-mu[3])*rs[3]*g + be;
        const unsigned d0 = cvt2(v0, v1), d1 = cvt2(v2, v3);
        tw[nt][0] = (ushort)d0; tw[nt][1] = (ushort)(d0 >> 16);
        tw[nt][2] = (ushort)d1; tw[nt][3] = (ushort)(d1 >> 16);
      }
    }
    __syncthreads();            // red (aliased with qnH) fully consumed
    #pragma unroll
    for(int nt = 0; nt < 2; nt++){
      const int col = (wave*2+nt)*16 + l15;
      const int colp = col + (col >> 4);
      #pragma unroll
      for(int r = 0; r < 4; r++){
        const int cell = 2*(q4>>1) + ((r>>1)&1);
        const int lp   = 2*(q4&1) + (r&1);
        qnH[cell*544 + colp*4 + lp] = tw[nt][r];
      }
    }
  }
  __syncthreads();

  // ---- attention: wave w owns cell w, 2 head-groups, no inner barriers ----
  const int hsub = l15 >> 2, px = l15 & 3;
  const int par4 = q4 >> 1, dbase = (q4 & 1) * 8;
  BF* const attw = uni + wave*1152;
  ushort* const Pb = (ushort*)attw;            // [16][72]
  const ushort* cidx = cidx2 + wave*64;
  const ushort* qp = qnH + wave*544;
  const int ic = 2*ip + (wave>>1), jcc = 2*jq + (wave&1);
  const int i0 = l15 >> 3;
  const int rj = jcc + 2*(l15 & 7) - 8;
  const bool vj = (rj >= 0) && (rj < 64);
  float madd[4];
  #pragma unroll
  for(int nt = 0; nt < 4; nt++){
    const int ri = ic + 2*(nt*2 + i0) - 8;
    madd[nt] = (vj && ri >= 0 && ri < 64) ? 0.f : -1e30f;
  }
  // direct-V bf16 base pointers (frag = 8 consecutive rjh at fixed d=hoff+l15)
  const int parv = jcc & 1;
  const int riA = min(63, max(0, ic + 2*q4 - 8));
  const int riB = min(63, max(0, ic + 2*q4));
  const BF* vbA = vcbT + ((((size_t)(b*2 + parv)*64 + riA)*128) + l15)*48 + (jcc>>1) + 4;
  const BF* vbB = vcbT + ((((size_t)(b*2 + parv)*64 + riB)*128) + l15)*48 + (jcc>>1) + 4;

  f32x4 oC[2];
  #pragma unroll
  for(int hg = 0; hg < 2; hg++){
    // block-diagonal q A-fragments
    bf16x8 afq0, afq1;
    {
      const int idx0 = (hg*64 + hsub*16 + dbase + (hg*4 + hsub))*4 + px;
      short bq[8];
      #pragma unroll
      for(int j = 0; j < 8; j++) bq[j] = (short)qp[idx0 + 4*j];
      const bool a0 = (par4 == hsub), a1 = ((2 + par4) == hsub);
      #pragma unroll
      for(int j = 0; j < 8; j++){
        afq0[j] = a0 ? bq[j] : (short)0;
        afq1[j] = a1 ? bq[j] : (short)0;
      }
    }
    // QK: 8 MFMA, operands straight from kcb (bf16, aligned)
    f32x4 accq[4];
    #pragma unroll
    for(int nt = 0; nt < 4; nt++){ accq[nt][0]=0.f; accq[nt][1]=0.f; accq[nt][2]=0.f; accq[nt][3]=0.f; }
    __builtin_amdgcn_s_setprio(1);
    #pragma unroll
    for(int nt = 0; nt < 4; nt++){
      const ushort* kp = (const ushort*)kcb + ((size_t)cidx[nt*16 + l15] << 7) + hg*64 + q4*8;
      bf16x8 b0, b1;
      __builtin_memcpy(&b0, kp, 16);
      __builtin_memcpy(&b1, kp + 32, 16);
      accq[nt] = __builtin_amdgcn_mfma_f32_16x16x32_bf16(afq0, b0, accq[nt], 0,0,0);
      accq[nt] = __builtin_amdgcn_mfma_f32_16x16x32_bf16(afq1, b1, accq[nt], 0,0,0);
    }
    __builtin_amdgcn_s_setprio(0);
    // softmax in-register, shift=0 (shift-invariant; scores bounded);
    // masked: exp(s - 1e30) == 0 exactly. Unnormalized e (bf16) -> Pb.
    float inv[4];
    #pragma unroll
    for(int reg = 0; reg < 4; reg++){
      const float e0 = __expf(accq[0][reg]*0.25f + madd[0]);
      const float e1 = __expf(accq[1][reg]*0.25f + madd[1]);
      const float e2 = __expf(accq[2][reg]*0.25f + madd[2]);
      const float e3 = __expf(accq[3][reg]*0.25f + madd[3]);
      ushort* pr = Pb + (q4*4 + reg)*72 + l15;
      const unsigned d0 = cvt2(e0, e1), d1 = cvt2(e2, e3);
      pr[0]  = (ushort)d0;
      pr[16] = (ushort)(d0 >> 16);
      pr[32] = (ushort)d1;
      pr[48] = (ushort)(d1 >> 16);
      float es = e0+e1+e2+e3;
      #pragma unroll
      for(int sft = 1; sft < 16; sft <<= 1) es += __shfl_xor(es, sft);
      inv[reg] = 1.f/es;
    }
    const bf16x8 pa0 = *(const bf16x8*)(Pb + l15*72 + q4*8);
    const bf16x8 pa1 = *(const bf16x8*)(Pb + l15*72 + 32 + q4*8);

    // PV: one (possibly unaligned) 16B bf16 load per fragment, zero cvt
    f32x4 oSel; oSel[0]=0.f; oSel[1]=0.f; oSel[2]=0.f; oSel[3]=0.f;
    __builtin_amdgcn_s_setprio(1);
    #pragma unroll
    for(int hs = 0; hs < 4; hs++){
      const int hoff = (hg*4 + hs)*16;
      bf16x8 c0, c1;
      __builtin_memcpy(&c0, vbA + (size_t)hoff*48, 16);
      __builtin_memcpy(&c1, vbB + (size_t)hoff*48, 16);
      f32x4 accv; accv[0]=0.f; accv[1]=0.f; accv[2]=0.f; accv[3]=0.f;
      accv = __builtin_amdgcn_mfma_f32_16x16x32_bf16(pa0, c0, accv, 0,0,0);
      accv = __builtin_amdgcn_mfma_f32_16x16x32_bf16(pa1, c1, accv, 0,0,0);
      if(q4 == hs){ oSel[0]=accv[0]; oSel[1]=accv[1]; oSel[2]=accv[2]; oSel[3]=accv[3]; }
    }
    __builtin_amdgcn_s_setprio(0);
    oC[hg][0] = oSel[0]*inv[0]; oC[hg][1] = oSel[1]*inv[1];
    oC[hg][2] = oSel[2]*inv[2]; oC[hg][3] = oSel[3]*inv[3];
  }
  __syncthreads();
  // ao -> Abuf[px p][head*16 + d] (cvt_pk pairs)
  {
    ushort* ab = (ushort*)Abuf;
    #pragma unroll
    for(int hg = 0; hg < 2; hg++){
      const int col = (hg*4 + q4)*16 + l15;
      const unsigned d0 = cvt2(oC[hg][0], oC[hg][1]);
      const unsigned d1 = cvt2(oC[hg][2], oC[hg][3]);
      const ushort ov[4] = {(ushort)d0, (ushort)(d0>>16), (ushort)d1, (ushort)(d1>>16)};
      #pragma unroll
      for(int reg = 0; reg < 4; reg++){
        const int row_p = 8*(wave>>1) + 4*(reg>>1) + 2*(wave&1) + (reg&1);
        ab[row_p*ASTR + col] = ov[reg];
      }
    }
  }
  __syncthreads();

  // ---- proj GEMM + ls1*res -> xh, LN2 -> Abuf ----
  float xh[2][4];
  {
    bf16x8 af[4];
    #pragma unroll
    for(int s = 0; s < 4; s++) af[s] = *(const bf16x8*)&Abuf[l15*ASTR + s*32 + q4*8];
    f32x4 acc[2];
    #pragma unroll
    for(int nt = 0; nt < 2; nt++){ acc[nt][0]=0.f; acc[nt][1]=0.f; acc[nt][2]=0.f; acc[nt][3]=0.f; }
    #pragma unroll
    for(int nt = 0; nt < 2; nt++){
      const int n = (wave*2+nt)*16 + l15;
      #pragma unroll
      for(int s = 0; s < 4; s++){
        bf16x8 bf = *(const bf16x8*)&packP[((s*128 + n)*4 + q4)*8];
        acc[nt] = __builtin_amdgcn_mfma_f32_16x16x32_bf16(af[s], bf, acc[nt], 0,0,0);
      }
    }
    float s1[4], s2[4];
    #pragma unroll
    for(int r = 0; r < 4; r++){ s1[r]=0.f; s2[r]=0.f; }
    #pragma unroll
    for(int nt = 0; nt < 2; nt++){
      const int col = (wave*2+nt)*16 + l15;
      const float bp = proj_b[col], l1 = ls1[col];
      #pragma unroll
      for(int r = 0; r < 4; r++){
        const int p = q4*4 + r;
        const float hx = xvL[p*128 + col] + l1*(acc[nt][r] + bp);
        xh[nt][r] = hx; s1[r] += hx; s2[r] += hx*hx;
      }
    }
    rowred4(s1, s2, red, wave, lane);
    #pragma unroll
    for(int nt = 0; nt < 2; nt++){
      const int col = (wave*2+nt)*16 + l15;
      const float g2 = n2g[col], be = n2b[col];
      #pragma unroll
      for(int r = 0; r < 4; r++){
        const int p = q4*4 + r;
        const float mu = s1[r]*(1.f/128.f);
        const float var = s2[r]*(1.f/128.f) - mu*mu;
        Abuf[p*ASTR + col] =
          __float2bfloat16((xh[nt][r]-mu)*rsqrtf(var+1e-6f)*g2 + be);
      }
    }
  }
  __syncthreads();

  // ---- fc1 GEMM (N=176, tiles 3/3/3/2) + midLN + gelu -> Abuf ----
  {
    bf16x8 af[4];
    #pragma unroll
    for(int s = 0; s < 4; s++) af[s] = *(const bf16x8*)&Abuf[l15*ASTR + s*32 + q4*8];
    const int NT1 = (wave < 3) ? 3 : 2;
    const int tb  = (wave < 3) ? wave*3 : 9;
    f32x4 acc1[3];
    #pragma unroll
    for(int nt = 0; nt < 3; nt++){ acc1[nt][0]=0.f; acc1[nt][1]=0.f; acc1[nt][2]=0.f; acc1[nt][3]=0.f; }
    for(int nt = 0; nt < NT1; nt++){
      const int n = (tb + nt)*16 + l15;
      #pragma unroll
      for(int s = 0; s < 4; s++){
        bf16x8 bf = *(const bf16x8*)&packF1[((s*176 + n)*4 + q4)*8];
        acc1[nt] = __builtin_amdgcn_mfma_f32_16x16x32_bf16(af[s], bf, acc1[nt], 0,0,0);
      }
    }
    float s1[4], s2[4];
    #pragma unroll
    for(int r = 0; r < 4; r++){ s1[r]=0.f; s2[r]=0.f; }
    for(int nt = 0; nt < NT1; nt++){
      const int col = (tb + nt)*16 + l15;
      const float b1 = (col < 170) ? fc1_b[col] : 0.f;
      #pragma unroll
      for(int r = 0; r < 4; r++){
        const float vv = acc1[nt][r] + b1;
        acc1[nt][r] = vv; s1[r] += vv; s2[r] += vv*vv;
      }
    }
    rowred4(s1, s2, red, wave, lane);
    for(int z = tid; z < 352; z += 256){          // zero fc2 K-pad cols 170..191
      const int row = z / 22, colz = 170 + (z - (z/22)*22);
      Abuf[row*ASTR + colz] = __float2bfloat16(0.f);
    }
    const float kA = 0.7978845608028654f, kB = 0.044715f;
    for(int nt = 0; nt < NT1; nt++){
      const int col = (tb + nt)*16 + l15;
      if(col < 170){
        const float g2 = mg[col], be = mb[col];
        #pragma unroll
        for(int r = 0; r < 4; r++){
          const int p = q4*4 + r;
          const float mu = s1[r]*(1.f/170.f);
          const float var = s2[r]*(1.f/170.f) - mu*mu;
          const float hn = (acc1[nt][r]-mu)*rsqrtf(var+1e-6f)*g2 + be;
          const float u = kA*(hn + kB*hn*hn*hn);
          const float gl = hn / (1.f + __expf(-2.f*u));
          Abuf[p*ASTR + col] = __float2bfloat16(gl);
        }
      }
    }
  }
  __syncthreads();

  // ---- fc2 GEMM (K=192) + ls2*res -> out (B,C,H,W) directly ----
  {
    bf16x8 af[6];
    #pragma unroll
    for(int s = 0; s < 6; s++) af[s] = *(const bf16x8*)&Abuf[l15*ASTR + s*32 + q4*8];
    f32x4 acc[2];
    #pragma unroll
    for(int nt = 0; nt < 2; nt++){ acc[nt][0]=0.f; acc[nt][1]=0.f; acc[nt][2]=0.f; acc[nt][3]=0.f; }
    #pragma unroll
    for(int nt = 0; nt < 2; nt++){
      const int n = (wave*2+nt)*16 + l15;
      #pragma unroll
      for(int s = 0; s < 6; s++){
        bf16x8 bf = *(const bf16x8*)&packF2[((s*128 + n)*4 + q4)*8];
        acc[nt] = __builtin_amdgcn_mfma_f32_16x16x32_bf16(af[s], bf, acc[nt], 0,0,0);
      }
    }
    #pragma unroll
    for(int nt = 0; nt < 2; nt++){
      const int col = (wave*2+nt)*16 + l15;
      const float bf2 = fc2_b[col], l2 = ls2[col];
      float4 o4;
      o4.x = xh[nt][0] + l2*(acc[nt][0] + bf2);
      o4.y = xh[nt][1] + l2*(acc[nt][1] + bf2);
      o4.z = xh[nt][2] + l2*(acc[nt][2] + bf2);
      o4.w = xh[nt][3] + l2*(acc[nt][3] + bf2);
      *(float4*)(out + (size_t)(b*128 + col)*16384 + (size_t)(4*ip + q4)*128 + 4*jq) = o4;
    }
  }
}

extern "C" void kernel_launch(void* const* d_in, const int* in_sizes, int n_in,
                              void* d_out, int out_size, void* d_ws, size_t ws_size,
                              hipStream_t stream){
  const float* x      = (const float*)d_in[0];
  const float* qkv_w  = (const float*)d_in[1];
  const float* qkv_b  = (const float*)d_in[2];
  const float* qg     = (const float*)d_in[3];
  const float* qb     = (const float*)d_in[4];
  const float* kg     = (const float*)d_in[5];
  const float* kb     = (const float*)d_in[6];
  const float* proj_w = (const float*)d_in[7];
  const float* proj_b = (const float*)d_in[8];
  const float* n1g    = (const float*)d_in[9];
  const float* n1b    = (const float*)d_in[10];
  const float* n2g    = (const float*)d_in[11];
  const float* n2b    = (const float*)d_in[12];
  const float* ls1    = (const float*)d_in[13];
  const float* ls2    = (const float*)d_in[14];
  const float* fc1_w  = (const float*)d_in[15];
  const float* fc1_b  = (const float*)d_in[16];
  const float* mg     = (const float*)d_in[17];
  const float* mb     = (const float*)d_in[18];
  const float* fc2_w  = (const float*)d_in[19];
  const float* fc2_b  = (const float*)d_in[20];

  float* ws   = (float*)d_ws;
  BF* kcb     = (BF*)ws;                       // 8192*128 bf16 = 2MB
  BF* vcbT    = (BF*)(ws + 524288);            // 2*2*64*128*48 bf16 = 6MB
  BF* pk      = (BF*)(ws + 2097152);
  BF* packQ   = pk;
  BF* packP   = pk + 49152;
  BF* packF1  = pk + 65536;
  BF* packF2  = pk + 88064;

  k_pre <<<952, 256, 0, stream>>>(x, qkv_w, proj_w, fc1_w, fc2_w, qkv_b,
                                  kg, kb, n1g, n1b, pk, kcb, vcbT);
  k_cell<<<2048, 256, 0, stream>>>(x, packQ, packP, packF1, packF2,
                                   qkv_b, qg, qb, n1g, n1b, proj_b, ls1, ls2,
                                   n2g, n2b, fc1_b, mg, mb, fc2_b,
                                   kcb, vcbT, (float*)d_out);
}